// Round 9
// baseline (425.560 us; speedup 1.0000x reference)
//
#include <hip/hip_runtime.h>
#include <hip/hip_cooperative_groups.h>
#include <math.h>

#define BB 8
#define CC 64
#define NN 2048
#define KK 20
#define OO 128
#define CANDT 40
#define NPART 512          // tail blocks (32 pts each)
#define M_TOT 327680.0f    // B*N*K

namespace cg = cooperative_groups;

typedef __attribute__((ext_vector_type(8))) __bf16 bf8v;
typedef __attribute__((ext_vector_type(16))) float f32x16;

// ---------------------------------------------------------------------------
// k_prep: xT[b][n][c] bf16 rows (MFMA frags), xTf f32 rows (rescore), xx/xxf.
// ---------------------------------------------------------------------------
__global__ __launch_bounds__(256) void k_prep(const float* __restrict__ x,
                                              ushort* __restrict__ xT,
                                              float* __restrict__ xTf,
                                              double* __restrict__ xx,
                                              float* __restrict__ xxf) {
  int i = blockIdx.x * 256 + threadIdx.x;
  int b = i >> 11, n = i & (NN - 1);
  const float* p = x + ((size_t)b * CC) * NN + n;
  ushort* rowp = xT + (size_t)i * CC;
  float* rowf = xTf + (size_t)i * CC;
  double s = 0.0;
#pragma unroll
  for (int c8 = 0; c8 < 8; ++c8) {
    float f[8];
    unsigned tmp[8];
#pragma unroll
    for (int e = 0; e < 8; ++e) {
      float v = p[(size_t)(c8 * 8 + e) * NN];
      f[e] = v;
      double dv = (double)v; s = fma(dv, dv, s);
      __bf16 h = (__bf16)v;
      ushort us; __builtin_memcpy(&us, &h, 2);
      tmp[e] = us;
    }
    uint4 pk;
    pk.x = tmp[0] | (tmp[1] << 16);
    pk.y = tmp[2] | (tmp[3] << 16);
    pk.z = tmp[4] | (tmp[5] << 16);
    pk.w = tmp[6] | (tmp[7] << 16);
    *(uint4*)(rowp + c8 * 8) = pk;
    *(float4*)(rowf + c8 * 8)     = make_float4(f[0], f[1], f[2], f[3]);
    *(float4*)(rowf + c8 * 8 + 4) = make_float4(f[4], f[5], f[6], f[7]);
  }
  xx[i] = s;
  xxf[i] = (float)s;
}

// ---------------------------------------------------------------------------
// k_knn: R4 structure (best measured: 78.8us). 512 blocks x 1024 thr;
// 32 rows/block; wave w covers cols [w*128,+128) via 32x32x16 MFMA; selection
// 2 rows/wave (ILP). Changes vs R4: (a) Phase B stores monotone-u16 KEYS from
// the f32 score (one transform at write; better precision than bf16 value);
// (b) packed b32 key reads (half the LDS ops, keys32[16] regs not u[32]);
// (c) ctz-bitmask compaction. fp64 rescore order identical -> same idx.
// ---------------------------------------------------------------------------
__global__ __launch_bounds__(1024, 4) void k_knn(
    const ushort* __restrict__ xT, const float* __restrict__ xxf,
    const float* __restrict__ xTf, const double* __restrict__ xx,
    int* __restrict__ idx) {
  extern __shared__ char smem[];
  ushort (*Sb)[NN] = (ushort(*)[NN])smem;          // [32][2048] u16 keys 128KB
  int* Cj = (int*)(smem + 32 * NN * 2);            // [16][64] 4KB
  double* Sd = (double*)(smem + 32 * NN * 2 + 4096); // [16][64] 8KB
  const int t = threadIdx.x;
  const int w = t >> 6, lane = t & 63;
  const int bidswz = ((blockIdx.x & 7) << 6) + (blockIdx.x >> 3); // batch/XCD
  const int b = bidswz >> 6;
  const int i0 = (bidswz & 63) << 5;
  const int lr = lane & 31, lh = lane >> 5;
  const ushort* xTb = xT + (((size_t)b) << 11) * CC;

  // ---- Phase A: MFMA 32x32x16 ----
  f32x16 acc[4];
#pragma unroll
  for (int tt = 0; tt < 4; ++tt)
#pragma unroll
    for (int q = 0; q < 16; ++q) acc[tt][q] = 0.f;

  const ushort* Ap = xTb + (size_t)(i0 + lr) * CC + lh * 8;
  bf8v a0 = *(const bf8v*)(Ap);
  bf8v a1 = *(const bf8v*)(Ap + 16);
  bf8v a2 = *(const bf8v*)(Ap + 32);
  bf8v a3 = *(const bf8v*)(Ap + 48);
  const int j0w = w << 7;
#pragma unroll
  for (int tt = 0; tt < 4; ++tt) {
    const ushort* Bp = xTb + (size_t)(j0w + tt * 32 + lr) * CC + lh * 8;
    bf8v b0 = *(const bf8v*)(Bp);
    bf8v b1 = *(const bf8v*)(Bp + 16);
    bf8v b2 = *(const bf8v*)(Bp + 32);
    bf8v b3 = *(const bf8v*)(Bp + 48);
    acc[tt] = __builtin_amdgcn_mfma_f32_32x32x16_bf16(a0, b0, acc[tt], 0, 0, 0);
    acc[tt] = __builtin_amdgcn_mfma_f32_32x32x16_bf16(a1, b1, acc[tt], 0, 0, 0);
    acc[tt] = __builtin_amdgcn_mfma_f32_32x32x16_bf16(a2, b2, acc[tt], 0, 0, 0);
    acc[tt] = __builtin_amdgcn_mfma_f32_32x32x16_bf16(a3, b3, acc[tt], 0, 0, 0);
  }

  // ---- Phase B: f32 score -> monotone u16 key -> LDS ----
  const float* xxfb = xxf + (b << 11);
#pragma unroll
  for (int tt = 0; tt < 4; ++tt) {
    int j = j0w + tt * 32 + lr;
    float xv = xxfb[j];
#pragma unroll
    for (int q = 0; q < 16; ++q) {
      int rr = (q & 3) + 8 * (q >> 2) + 4 * lh;    // 32x32 C/D map (m74/m101)
      float sv = fmaf(2.f, acc[tt][q], -xv);
      unsigned u = __float_as_uint(sv);
      u ^= (0x80000000u | (unsigned)((int)u >> 31)); // monotone u32
      Sb[rr][j] = (ushort)(u >> 16);
    }
  }
  __syncthreads();

  // ---- Phase C: 2 rows per wave ----
  const float* xTfb = xTf + (((size_t)b) << 11) * CC;
  const double* xxb = xx + (b << 11);
#pragma unroll 1
  for (int rw = 0; rw < 2; ++rw) {
    const int rr = w + 16 * rw;
    const int irow = i0 + rr;
    unsigned keys32[16];
    unsigned t0 = 0, t1 = 0, t2 = 0, t3 = 0;
#pragma unroll
    for (int g = 0; g < 16; ++g) {
      unsigned raw = *(const unsigned*)(&Sb[rr][lane * 2 + g * 128]);
      keys32[g] = raw;
      unsigned k0 = raw & 0xffffu, k1 = raw >> 16;
      unsigned mx, mn;
      mx = k0 > t0 ? k0 : t0; mn = k0 > t0 ? t0 : k0; t0 = mx;
      mx = mn > t1 ? mn : t1; mn = mn > t1 ? t1 : mn; t1 = mx;
      mx = mn > t2 ? mn : t2; mn = mn > t2 ? t2 : mn; t2 = mx;
      t3 = mn > t3 ? mn : t3;
      mx = k1 > t0 ? k1 : t0; mn = k1 > t0 ? t0 : k1; t0 = mx;
      mx = mn > t1 ? mn : t1; mn = mn > t1 ? t1 : mn; t1 = mx;
      mx = mn > t2 ? mn : t2; mn = mn > t2 ? t2 : mn; t2 = mx;
      t3 = mn > t3 ? mn : t3;
    }
    // MSB radix with capped (top-4) ballot counts -> tau (<= true 40th key)
    unsigned tau = 0;
    for (int bit = 15; bit >= 0; --bit) {
      unsigned cnd = tau | (1u << bit);
      int tot = __popcll(__ballot(t0 >= cnd)) + __popcll(__ballot(t1 >= cnd)) +
                __popcll(__ballot(t2 >= cnd)) + __popcll(__ballot(t3 >= cnd));
      if (tot >= CANDT) tau = cnd;
    }
    // hit mask from regs + prefix scan
    unsigned mask = 0;
#pragma unroll
    for (int g = 0; g < 16; ++g) {
      mask |= ((keys32[g] & 0xffffu) >= tau ? 1u : 0u) << (2 * g);
      mask |= ((keys32[g] >> 16) >= tau ? 1u : 0u) << (2 * g + 1);
    }
    int myc = __popc(mask);
    int pre = myc;
#pragma unroll
    for (int off = 1; off < 64; off <<= 1) {
      int o = __shfl_up(pre, off, 64);
      pre += (lane >= off) ? o : 0;
    }
    int tot = __shfl(pre, 63, 64);
    if (tot > 64) {                                // cold exact-radix fallback
      tau = 0;
      for (int bit = 15; bit >= 0; --bit) {
        unsigned cnd = tau | (1u << bit);
        int cc = 0;
#pragma unroll
        for (int g = 0; g < 16; ++g) {
          cc += ((keys32[g] & 0xffffu) >= cnd) ? 1 : 0;
          cc += ((keys32[g] >> 16) >= cnd) ? 1 : 0;
        }
#pragma unroll
        for (int off = 1; off < 64; off <<= 1) cc += __shfl_xor(cc, off, 64);
        if (cc >= CANDT) tau = cnd;
      }
      mask = 0;
#pragma unroll
      for (int g = 0; g < 16; ++g) {
        mask |= ((keys32[g] & 0xffffu) >= tau ? 1u : 0u) << (2 * g);
        mask |= ((keys32[g] >> 16) >= tau ? 1u : 0u) << (2 * g + 1);
      }
      myc = __popc(mask);
      pre = myc;
#pragma unroll
      for (int off = 1; off < 64; off <<= 1) {
        int o = __shfl_up(pre, off, 64);
        pre += (lane >= off) ? o : 0;
      }
      tot = __shfl(pre, 63, 64);
    }
    // ctz-bitmask compaction
    {
      int slot = pre - myc;
      unsigned m2 = mask;
      while (m2) {
        int bp = __builtin_ctz(m2); m2 &= m2 - 1;
        if (slot < 64) Cj[w * 64 + slot] = lane * 2 + ((bp >> 1) << 7) + (bp & 1);
        ++slot;
      }
    }
    int cnt = tot > 64 ? 64 : tot;
    int j = Cj[w * 64 + (lane < cnt ? lane : 0)];
    // fp64 rescore (accumulation order identical to R3..R8)
    const float* xi = xTfb + (size_t)irow * CC;
    const float* xj = xTfb + (size_t)j * CC;
    double d0 = 0, d1 = 0, d2 = 0, d3 = 0;
#pragma unroll
    for (int c = 0; c < CC; c += 4) {
      float4 fi = *(const float4*)(xi + c);
      float4 fj = *(const float4*)(xj + c);
      d0 = fma((double)fi.x, (double)fj.x, d0);
      d1 = fma((double)fi.y, (double)fj.y, d1);
      d2 = fma((double)fi.z, (double)fj.z, d2);
      d3 = fma((double)fi.w, (double)fj.w, d3);
    }
    double sc = 2.0 * ((d0 + d1) + (d2 + d3)) - xxb[j];
    // rank via LDS broadcast reads
    Sd[w * 64 + lane] = sc;
    int rank = 0;
#pragma unroll 4
    for (int mm = 0; mm < cnt; ++mm) {
      double sm = Sd[w * 64 + mm];
      int jm = Cj[w * 64 + mm];
      rank += (sm > sc || (sm == sc && jm < j)) ? 1 : 0;
    }
    if (lane < cnt && rank < KK)
      idx[(size_t)((b << 11) + irow) * KK + rank] = j;
  }
}

// ---------------------------------------------------------------------------
// k_pq: P[pt][o] = W1.x, Q[pt][o] = (W2-W1).x  (fp32 VALU, LDS transpose).
// ---------------------------------------------------------------------------
__global__ __launch_bounds__(256) void k_pq(const float* __restrict__ x,
                                            const float* __restrict__ W,
                                            float* __restrict__ P,
                                            float* __restrict__ Q) {
  __shared__ float tile[64][OO + 1];
  const int t = threadIdx.x;
  const int jj = t & 63, og = t >> 6;
  const int pt0 = blockIdx.x * 64;
  const int b = pt0 >> 11;
  const int jn = (pt0 & (NN - 1)) + jj;

  float xcol[CC];
#pragma unroll
  for (int c = 0; c < CC; ++c) xcol[c] = x[((size_t)(b * CC + c) << 11) + jn];

  for (int oo = 0; oo < 32; ++oo) {
    int o = og * 32 + oo;
    const float* wr = W + (size_t)o * (2 * CC);
    float sp = 0.f;
#pragma unroll
    for (int c = 0; c < CC; ++c) sp = fmaf(wr[c], xcol[c], sp);
    tile[jj][o] = sp;
  }
  __syncthreads();
  for (int it = 0; it < 32; ++it) {
    int r = it * 2 + (t >> 7);
    P[((size_t)(pt0 + r)) * OO + (t & 127)] = tile[r][t & 127];
  }
  __syncthreads();
  for (int oo = 0; oo < 32; ++oo) {
    int o = og * 32 + oo;
    const float* wr = W + (size_t)o * (2 * CC);
    float sq = 0.f;
#pragma unroll
    for (int c = 0; c < CC; ++c) sq = fmaf(wr[CC + c] - wr[c], xcol[c], sq);
    tile[jj][o] = sq;
  }
  __syncthreads();
  for (int it = 0; it < 32; ++it) {
    int r = it * 2 + (t >> 7);
    Q[((size_t)(pt0 + r)) * OO + (t & 127)] = tile[r][t & 127];
  }
}

// ---------------------------------------------------------------------------
// k_tail (cooperative, 512 blocks x 256 thr, 2 blocks/CU — wide residency
// margin): Phase 1 gather-stats keeping vmax/vmin of its 32 pts IN REGISTERS;
// grid.sync; Phase 2: 128 o-blocks reduce 512 partials -> ss (scale/shift);
// grid.sync; Phase 3: BN+exact-GELU on register vmax/vmin -> LDS transpose
// -> out[b][o][n]. Replaces k_stats+k_fin1+k_fin2+k_out and the 32MB
// vmax/vmin HBM round-trip. All reductions fixed-order (deterministic).
// ---------------------------------------------------------------------------
__global__ __launch_bounds__(256, 4) void k_tail(
    const float* __restrict__ P, const float* __restrict__ Q,
    const int* __restrict__ idx, float* __restrict__ partial,
    float* __restrict__ ss, const float* __restrict__ gamma,
    const float* __restrict__ beta, float* __restrict__ out) {
  __shared__ float red[2][256];
  __shared__ float tile[32][OO + 1];               // 16.5KB
  const int t = threadIdx.x;
  const int o = t & 127, half = t >> 7;
  const int bid = (blockIdx.x & 7) * 64 + (blockIdx.x >> 3);  // batch/XCD
  const int pt0 = bid * 32;
  const int b = pt0 >> 11;

  // ---- Phase 1: gather stats; vmax/vmin stay in regs ----
  float vmx[16], vmn[16];
  float s = 0.f, s2 = 0.f;
#pragma unroll
  for (int it = 0; it < 16; ++it) {
    int pt = pt0 + it * 2 + half;
    float qv = Q[(size_t)pt * OO + o];
    const int* ip = idx + (size_t)pt * KK;
    float vmax = -3.0e38f, vmin = 3.0e38f;
#pragma unroll
    for (int k = 0; k < KK; ++k) {
      float v = P[((size_t)((b << 11) + ip[k])) * OO + o] + qv;
      s += v;
      s2 = fmaf(v, v, s2);
      vmax = fmaxf(vmax, v);
      vmin = fminf(vmin, v);
    }
    vmx[it] = vmax; vmn[it] = vmin;
  }
  red[0][t] = s; red[1][t] = s2;
  __syncthreads();
  if (t < 128) {
    partial[bid * 128 + o]               = red[0][t] + red[0][t + 128];
    partial[NPART * 128 + bid * 128 + o] = red[1][t] + red[1][t + 128];
  }
  __threadfence();
  cg::this_grid().sync();

  // ---- Phase 2: blocks 0..127 reduce their o across 512 partials ----
  if (blockIdx.x < 128) {
    const int oo = blockIdx.x;
    float a  = partial[(size_t)(t * 2) * 128 + oo] +
               partial[(size_t)(t * 2 + 1) * 128 + oo];
    float a2 = partial[(size_t)NPART * 128 + (size_t)(t * 2) * 128 + oo] +
               partial[(size_t)NPART * 128 + (size_t)(t * 2 + 1) * 128 + oo];
    __syncthreads();                               // red[] reuse safety
    red[0][t] = a; red[1][t] = a2;
    __syncthreads();
    for (int st = 128; st >= 1; st >>= 1) {
      if (t < st) { red[0][t] += red[0][t + st]; red[1][t] += red[1][t + st]; }
      __syncthreads();
    }
    if (t == 0) {
      float mean = red[0][0] * (1.0f / M_TOT);
      float var  = red[1][0] * (1.0f / M_TOT) - mean * mean;
      float rs = 1.0f / sqrtf(var + 1e-5f);
      float scale = gamma[oo] * rs;
      ss[oo] = scale;
      ss[128 + oo] = beta[oo] - mean * scale;
    }
  }
  __threadfence();
  cg::this_grid().sync();

  // ---- Phase 3: BN + exact GELU on register vmax/vmin -> out ----
  const float scale = ss[o], shift = ss[128 + o];
  const float inv_sqrt2 = 0.70710678118654752f;
#pragma unroll
  for (int it = 0; it < 16; ++it) {
    int pl = it * 2 + half;
    float vmax = vmx[it], vmin = vmn[it];
    float ymax, ymin;
    if (scale >= 0.f) { ymax = fmaf(vmax, scale, shift); ymin = fmaf(vmin, scale, shift); }
    else              { ymax = fmaf(vmin, scale, shift); ymin = fmaf(vmax, scale, shift); }
    float g;
    if (ymax > 0.f) {
      g = 0.5f * ymax * (1.0f + erff(ymax * inv_sqrt2));
    } else {
      float g1 = 0.5f * ymax * (1.0f + erff(ymax * inv_sqrt2));
      float g2 = 0.5f * ymin * (1.0f + erff(ymin * inv_sqrt2));
      g = fmaxf(g1, g2);
    }
    tile[pl][o] = g;
  }
  __syncthreads();
  const int n0 = pt0 & (NN - 1);
  for (int rep = 0; rep < 16; ++rep) {
    int oo2 = rep * 8 + (t >> 5);
    int nn = t & 31;
    out[((size_t)(b * OO + oo2) << 11) + n0 + nn] = tile[nn][oo2];
  }
}

// ---------------------------------------------------------------------------
extern "C" void kernel_launch(void* const* d_in, const int* in_sizes, int n_in,
                              void* d_out, int out_size, void* d_ws, size_t ws_size,
                              hipStream_t stream) {
  const float* x     = (const float*)d_in[0];
  const float* W     = (const float*)d_in[1];
  const float* gamma = (const float*)d_in[2];
  const float* beta  = (const float*)d_in[3];
  float* out = (float*)d_out;

  // ws layout (~18.7 MB; R1 proved >=18.4 MB works):
  double* xx   = (double*)d_ws;                        // 131072 B
  int*    idxp = (int*)(xx + BB * NN);                 // 1310720 B
  float*  part = (float*)(idxp + (size_t)BB * NN * KK);// 2*512*128*4 = 512KB
  float*  ss   = part + 2 * NPART * 128;               // 1024 B
  float*  P    = ss + 256;                             // 8 MB
  float*  Q    = P + (size_t)BB * NN * OO;             // 8 MB
  // aliases consumed by k_knn before k_pq writes P/Q:
  ushort* xT   = (ushort*)P;                           // 2 MB
  float*  xTf  = P + (size_t)BB * NN * (CC / 2);       // 4 MB
  float*  xxf  = Q;                                    // 64 KB

  const int knn_lds = 32 * NN * 2 + 4096 + 8192;       // 143360 B
  hipFuncSetAttribute((const void*)k_knn,
                      hipFuncAttributeMaxDynamicSharedMemorySize, knn_lds);

  hipLaunchKernelGGL(k_prep, dim3(BB * NN / 256), dim3(256), 0, stream,
                     x, xT, xTf, xx, xxf);
  hipLaunchKernelGGL(k_knn, dim3(BB * NN / 32), dim3(1024), knn_lds, stream,
                     xT, xxf, xTf, xx, idxp);
  hipLaunchKernelGGL(k_pq, dim3(BB * NN / 64), dim3(256), 0, stream, x, W, P, Q);

  const float* Pc = P; const float* Qc = Q; const int* idxc = idxp;
  void* args[] = {(void*)&Pc, (void*)&Qc, (void*)&idxc, (void*)&part,
                  (void*)&ss, (void*)&gamma, (void*)&beta, (void*)&out};
  hipLaunchCooperativeKernel((void*)k_tail, dim3(NPART), dim3(256), args, 0, stream);
}

// Round 10
// 180.491 us; speedup vs baseline: 2.3578x; 2.3578x over previous
//
#include <hip/hip_runtime.h>
#include <math.h>

#define BB 8
#define CC 64
#define NN 2048
#define KK 20
#define OO 128
#define CANDT 40
#define NPART 1024
#define NRED 64
#define M_TOT 327680.0f    // B*N*K

typedef __attribute__((ext_vector_type(8))) __bf16 bf8v;
typedef __attribute__((ext_vector_type(16))) float f32x16;

// ---------------------------------------------------------------------------
// k_pqprep (Path A): P/Q GEMMs + bf16 xT rows + f32 xTf rows + xx/xxf norms.
// 32-pt blocks (512 blocks -> 2 waves/SIMD makespan).
// ---------------------------------------------------------------------------
__global__ __launch_bounds__(256) void k_pqprep(const float* __restrict__ x,
                                                const float* __restrict__ W,
                                                float* __restrict__ P,
                                                float* __restrict__ Q,
                                                ushort* __restrict__ xT,
                                                float* __restrict__ xTf,
                                                double* __restrict__ xx,
                                                float* __restrict__ xxf) {
  __shared__ float tile[32][OO + 1];               // 16.5KB
  const int t = threadIdx.x;
  const int jj = t & 31, og = t >> 5;              // 8 o-groups of 16
  const int pt0 = blockIdx.x * 32;
  const int b = pt0 >> 11;
  const int jn = (pt0 & (NN - 1)) + jj;

  float xcol[CC];
#pragma unroll
  for (int c = 0; c < CC; ++c) xcol[c] = x[((size_t)(b * CC + c) << 11) + jn];

  if (t < 32) {                                    // prep outputs
    int i = pt0 + t;
    ushort* rowp = xT + (size_t)i * CC;
    float* rowf = xTf + (size_t)i * CC;
    double s = 0.0;
#pragma unroll
    for (int c8 = 0; c8 < 8; ++c8) {
      unsigned tmp[8];
#pragma unroll
      for (int e = 0; e < 8; ++e) {
        float v = xcol[c8 * 8 + e];
        double dv = (double)v; s = fma(dv, dv, s);
        __bf16 h = (__bf16)v;
        ushort us; __builtin_memcpy(&us, &h, 2);
        tmp[e] = us;
      }
      uint4 pk;
      pk.x = tmp[0] | (tmp[1] << 16);
      pk.y = tmp[2] | (tmp[3] << 16);
      pk.z = tmp[4] | (tmp[5] << 16);
      pk.w = tmp[6] | (tmp[7] << 16);
      *(uint4*)(rowp + c8 * 8) = pk;
      *(float4*)(rowf + c8 * 8)     = make_float4(xcol[c8*8], xcol[c8*8+1], xcol[c8*8+2], xcol[c8*8+3]);
      *(float4*)(rowf + c8 * 8 + 4) = make_float4(xcol[c8*8+4], xcol[c8*8+5], xcol[c8*8+6], xcol[c8*8+7]);
    }
    xx[i] = s;
    xxf[i] = (float)s;
  }

  for (int oo = 0; oo < 16; ++oo) {
    int o = og * 16 + oo;
    const float* wr = W + (size_t)o * (2 * CC);
    float sp = 0.f;
#pragma unroll
    for (int c = 0; c < CC; ++c) sp = fmaf(wr[c], xcol[c], sp);
    tile[jj][o] = sp;
  }
  __syncthreads();
  for (int it = 0; it < 16; ++it) {
    int r = it * 2 + (t >> 7);
    P[((size_t)(pt0 + r)) * OO + (t & 127)] = tile[r][t & 127];
  }
  __syncthreads();
  for (int oo = 0; oo < 16; ++oo) {
    int o = og * 16 + oo;
    const float* wr = W + (size_t)o * (2 * CC);
    float sq = 0.f;
#pragma unroll
    for (int c = 0; c < CC; ++c) sq = fmaf(wr[CC + c] - wr[c], xcol[c], sq);
    tile[jj][o] = sq;
  }
  __syncthreads();
  for (int it = 0; it < 16; ++it) {
    int r = it * 2 + (t >> 7);
    Q[((size_t)(pt0 + r)) * OO + (t & 127)] = tile[r][t & 127];
  }
}

// ---------------------------------------------------------------------------
// k_prep (Path B fallback): standalone prep pass.
// ---------------------------------------------------------------------------
__global__ __launch_bounds__(256) void k_prep(const float* __restrict__ x,
                                              ushort* __restrict__ xT,
                                              float* __restrict__ xTf,
                                              double* __restrict__ xx,
                                              float* __restrict__ xxf) {
  int i = blockIdx.x * 256 + threadIdx.x;
  int b = i >> 11, n = i & (NN - 1);
  const float* p = x + ((size_t)b * CC) * NN + n;
  ushort* rowp = xT + (size_t)i * CC;
  float* rowf = xTf + (size_t)i * CC;
  double s = 0.0;
#pragma unroll
  for (int c8 = 0; c8 < 8; ++c8) {
    float f[8];
    unsigned tmp[8];
#pragma unroll
    for (int e = 0; e < 8; ++e) {
      float v = p[(size_t)(c8 * 8 + e) * NN];
      f[e] = v;
      double dv = (double)v; s = fma(dv, dv, s);
      __bf16 h = (__bf16)v;
      ushort us; __builtin_memcpy(&us, &h, 2);
      tmp[e] = us;
    }
    uint4 pk;
    pk.x = tmp[0] | (tmp[1] << 16);
    pk.y = tmp[2] | (tmp[3] << 16);
    pk.z = tmp[4] | (tmp[5] << 16);
    pk.w = tmp[6] | (tmp[7] << 16);
    *(uint4*)(rowp + c8 * 8) = pk;
    *(float4*)(rowf + c8 * 8)     = make_float4(f[0], f[1], f[2], f[3]);
    *(float4*)(rowf + c8 * 8 + 4) = make_float4(f[4], f[5], f[6], f[7]);
  }
  xx[i] = s;
  xxf[i] = (float)s;
}

// ---------------------------------------------------------------------------
// k_pq (Path B fallback): P/Q GEMMs only.
// ---------------------------------------------------------------------------
__global__ __launch_bounds__(256) void k_pq(const float* __restrict__ x,
                                            const float* __restrict__ W,
                                            float* __restrict__ P,
                                            float* __restrict__ Q) {
  __shared__ float tile[64][OO + 1];
  const int t = threadIdx.x;
  const int jj = t & 63, og = t >> 6;
  const int pt0 = blockIdx.x * 64;
  const int b = pt0 >> 11;
  const int jn = (pt0 & (NN - 1)) + jj;

  float xcol[CC];
#pragma unroll
  for (int c = 0; c < CC; ++c) xcol[c] = x[((size_t)(b * CC + c) << 11) + jn];

  for (int oo = 0; oo < 32; ++oo) {
    int o = og * 32 + oo;
    const float* wr = W + (size_t)o * (2 * CC);
    float sp = 0.f;
#pragma unroll
    for (int c = 0; c < CC; ++c) sp = fmaf(wr[c], xcol[c], sp);
    tile[jj][o] = sp;
  }
  __syncthreads();
  for (int it = 0; it < 32; ++it) {
    int r = it * 2 + (t >> 7);
    P[((size_t)(pt0 + r)) * OO + (t & 127)] = tile[r][t & 127];
  }
  __syncthreads();
  for (int oo = 0; oo < 32; ++oo) {
    int o = og * 32 + oo;
    const float* wr = W + (size_t)o * (2 * CC);
    float sq = 0.f;
#pragma unroll
    for (int c = 0; c < CC; ++c) sq = fmaf(wr[CC + c] - wr[c], xcol[c], sq);
    tile[jj][o] = sq;
  }
  __syncthreads();
  for (int it = 0; it < 32; ++it) {
    int r = it * 2 + (t >> 7);
    Q[((size_t)(pt0 + r)) * OO + (t & 127)] = tile[r][t & 127];
  }
}

// ---------------------------------------------------------------------------
// k_knn (R9 version — R4 structure + u16-key micro-opts). 512 blocks x 1024
// thr; 32 rows/block; 32x32x16 MFMA; selection 2 rows/wave.
// ---------------------------------------------------------------------------
__global__ __launch_bounds__(1024, 4) void k_knn(
    const ushort* __restrict__ xT, const float* __restrict__ xxf,
    const float* __restrict__ xTf, const double* __restrict__ xx,
    int* __restrict__ idx) {
  extern __shared__ char smem[];
  ushort (*Sb)[NN] = (ushort(*)[NN])smem;          // [32][2048] u16 keys 128KB
  int* Cj = (int*)(smem + 32 * NN * 2);            // [16][64] 4KB
  double* Sd = (double*)(smem + 32 * NN * 2 + 4096); // [16][64] 8KB
  const int t = threadIdx.x;
  const int w = t >> 6, lane = t & 63;
  const int bidswz = ((blockIdx.x & 7) << 6) + (blockIdx.x >> 3); // batch/XCD
  const int b = bidswz >> 6;
  const int i0 = (bidswz & 63) << 5;
  const int lr = lane & 31, lh = lane >> 5;
  const ushort* xTb = xT + (((size_t)b) << 11) * CC;

  // ---- Phase A: MFMA 32x32x16 ----
  f32x16 acc[4];
#pragma unroll
  for (int tt = 0; tt < 4; ++tt)
#pragma unroll
    for (int q = 0; q < 16; ++q) acc[tt][q] = 0.f;

  const ushort* Ap = xTb + (size_t)(i0 + lr) * CC + lh * 8;
  bf8v a0 = *(const bf8v*)(Ap);
  bf8v a1 = *(const bf8v*)(Ap + 16);
  bf8v a2 = *(const bf8v*)(Ap + 32);
  bf8v a3 = *(const bf8v*)(Ap + 48);
  const int j0w = w << 7;
#pragma unroll
  for (int tt = 0; tt < 4; ++tt) {
    const ushort* Bp = xTb + (size_t)(j0w + tt * 32 + lr) * CC + lh * 8;
    bf8v b0 = *(const bf8v*)(Bp);
    bf8v b1 = *(const bf8v*)(Bp + 16);
    bf8v b2 = *(const bf8v*)(Bp + 32);
    bf8v b3 = *(const bf8v*)(Bp + 48);
    acc[tt] = __builtin_amdgcn_mfma_f32_32x32x16_bf16(a0, b0, acc[tt], 0, 0, 0);
    acc[tt] = __builtin_amdgcn_mfma_f32_32x32x16_bf16(a1, b1, acc[tt], 0, 0, 0);
    acc[tt] = __builtin_amdgcn_mfma_f32_32x32x16_bf16(a2, b2, acc[tt], 0, 0, 0);
    acc[tt] = __builtin_amdgcn_mfma_f32_32x32x16_bf16(a3, b3, acc[tt], 0, 0, 0);
  }

  // ---- Phase B: f32 score -> monotone u16 key -> LDS ----
  const float* xxfb = xxf + (b << 11);
#pragma unroll
  for (int tt = 0; tt < 4; ++tt) {
    int j = j0w + tt * 32 + lr;
    float xv = xxfb[j];
#pragma unroll
    for (int q = 0; q < 16; ++q) {
      int rr = (q & 3) + 8 * (q >> 2) + 4 * lh;    // 32x32 C/D map (m74/m101)
      float sv = fmaf(2.f, acc[tt][q], -xv);
      unsigned u = __float_as_uint(sv);
      u ^= (0x80000000u | (unsigned)((int)u >> 31)); // monotone u32
      Sb[rr][j] = (ushort)(u >> 16);
    }
  }
  __syncthreads();

  // ---- Phase C: 2 rows per wave ----
  const float* xTfb = xTf + (((size_t)b) << 11) * CC;
  const double* xxb = xx + (b << 11);
#pragma unroll 1
  for (int rw = 0; rw < 2; ++rw) {
    const int rr = w + 16 * rw;
    const int irow = i0 + rr;
    unsigned keys32[16];
    unsigned t0 = 0, t1 = 0, t2 = 0, t3 = 0;
#pragma unroll
    for (int g = 0; g < 16; ++g) {
      unsigned raw = *(const unsigned*)(&Sb[rr][lane * 2 + g * 128]);
      keys32[g] = raw;
      unsigned k0 = raw & 0xffffu, k1 = raw >> 16;
      unsigned mx, mn;
      mx = k0 > t0 ? k0 : t0; mn = k0 > t0 ? t0 : k0; t0 = mx;
      mx = mn > t1 ? mn : t1; mn = mn > t1 ? t1 : mn; t1 = mx;
      mx = mn > t2 ? mn : t2; mn = mn > t2 ? t2 : mn; t2 = mx;
      t3 = mn > t3 ? mn : t3;
      mx = k1 > t0 ? k1 : t0; mn = k1 > t0 ? t0 : k1; t0 = mx;
      mx = mn > t1 ? mn : t1; mn = mn > t1 ? t1 : mn; t1 = mx;
      mx = mn > t2 ? mn : t2; mn = mn > t2 ? t2 : mn; t2 = mx;
      t3 = mn > t3 ? mn : t3;
    }
    unsigned tau = 0;
    for (int bit = 15; bit >= 0; --bit) {
      unsigned cnd = tau | (1u << bit);
      int tot = __popcll(__ballot(t0 >= cnd)) + __popcll(__ballot(t1 >= cnd)) +
                __popcll(__ballot(t2 >= cnd)) + __popcll(__ballot(t3 >= cnd));
      if (tot >= CANDT) tau = cnd;
    }
    unsigned mask = 0;
#pragma unroll
    for (int g = 0; g < 16; ++g) {
      mask |= ((keys32[g] & 0xffffu) >= tau ? 1u : 0u) << (2 * g);
      mask |= ((keys32[g] >> 16) >= tau ? 1u : 0u) << (2 * g + 1);
    }
    int myc = __popc(mask);
    int pre = myc;
#pragma unroll
    for (int off = 1; off < 64; off <<= 1) {
      int o = __shfl_up(pre, off, 64);
      pre += (lane >= off) ? o : 0;
    }
    int tot = __shfl(pre, 63, 64);
    if (tot > 64) {                                // cold exact-radix fallback
      tau = 0;
      for (int bit = 15; bit >= 0; --bit) {
        unsigned cnd = tau | (1u << bit);
        int cc = 0;
#pragma unroll
        for (int g = 0; g < 16; ++g) {
          cc += ((keys32[g] & 0xffffu) >= cnd) ? 1 : 0;
          cc += ((keys32[g] >> 16) >= cnd) ? 1 : 0;
        }
#pragma unroll
        for (int off = 1; off < 64; off <<= 1) cc += __shfl_xor(cc, off, 64);
        if (cc >= CANDT) tau = cnd;
      }
      mask = 0;
#pragma unroll
      for (int g = 0; g < 16; ++g) {
        mask |= ((keys32[g] & 0xffffu) >= tau ? 1u : 0u) << (2 * g);
        mask |= ((keys32[g] >> 16) >= tau ? 1u : 0u) << (2 * g + 1);
      }
      myc = __popc(mask);
      pre = myc;
#pragma unroll
      for (int off = 1; off < 64; off <<= 1) {
        int o = __shfl_up(pre, off, 64);
        pre += (lane >= off) ? o : 0;
      }
      tot = __shfl(pre, 63, 64);
    }
    {
      int slot = pre - myc;
      unsigned m2 = mask;
      while (m2) {
        int bp = __builtin_ctz(m2); m2 &= m2 - 1;
        if (slot < 64) Cj[w * 64 + slot] = lane * 2 + ((bp >> 1) << 7) + (bp & 1);
        ++slot;
      }
    }
    int cnt = tot > 64 ? 64 : tot;
    int j = Cj[w * 64 + (lane < cnt ? lane : 0)];
    const float* xi = xTfb + (size_t)irow * CC;
    const float* xj = xTfb + (size_t)j * CC;
    double d0 = 0, d1 = 0, d2 = 0, d3 = 0;
#pragma unroll
    for (int c = 0; c < CC; c += 4) {
      float4 fi = *(const float4*)(xi + c);
      float4 fj = *(const float4*)(xj + c);
      d0 = fma((double)fi.x, (double)fj.x, d0);
      d1 = fma((double)fi.y, (double)fj.y, d1);
      d2 = fma((double)fi.z, (double)fj.z, d2);
      d3 = fma((double)fi.w, (double)fj.w, d3);
    }
    double sc = 2.0 * ((d0 + d1) + (d2 + d3)) - xxb[j];
    Sd[w * 64 + lane] = sc;
    int rank = 0;
#pragma unroll 4
    for (int mm = 0; mm < cnt; ++mm) {
      double sm = Sd[w * 64 + mm];
      int jm = Cj[w * 64 + mm];
      rank += (sm > sc || (sm == sc && jm < j)) ? 1 : 0;
    }
    if (lane < cnt && rank < KK)
      idx[(size_t)((b << 11) + irow) * KK + rank] = j;
  }
}

// ---------------------------------------------------------------------------
// k_stats: per-o sum & sumsq of h = P[gather]+Q (+ optional vmax/vmin emit).
// 1024 blocks x 16 pts; one batch per XCD (bid swizzle) for P-slab L2 locality.
// ---------------------------------------------------------------------------
__global__ __launch_bounds__(256) void k_stats(const float* __restrict__ P,
                                               const float* __restrict__ Q,
                                               const int* __restrict__ idx,
                                               float* __restrict__ partial,
                                               float* __restrict__ vmaxA,
                                               float* __restrict__ vminA) {
  const int t = threadIdx.x;
  const int o = t & 127, half = t >> 7;
  const int bid = (blockIdx.x & 7) * 128 + (blockIdx.x >> 3);
  float s = 0.f, s2 = 0.f;
  for (int it = 0; it < 8; ++it) {
    int pt = bid * 16 + it * 2 + half;
    int b = pt >> 11;
    float qv = Q[(size_t)pt * OO + o];
    const int* ip = idx + (size_t)pt * KK;
    float vmax = -3.0e38f, vmin = 3.0e38f;
#pragma unroll
    for (int k = 0; k < KK; ++k) {
      float v = P[((size_t)((b << 11) + ip[k])) * OO + o] + qv;
      s += v;
      s2 = fmaf(v, v, s2);
      vmax = fmaxf(vmax, v);
      vmin = fminf(vmin, v);
    }
    if (vmaxA) {
      vmaxA[(size_t)pt * OO + o] = vmax;
      vminA[(size_t)pt * OO + o] = vmin;
    }
  }
  __shared__ float red[512];
  red[t] = s; red[256 + t] = s2;
  __syncthreads();
  if (t < 128) {
    partial[bid * 128 + o]               = red[t] + red[t + 128];
    partial[NPART * 128 + bid * 128 + o] = red[256 + t] + red[256 + t + 128];
  }
}

// ---------------------------------------------------------------------------
// k_fin1 / k_fin2: two-stage BN finalize.
// ---------------------------------------------------------------------------
__global__ __launch_bounds__(256) void k_fin1(const float* __restrict__ partial,
                                              float* __restrict__ part2) {
  __shared__ float red[512];
  const int t = threadIdx.x;
  const int o = t & 127, h = t >> 7;
  const int r = blockIdx.x;
  float s = 0.f, s2 = 0.f;
  for (int q = h; q < NPART / NRED; q += 2) {
    int blk = r * (NPART / NRED) + q;
    s  += partial[blk * 128 + o];
    s2 += partial[NPART * 128 + blk * 128 + o];
  }
  red[t] = s; red[256 + t] = s2;
  __syncthreads();
  if (t < 128) {
    part2[r * 128 + o]              = red[t] + red[t + 128];
    part2[NRED * 128 + r * 128 + o] = red[256 + t] + red[256 + t + 128];
  }
}

__global__ __launch_bounds__(256) void k_fin2(const float* __restrict__ part2,
                                              const float* __restrict__ gamma,
                                              const float* __restrict__ beta,
                                              float* __restrict__ ss) {
  __shared__ float red[512];
  int t = threadIdx.x;
  int o = t & 127, h = t >> 7;
  float s = 0.f, s2 = 0.f;
  for (int blk = h; blk < NRED; blk += 2) {
    s  += part2[blk * 128 + o];
    s2 += part2[NRED * 128 + blk * 128 + o];
  }
  red[t] = s; red[256 + t] = s2;
  __syncthreads();
  if (t < 128) {
    float st  = red[t] + red[t + 128];
    float s2t = red[256 + t] + red[256 + t + 128];
    float mean = st * (1.0f / M_TOT);
    float var  = s2t * (1.0f / M_TOT) - mean * mean;
    float rs = 1.0f / sqrtf(var + 1e-5f);
    float scale = gamma[t] * rs;
    ss[t] = scale;
    ss[128 + t] = beta[t] - mean * scale;
  }
}

// ---------------------------------------------------------------------------
// k_out: BN affine -> exact GELU -> max over k -> out[b][o][n].
// use_minmax: stream vmax/vmin (no second gather); else gather P (fallback).
// ---------------------------------------------------------------------------
__global__ __launch_bounds__(256) void k_out(const float* __restrict__ P,
                                             const float* __restrict__ Q,
                                             const int* __restrict__ idx,
                                             const float* __restrict__ ss,
                                             const float* __restrict__ vmaxA,
                                             const float* __restrict__ vminA,
                                             int use_minmax,
                                             float* __restrict__ out) {
  __shared__ float tile[64][OO + 1];
  const int t = threadIdx.x;
  const int o = t & 127, half = t >> 7;
  const int bid = (blockIdx.x & 7) * 32 + (blockIdx.x >> 3);
  const float scale = ss[o], shift = ss[128 + o];
  const int pt0 = bid * 64;
  const int b = pt0 >> 11;
  const float inv_sqrt2 = 0.70710678118654752f;
  for (int it = 0; it < 32; ++it) {
    int pl = it * 2 + half;
    int pt = pt0 + pl;
    float vmax, vmin;
    if (use_minmax) {
      vmax = vmaxA[(size_t)pt * OO + o];
      vmin = vminA[(size_t)pt * OO + o];
    } else {
      float qv = Q[(size_t)pt * OO + o];
      const int* ip = idx + (size_t)pt * KK;
      vmax = -3.0e38f; vmin = 3.0e38f;
#pragma unroll
      for (int k = 0; k < KK; ++k) {
        float v = P[((size_t)((b << 11) + ip[k])) * OO + o] + qv;
        vmax = fmaxf(vmax, v);
        vmin = fminf(vmin, v);
      }
    }
    float ymax, ymin;
    if (scale >= 0.f) { ymax = fmaf(vmax, scale, shift); ymin = fmaf(vmin, scale, shift); }
    else              { ymax = fmaf(vmin, scale, shift); ymin = fmaf(vmax, scale, shift); }
    float g;
    if (ymax > 0.f) {
      g = 0.5f * ymax * (1.0f + erff(ymax * inv_sqrt2));
    } else {
      float g1 = 0.5f * ymax * (1.0f + erff(ymax * inv_sqrt2));
      float g2 = 0.5f * ymin * (1.0f + erff(ymin * inv_sqrt2));
      g = fmaxf(g1, g2);
    }
    tile[pl][o] = g;
  }
  __syncthreads();
  const int n0 = pt0 & (NN - 1);
  for (int rep = 0; rep < 32; ++rep) {
    int oo = rep * 4 + (t >> 6);
    int nn = t & 63;
    out[((size_t)(b * OO + oo) << 11) + n0 + nn] = tile[nn][oo];
  }
}

// ---------------------------------------------------------------------------
extern "C" void kernel_launch(void* const* d_in, const int* in_sizes, int n_in,
                              void* d_out, int out_size, void* d_ws, size_t ws_size,
                              hipStream_t stream) {
  const float* x     = (const float*)d_in[0];
  const float* W     = (const float*)d_in[1];
  const float* gamma = (const float*)d_in[2];
  const float* beta  = (const float*)d_in[3];
  float* out = (float*)d_out;

  const int knn_lds = 32 * NN * 2 + 4096 + 8192;       // 143360 B
  hipFuncSetAttribute((const void*)k_knn,
                      hipFuncAttributeMaxDynamicSharedMemorySize, knn_lds);

  const size_t needA = 131072 + 65536 + 1310720 + (size_t)2 * NPART * 128 * 4 +
                       (size_t)2 * NRED * 128 * 4 + 1024 + 4ull * 8388608;

  if (ws_size >= needA) {
    // Path A layout
    double* xx   = (double*)d_ws;                      // 131072 B
    float*  xxf  = (float*)(xx + BB * NN);             // 65536 B
    int*    idxp = (int*)(xxf + BB * NN);              // 1310720 B
    float*  part = (float*)(idxp + (size_t)BB * NN * KK); // 1 MB
    float*  part2= part + 2 * NPART * 128;             // 64 KB
    float*  ss   = part2 + 2 * NRED * 128;             // 1024 B
    float*  P    = ss + 256;                           // 8 MB
    float*  Q    = P + (size_t)BB * NN * OO;           // 8 MB
    float*  vmax = Q + (size_t)BB * NN * OO;           // 8 MB
    float*  vmin = vmax + (size_t)BB * NN * OO;        // 8 MB
    ushort* xT   = (ushort*)vmax;                      // 2 MB alias (pre-stats)
    float*  xTf  = vmax + (size_t)BB * NN * (CC / 2);  // 4 MB alias

    hipLaunchKernelGGL(k_pqprep, dim3(BB * NN / 32), dim3(256), 0, stream,
                       x, W, P, Q, xT, xTf, xx, xxf);
    hipLaunchKernelGGL(k_knn, dim3(BB * NN / 32), dim3(1024), knn_lds, stream,
                       xT, xxf, xTf, xx, idxp);
    hipLaunchKernelGGL(k_stats, dim3(NPART), dim3(256), 0, stream,
                       P, Q, idxp, part, vmax, vmin);
    hipLaunchKernelGGL(k_fin1, dim3(NRED), dim3(256), 0, stream, part, part2);
    hipLaunchKernelGGL(k_fin2, dim3(1), dim3(256), 0, stream, part2, gamma, beta, ss);
    hipLaunchKernelGGL(k_out, dim3(BB * NN / 64), dim3(256), 0, stream,
                       P, Q, idxp, ss, vmax, vmin, 1, out);
  } else {
    // Path B layout
    double* xx   = (double*)d_ws;
    int*    idxp = (int*)(xx + BB * NN);
    float*  P    = (float*)(idxp + (size_t)BB * NN * KK);
    float*  Q    = P + (size_t)BB * NN * OO;
    float*  part = Q + (size_t)BB * NN * OO;
    float*  part2= part + 2 * NPART * 128;
    float*  ss   = part2 + 2 * NRED * 128;
    ushort* xT   = (ushort*)P;
    float*  xTf  = P + (size_t)BB * NN * (CC / 2);
    float*  xxf  = Q;

    hipLaunchKernelGGL(k_prep, dim3(BB * NN / 256), dim3(256), 0, stream,
                       x, xT, xTf, xx, xxf);
    hipLaunchKernelGGL(k_knn, dim3(BB * NN / 32), dim3(1024), knn_lds, stream,
                       xT, xxf, xTf, xx, idxp);
    hipLaunchKernelGGL(k_pq, dim3(BB * NN / 64), dim3(256), 0, stream, x, W, P, Q);
    hipLaunchKernelGGL(k_stats, dim3(NPART), dim3(256), 0, stream,
                       P, Q, idxp, part, (float*)nullptr, (float*)nullptr);
    hipLaunchKernelGGL(k_fin1, dim3(NRED), dim3(256), 0, stream, part, part2);
    hipLaunchKernelGGL(k_fin2, dim3(1), dim3(256), 0, stream, part2, gamma, beta, ss);
    hipLaunchKernelGGL(k_out, dim3(BB * NN / 64), dim3(256), 0, stream,
                       P, Q, idxp, ss, (const float*)nullptr, (const float*)nullptr, 0, out);
  }
}

// Round 11
// 168.913 us; speedup vs baseline: 2.5194x; 1.0685x over previous
//
#include <hip/hip_runtime.h>
#include <math.h>

#define BB 8
#define CC 64
#define NN 2048
#define KK 20
#define OO 128
#define CANDT 40
#define NPART 1024
#define M_TOT 327680.0f    // B*N*K

typedef __attribute__((ext_vector_type(8))) __bf16 bf8v;
typedef __attribute__((ext_vector_type(16))) float f32x16;

// ---------------------------------------------------------------------------
// k_pqprep (Path A): P/Q GEMMs + bf16 xT rows + f32 xTf rows + xx/xxf norms.
// ---------------------------------------------------------------------------
__global__ __launch_bounds__(256) void k_pqprep(const float* __restrict__ x,
                                                const float* __restrict__ W,
                                                float* __restrict__ P,
                                                float* __restrict__ Q,
                                                ushort* __restrict__ xT,
                                                float* __restrict__ xTf,
                                                double* __restrict__ xx,
                                                float* __restrict__ xxf) {
  __shared__ float tile[32][OO + 1];               // 16.5KB
  const int t = threadIdx.x;
  const int jj = t & 31, og = t >> 5;              // 8 o-groups of 16
  const int pt0 = blockIdx.x * 32;
  const int b = pt0 >> 11;
  const int jn = (pt0 & (NN - 1)) + jj;

  float xcol[CC];
#pragma unroll
  for (int c = 0; c < CC; ++c) xcol[c] = x[((size_t)(b * CC + c) << 11) + jn];

  if (t < 32) {                                    // prep outputs
    int i = pt0 + t;
    ushort* rowp = xT + (size_t)i * CC;
    float* rowf = xTf + (size_t)i * CC;
    double s = 0.0;
#pragma unroll
    for (int c8 = 0; c8 < 8; ++c8) {
      unsigned tmp[8];
#pragma unroll
      for (int e = 0; e < 8; ++e) {
        float v = xcol[c8 * 8 + e];
        double dv = (double)v; s = fma(dv, dv, s);
        __bf16 h = (__bf16)v;
        ushort us; __builtin_memcpy(&us, &h, 2);
        tmp[e] = us;
      }
      uint4 pk;
      pk.x = tmp[0] | (tmp[1] << 16);
      pk.y = tmp[2] | (tmp[3] << 16);
      pk.z = tmp[4] | (tmp[5] << 16);
      pk.w = tmp[6] | (tmp[7] << 16);
      *(uint4*)(rowp + c8 * 8) = pk;
      *(float4*)(rowf + c8 * 8)     = make_float4(xcol[c8*8], xcol[c8*8+1], xcol[c8*8+2], xcol[c8*8+3]);
      *(float4*)(rowf + c8 * 8 + 4) = make_float4(xcol[c8*8+4], xcol[c8*8+5], xcol[c8*8+6], xcol[c8*8+7]);
    }
    xx[i] = s;
    xxf[i] = (float)s;
  }

  for (int oo = 0; oo < 16; ++oo) {
    int o = og * 16 + oo;
    const float* wr = W + (size_t)o * (2 * CC);
    float sp = 0.f;
#pragma unroll
    for (int c = 0; c < CC; ++c) sp = fmaf(wr[c], xcol[c], sp);
    tile[jj][o] = sp;
  }
  __syncthreads();
  for (int it = 0; it < 16; ++it) {
    int r = it * 2 + (t >> 7);
    P[((size_t)(pt0 + r)) * OO + (t & 127)] = tile[r][t & 127];
  }
  __syncthreads();
  for (int oo = 0; oo < 16; ++oo) {
    int o = og * 16 + oo;
    const float* wr = W + (size_t)o * (2 * CC);
    float sq = 0.f;
#pragma unroll
    for (int c = 0; c < CC; ++c) sq = fmaf(wr[CC + c] - wr[c], xcol[c], sq);
    tile[jj][o] = sq;
  }
  __syncthreads();
  for (int it = 0; it < 16; ++it) {
    int r = it * 2 + (t >> 7);
    Q[((size_t)(pt0 + r)) * OO + (t & 127)] = tile[r][t & 127];
  }
}

// ---------------------------------------------------------------------------
// k_prep (Path B fallback): standalone prep pass.
// ---------------------------------------------------------------------------
__global__ __launch_bounds__(256) void k_prep(const float* __restrict__ x,
                                              ushort* __restrict__ xT,
                                              float* __restrict__ xTf,
                                              double* __restrict__ xx,
                                              float* __restrict__ xxf) {
  int i = blockIdx.x * 256 + threadIdx.x;
  int b = i >> 11, n = i & (NN - 1);
  const float* p = x + ((size_t)b * CC) * NN + n;
  ushort* rowp = xT + (size_t)i * CC;
  float* rowf = xTf + (size_t)i * CC;
  double s = 0.0;
#pragma unroll
  for (int c8 = 0; c8 < 8; ++c8) {
    float f[8];
    unsigned tmp[8];
#pragma unroll
    for (int e = 0; e < 8; ++e) {
      float v = p[(size_t)(c8 * 8 + e) * NN];
      f[e] = v;
      double dv = (double)v; s = fma(dv, dv, s);
      __bf16 h = (__bf16)v;
      ushort us; __builtin_memcpy(&us, &h, 2);
      tmp[e] = us;
    }
    uint4 pk;
    pk.x = tmp[0] | (tmp[1] << 16);
    pk.y = tmp[2] | (tmp[3] << 16);
    pk.z = tmp[4] | (tmp[5] << 16);
    pk.w = tmp[6] | (tmp[7] << 16);
    *(uint4*)(rowp + c8 * 8) = pk;
    *(float4*)(rowf + c8 * 8)     = make_float4(f[0], f[1], f[2], f[3]);
    *(float4*)(rowf + c8 * 8 + 4) = make_float4(f[4], f[5], f[6], f[7]);
  }
  xx[i] = s;
  xxf[i] = (float)s;
}

// ---------------------------------------------------------------------------
// k_pq (Path B fallback): P/Q GEMMs only.
// ---------------------------------------------------------------------------
__global__ __launch_bounds__(256) void k_pq(const float* __restrict__ x,
                                            const float* __restrict__ W,
                                            float* __restrict__ P,
                                            float* __restrict__ Q) {
  __shared__ float tile[64][OO + 1];
  const int t = threadIdx.x;
  const int jj = t & 63, og = t >> 6;
  const int pt0 = blockIdx.x * 64;
  const int b = pt0 >> 11;
  const int jn = (pt0 & (NN - 1)) + jj;

  float xcol[CC];
#pragma unroll
  for (int c = 0; c < CC; ++c) xcol[c] = x[((size_t)(b * CC + c) << 11) + jn];

  for (int oo = 0; oo < 32; ++oo) {
    int o = og * 32 + oo;
    const float* wr = W + (size_t)o * (2 * CC);
    float sp = 0.f;
#pragma unroll
    for (int c = 0; c < CC; ++c) sp = fmaf(wr[c], xcol[c], sp);
    tile[jj][o] = sp;
  }
  __syncthreads();
  for (int it = 0; it < 32; ++it) {
    int r = it * 2 + (t >> 7);
    P[((size_t)(pt0 + r)) * OO + (t & 127)] = tile[r][t & 127];
  }
  __syncthreads();
  for (int oo = 0; oo < 32; ++oo) {
    int o = og * 32 + oo;
    const float* wr = W + (size_t)o * (2 * CC);
    float sq = 0.f;
#pragma unroll
    for (int c = 0; c < CC; ++c) sq = fmaf(wr[CC + c] - wr[c], xcol[c], sq);
    tile[jj][o] = sq;
  }
  __syncthreads();
  for (int it = 0; it < 32; ++it) {
    int r = it * 2 + (t >> 7);
    Q[((size_t)(pt0 + r)) * OO + (t & 127)] = tile[r][t & 127];
  }
}

// ---------------------------------------------------------------------------
// k_knn: R10 structure, phase C FUSED across the wave's two rows (w, w+16) —
// interleaved key scans / radix ballots / scans / rescores / rank loops give
// 2x per-wave ILP on the latency chains that left R10 at 38% VALUBusy.
// Selection math and fp64 rescore order bit-identical to R10.
// ---------------------------------------------------------------------------
#define TOP4(k, u0, u1, u2, u3) do { unsigned mx_, mn_;                 \
    mx_ = (k) > u0 ? (k) : u0; mn_ = (k) > u0 ? u0 : (k); u0 = mx_;     \
    mx_ = mn_ > u1 ? mn_ : u1; mn_ = mn_ > u1 ? u1 : mn_; u1 = mx_;     \
    mx_ = mn_ > u2 ? mn_ : u2; mn_ = mn_ > u2 ? u2 : mn_; u2 = mx_;     \
    u3 = mn_ > u3 ? mn_ : u3; } while (0)

#define EXACT_RADIX(keys, tau, mask, myc, pre, tot) do {                \
    tau = 0;                                                            \
    for (int bit_ = 15; bit_ >= 0; --bit_) {                            \
      unsigned cnd_ = tau | (1u << bit_);                               \
      int cc_ = 0;                                                      \
      _Pragma("unroll") for (int g_ = 0; g_ < 16; ++g_) {               \
        cc_ += ((keys[g_] & 0xffffu) >= cnd_) ? 1 : 0;                  \
        cc_ += ((keys[g_] >> 16) >= cnd_) ? 1 : 0;                      \
      }                                                                 \
      _Pragma("unroll") for (int off_ = 1; off_ < 64; off_ <<= 1)       \
        cc_ += __shfl_xor(cc_, off_, 64);                               \
      if (cc_ >= CANDT) tau = cnd_;                                     \
    }                                                                   \
    mask = 0;                                                           \
    _Pragma("unroll") for (int g_ = 0; g_ < 16; ++g_) {                 \
      mask |= ((keys[g_] & 0xffffu) >= tau ? 1u : 0u) << (2 * g_);      \
      mask |= ((keys[g_] >> 16) >= tau ? 1u : 0u) << (2 * g_ + 1);      \
    }                                                                   \
    myc = __popc(mask); pre = myc;                                      \
    _Pragma("unroll") for (int off_ = 1; off_ < 64; off_ <<= 1) {       \
      int o_ = __shfl_up(pre, off_, 64);                                \
      pre += (lane >= off_) ? o_ : 0;                                   \
    }                                                                   \
    tot = __shfl(pre, 63, 64); } while (0)

#define COMPACT(row, pre, myc, mask) do {                               \
    int slot_ = (pre) - (myc); unsigned m2_ = (mask);                   \
    while (m2_) {                                                       \
      int bp_ = __builtin_ctz(m2_); m2_ &= m2_ - 1;                     \
      if (slot_ < 64) CjS[row][slot_] = lane * 2 + ((bp_ >> 1) << 7) + (bp_ & 1); \
      ++slot_;                                                          \
    } } while (0)

__global__ __launch_bounds__(1024, 4) void k_knn(
    const ushort* __restrict__ xT, const float* __restrict__ xxf,
    const float* __restrict__ xTf, const double* __restrict__ xx,
    int* __restrict__ idx) {
  extern __shared__ char smem[];
  ushort (*Sb)[NN] = (ushort(*)[NN])smem;          // [32][2048] u16 keys 128KB
  int (*CjS)[64] = (int(*)[64])(smem + 32 * NN * 2);        // [32][64] 8KB
  double (*SdS)[64] = (double(*)[64])(smem + 32 * NN * 2 + 8192); // [32][64] 16KB
  const int t = threadIdx.x;
  const int w = t >> 6, lane = t & 63;
  const int bidswz = ((blockIdx.x & 7) << 6) + (blockIdx.x >> 3); // batch/XCD
  const int b = bidswz >> 6;
  const int i0 = (bidswz & 63) << 5;
  const int lr = lane & 31, lh = lane >> 5;
  const ushort* xTb = xT + (((size_t)b) << 11) * CC;

  // ---- Phase A: MFMA 32x32x16 ----
  f32x16 acc[4];
#pragma unroll
  for (int tt = 0; tt < 4; ++tt)
#pragma unroll
    for (int q = 0; q < 16; ++q) acc[tt][q] = 0.f;

  const ushort* Ap = xTb + (size_t)(i0 + lr) * CC + lh * 8;
  bf8v a0 = *(const bf8v*)(Ap);
  bf8v a1 = *(const bf8v*)(Ap + 16);
  bf8v a2 = *(const bf8v*)(Ap + 32);
  bf8v a3 = *(const bf8v*)(Ap + 48);
  const int j0w = w << 7;
#pragma unroll
  for (int tt = 0; tt < 4; ++tt) {
    const ushort* Bp = xTb + (size_t)(j0w + tt * 32 + lr) * CC + lh * 8;
    bf8v b0 = *(const bf8v*)(Bp);
    bf8v b1 = *(const bf8v*)(Bp + 16);
    bf8v b2 = *(const bf8v*)(Bp + 32);
    bf8v b3 = *(const bf8v*)(Bp + 48);
    acc[tt] = __builtin_amdgcn_mfma_f32_32x32x16_bf16(a0, b0, acc[tt], 0, 0, 0);
    acc[tt] = __builtin_amdgcn_mfma_f32_32x32x16_bf16(a1, b1, acc[tt], 0, 0, 0);
    acc[tt] = __builtin_amdgcn_mfma_f32_32x32x16_bf16(a2, b2, acc[tt], 0, 0, 0);
    acc[tt] = __builtin_amdgcn_mfma_f32_32x32x16_bf16(a3, b3, acc[tt], 0, 0, 0);
  }

  // ---- Phase B: f32 score -> monotone u16 key -> LDS ----
  const float* xxfb = xxf + (b << 11);
#pragma unroll
  for (int tt = 0; tt < 4; ++tt) {
    int j = j0w + tt * 32 + lr;
    float xv = xxfb[j];
#pragma unroll
    for (int q = 0; q < 16; ++q) {
      int rr = (q & 3) + 8 * (q >> 2) + 4 * lh;    // 32x32 C/D map (m74/m101)
      float sv = fmaf(2.f, acc[tt][q], -xv);
      unsigned u = __float_as_uint(sv);
      u ^= (0x80000000u | (unsigned)((int)u >> 31)); // monotone u32
      Sb[rr][j] = (ushort)(u >> 16);
    }
  }
  __syncthreads();

  // ---- Phase C: rows rrA=w, rrB=w+16 fully interleaved ----
  const float* xTfb = xTf + (((size_t)b) << 11) * CC;
  const double* xxb = xx + (b << 11);
  const int rrA = w, rrB = w + 16;
  const int irowA = i0 + rrA, irowB = i0 + rrB;

  unsigned keysA[16], keysB[16];
  unsigned tA0 = 0, tA1 = 0, tA2 = 0, tA3 = 0;
  unsigned tB0 = 0, tB1 = 0, tB2 = 0, tB3 = 0;
#pragma unroll
  for (int g = 0; g < 16; ++g) {
    unsigned rawA = *(const unsigned*)(&Sb[rrA][lane * 2 + g * 128]);
    unsigned rawB = *(const unsigned*)(&Sb[rrB][lane * 2 + g * 128]);
    keysA[g] = rawA; keysB[g] = rawB;
    unsigned kA0 = rawA & 0xffffu, kA1 = rawA >> 16;
    unsigned kB0 = rawB & 0xffffu, kB1 = rawB >> 16;
    TOP4(kA0, tA0, tA1, tA2, tA3);
    TOP4(kB0, tB0, tB1, tB2, tB3);
    TOP4(kA1, tA0, tA1, tA2, tA3);
    TOP4(kB1, tB0, tB1, tB2, tB3);
  }
  // dual MSB radix with capped (top-4) ballot counts
  unsigned tauA = 0, tauB = 0;
  for (int bit = 15; bit >= 0; --bit) {
    unsigned cA = tauA | (1u << bit), cB = tauB | (1u << bit);
    int totA_ = __popcll(__ballot(tA0 >= cA)) + __popcll(__ballot(tA1 >= cA)) +
                __popcll(__ballot(tA2 >= cA)) + __popcll(__ballot(tA3 >= cA));
    int totB_ = __popcll(__ballot(tB0 >= cB)) + __popcll(__ballot(tB1 >= cB)) +
                __popcll(__ballot(tB2 >= cB)) + __popcll(__ballot(tB3 >= cB));
    if (totA_ >= CANDT) tauA = cA;
    if (totB_ >= CANDT) tauB = cB;
  }
  // masks + dual prefix scan
  unsigned maskA = 0, maskB = 0;
#pragma unroll
  for (int g = 0; g < 16; ++g) {
    maskA |= ((keysA[g] & 0xffffu) >= tauA ? 1u : 0u) << (2 * g);
    maskA |= ((keysA[g] >> 16) >= tauA ? 1u : 0u) << (2 * g + 1);
    maskB |= ((keysB[g] & 0xffffu) >= tauB ? 1u : 0u) << (2 * g);
    maskB |= ((keysB[g] >> 16) >= tauB ? 1u : 0u) << (2 * g + 1);
  }
  int mycA = __popc(maskA), mycB = __popc(maskB);
  int preA = mycA, preB = mycB;
#pragma unroll
  for (int off = 1; off < 64; off <<= 1) {
    int oA = __shfl_up(preA, off, 64);
    int oB = __shfl_up(preB, off, 64);
    preA += (lane >= off) ? oA : 0;
    preB += (lane >= off) ? oB : 0;
  }
  int totA = __shfl(preA, 63, 64);
  int totB = __shfl(preB, 63, 64);
  if (totA > 64) EXACT_RADIX(keysA, tauA, maskA, mycA, preA, totA);  // cold
  if (totB > 64) EXACT_RADIX(keysB, tauB, maskB, mycB, preB, totB);  // cold
  COMPACT(rrA, preA, mycA, maskA);
  COMPACT(rrB, preB, mycB, maskB);
  const int cntA = totA > 64 ? 64 : totA;
  const int cntB = totB > 64 ? 64 : totB;

  // dual fp64 rescore (accumulation order identical to R3..R10)
  int jA = CjS[rrA][lane < cntA ? lane : 0];
  int jB = CjS[rrB][lane < cntB ? lane : 0];
  const float* xiA = xTfb + (size_t)irowA * CC;
  const float* xiB = xTfb + (size_t)irowB * CC;
  const float* xjA = xTfb + (size_t)jA * CC;
  const float* xjB = xTfb + (size_t)jB * CC;
  double dA0 = 0, dA1 = 0, dA2 = 0, dA3 = 0;
  double dB0 = 0, dB1 = 0, dB2 = 0, dB3 = 0;
#pragma unroll
  for (int c = 0; c < CC; c += 4) {
    float4 fiA = *(const float4*)(xiA + c);
    float4 fjA = *(const float4*)(xjA + c);
    float4 fiB = *(const float4*)(xiB + c);
    float4 fjB = *(const float4*)(xjB + c);
    dA0 = fma((double)fiA.x, (double)fjA.x, dA0);
    dB0 = fma((double)fiB.x, (double)fjB.x, dB0);
    dA1 = fma((double)fiA.y, (double)fjA.y, dA1);
    dB1 = fma((double)fiB.y, (double)fjB.y, dB1);
    dA2 = fma((double)fiA.z, (double)fjA.z, dA2);
    dB2 = fma((double)fiB.z, (double)fjB.z, dB2);
    dA3 = fma((double)fiA.w, (double)fjA.w, dA3);
    dB3 = fma((double)fiB.w, (double)fjB.w, dB3);
  }
  double scA = 2.0 * ((dA0 + dA1) + (dA2 + dA3)) - xxb[jA];
  double scB = 2.0 * ((dB0 + dB1) + (dB2 + dB3)) - xxb[jB];

  // dual rank via LDS broadcast reads (same-wave write->read, no barrier)
  SdS[rrA][lane] = scA;
  SdS[rrB][lane] = scB;
  int rankA = 0, rankB = 0;
  const int cmax = cntA > cntB ? cntA : cntB;
  for (int mm = 0; mm < cmax; ++mm) {
    int mA = mm < cntA ? mm : 0;
    int mB = mm < cntB ? mm : 0;
    double smA = SdS[rrA][mA]; int jmA = CjS[rrA][mA];
    double smB = SdS[rrB][mB]; int jmB = CjS[rrB][mB];
    if (mm < cntA) rankA += (smA > scA || (smA == scA && jmA < jA)) ? 1 : 0;
    if (mm < cntB) rankB += (smB > scB || (smB == scB && jmB < jB)) ? 1 : 0;
  }
  if (lane < cntA && rankA < KK)
    idx[(size_t)((b << 11) + irowA) * KK + rankA] = jA;
  if (lane < cntB && rankB < KK)
    idx[(size_t)((b << 11) + irowB) * KK + rankB] = jB;
}

// ---------------------------------------------------------------------------
// k_stats: per-o sum & sumsq of h = P[gather]+Q (+ optional vmax/vmin emit).
// ---------------------------------------------------------------------------
__global__ __launch_bounds__(256) void k_stats(const float* __restrict__ P,
                                               const float* __restrict__ Q,
                                               const int* __restrict__ idx,
                                               float* __restrict__ partial,
                                               float* __restrict__ vmaxA,
                                               float* __restrict__ vminA) {
  const int t = threadIdx.x;
  const int o = t & 127, half = t >> 7;
  const int bid = (blockIdx.x & 7) * 128 + (blockIdx.x >> 3);
  float s = 0.f, s2 = 0.f;
  for (int it = 0; it < 8; ++it) {
    int pt = bid * 16 + it * 2 + half;
    int b = pt >> 11;
    float qv = Q[(size_t)pt * OO + o];
    const int* ip = idx + (size_t)pt * KK;
    float vmax = -3.0e38f, vmin = 3.0e38f;
#pragma unroll
    for (int k = 0; k < KK; ++k) {
      float v = P[((size_t)((b << 11) + ip[k])) * OO + o] + qv;
      s += v;
      s2 = fmaf(v, v, s2);
      vmax = fmaxf(vmax, v);
      vmin = fminf(vmin, v);
    }
    if (vmaxA) {
      vmaxA[(size_t)pt * OO + o] = vmax;
      vminA[(size_t)pt * OO + o] = vmin;
    }
  }
  __shared__ float red[512];
  red[t] = s; red[256 + t] = s2;
  __syncthreads();
  if (t < 128) {
    partial[bid * 128 + o]               = red[t] + red[t + 128];
    partial[NPART * 128 + bid * 128 + o] = red[256 + t] + red[256 + t + 128];
  }
}

// ---------------------------------------------------------------------------
// k_fin: single-kernel BN finalize. 128 blocks (one per o); 256 threads each
// load 4+4 partials (L2-resident) + tree reduce. Replaces fin1+fin2.
// ---------------------------------------------------------------------------
__global__ __launch_bounds__(256) void k_fin(const float* __restrict__ partial,
                                             const float* __restrict__ gamma,
                                             const float* __restrict__ beta,
                                             float* __restrict__ ss) {
  __shared__ float red[2][256];
  const int o = blockIdx.x;
  const int t = threadIdx.x;
  float s = 0.f, s2 = 0.f;
  for (int blk = t; blk < NPART; blk += 256) {
    s  += partial[(size_t)blk * 128 + o];
    s2 += partial[(size_t)NPART * 128 + (size_t)blk * 128 + o];
  }
  red[0][t] = s; red[1][t] = s2;
  __syncthreads();
  for (int st = 128; st >= 1; st >>= 1) {
    if (t < st) { red[0][t] += red[0][t + st]; red[1][t] += red[1][t + st]; }
    __syncthreads();
  }
  if (t == 0) {
    float mean = red[0][0] * (1.0f / M_TOT);
    float var  = red[1][0] * (1.0f / M_TOT) - mean * mean;
    float rs = 1.0f / sqrtf(var + 1e-5f);
    float scale = gamma[o] * rs;
    ss[o] = scale;
    ss[128 + o] = beta[o] - mean * scale;
  }
}

// ---------------------------------------------------------------------------
// k_out: BN affine -> exact GELU -> max over k -> out[b][o][n].
// ---------------------------------------------------------------------------
__global__ __launch_bounds__(256) void k_out(const float* __restrict__ P,
                                             const float* __restrict__ Q,
                                             const int* __restrict__ idx,
                                             const float* __restrict__ ss,
                                             const float* __restrict__ vmaxA,
                                             const float* __restrict__ vminA,
                                             int use_minmax,
                                             float* __restrict__ out) {
  __shared__ float tile[64][OO + 1];
  const int t = threadIdx.x;
  const int o = t & 127, half = t >> 7;
  const int bid = (blockIdx.x & 7) * 32 + (blockIdx.x >> 3);
  const float scale = ss[o], shift = ss[128 + o];
  const int pt0 = bid * 64;
  const int b = pt0 >> 11;
  const float inv_sqrt2 = 0.70710678118654752f;
  for (int it = 0; it < 32; ++it) {
    int pl = it * 2 + half;
    int pt = pt0 + pl;
    float vmax, vmin;
    if (use_minmax) {
      vmax = vmaxA[(size_t)pt * OO + o];
      vmin = vminA[(size_t)pt * OO + o];
    } else {
      float qv = Q[(size_t)pt * OO + o];
      const int* ip = idx + (size_t)pt * KK;
      vmax = -3.0e38f; vmin = 3.0e38f;
#pragma unroll
      for (int k = 0; k < KK; ++k) {
        float v = P[((size_t)((b << 11) + ip[k])) * OO + o] + qv;
        vmax = fmaxf(vmax, v);
        vmin = fminf(vmin, v);
      }
    }
    float ymax, ymin;
    if (scale >= 0.f) { ymax = fmaf(vmax, scale, shift); ymin = fmaf(vmin, scale, shift); }
    else              { ymax = fmaf(vmin, scale, shift); ymin = fmaf(vmax, scale, shift); }
    float g;
    if (ymax > 0.f) {
      g = 0.5f * ymax * (1.0f + erff(ymax * inv_sqrt2));
    } else {
      float g1 = 0.5f * ymax * (1.0f + erff(ymax * inv_sqrt2));
      float g2 = 0.5f * ymin * (1.0f + erff(ymin * inv_sqrt2));
      g = fmaxf(g1, g2);
    }
    tile[pl][o] = g;
  }
  __syncthreads();
  const int n0 = pt0 & (NN - 1);
  for (int rep = 0; rep < 32; ++rep) {
    int oo = rep * 4 + (t >> 6);
    int nn = t & 63;
    out[((size_t)(b * OO + oo) << 11) + n0 + nn] = tile[nn][oo];
  }
}

// ---------------------------------------------------------------------------
extern "C" void kernel_launch(void* const* d_in, const int* in_sizes, int n_in,
                              void* d_out, int out_size, void* d_ws, size_t ws_size,
                              hipStream_t stream) {
  const float* x     = (const float*)d_in[0];
  const float* W     = (const float*)d_in[1];
  const float* gamma = (const float*)d_in[2];
  const float* beta  = (const float*)d_in[3];
  float* out = (float*)d_out;

  const int knn_lds = 32 * NN * 2 + 8192 + 16384;      // 155648 B
  hipFuncSetAttribute((const void*)k_knn,
                      hipFuncAttributeMaxDynamicSharedMemorySize, knn_lds);

  const size_t needA = 131072 + 65536 + 1310720 + (size_t)2 * NPART * 128 * 4 +
                       1024 + 4ull * 8388608;

  if (ws_size >= needA) {
    // Path A layout
    double* xx   = (double*)d_ws;                      // 131072 B
    float*  xxf  = (float*)(xx + BB * NN);             // 65536 B
    int*    idxp = (int*)(xxf + BB * NN);              // 1310720 B
    float*  part = (float*)(idxp + (size_t)BB * NN * KK); // 1 MB
    float*  ss   = part + 2 * NPART * 128;             // 1024 B
    float*  P    = ss + 256;                           // 8 MB
    float*  Q    = P + (size_t)BB * NN * OO;           // 8 MB
    float*  vmax = Q + (size_t)BB * NN * OO;           // 8 MB
    float*  vmin = vmax + (size_t)BB * NN * OO;        // 8 MB
    ushort* xT   = (ushort*)vmax;                      // 2 MB alias (pre-stats)
    float*  xTf  = vmax + (size_t)BB * NN * (CC / 2);  // 4 MB alias

    hipLaunchKernelGGL(k_pqprep, dim3(BB * NN / 32), dim3(256), 0, stream,
                       x, W, P, Q, xT, xTf, xx, xxf);
    hipLaunchKernelGGL(k_knn, dim3(BB * NN / 32), dim3(1024), knn_lds, stream,
                       xT, xxf, xTf, xx, idxp);
    hipLaunchKernelGGL(k_stats, dim3(NPART), dim3(256), 0, stream,
                       P, Q, idxp, part, vmax, vmin);
    hipLaunchKernelGGL(k_fin, dim3(128), dim3(256), 0, stream, part, gamma, beta, ss);
    hipLaunchKernelGGL(k_out, dim3(BB * NN / 64), dim3(256), 0, stream,
                       P, Q, idxp, ss, vmax, vmin, 1, out);
  } else {
    // Path B layout
    double* xx   = (double*)d_ws;
    int*    idxp = (int*)(xx + BB * NN);
    float*  P    = (float*)(idxp + (size_t)BB * NN * KK);
    float*  Q    = P + (size_t)BB * NN * OO;
    float*  part = Q + (size_t)BB * NN * OO;
    float*  ss   = part + 2 * NPART * 128;
    ushort* xT   = (ushort*)P;
    float*  xTf  = P + (size_t)BB * NN * (CC / 2);
    float*  xxf  = Q;

    hipLaunchKernelGGL(k_prep, dim3(BB * NN / 256), dim3(256), 0, stream,
                       x, xT, xTf, xx, xxf);
    hipLaunchKernelGGL(k_knn, dim3(BB * NN / 32), dim3(1024), knn_lds, stream,
                       xT, xxf, xTf, xx, idxp);
    hipLaunchKernelGGL(k_pq, dim3(BB * NN / 64), dim3(256), 0, stream, x, W, P, Q);
    hipLaunchKernelGGL(k_stats, dim3(NPART), dim3(256), 0, stream,
                       P, Q, idxp, part, (float*)nullptr, (float*)nullptr);
    hipLaunchKernelGGL(k_fin, dim3(128), dim3(256), 0, stream, part, gamma, beta, ss);
    hipLaunchKernelGGL(k_out, dim3(BB * NN / 64), dim3(256), 0, stream,
                       P, Q, idxp, ss, (const float*)nullptr, (const float*)nullptr, 0, out);
  }
}

// Round 12
// 168.293 us; speedup vs baseline: 2.5287x; 1.0037x over previous
//
#include <hip/hip_runtime.h>
#include <math.h>

#define BB 8
#define CC 64
#define NN 2048
#define KK 20
#define OO 128
#define CANDT 40
#define NPART 1024
#define M_TOT 327680.0f    // B*N*K

typedef __attribute__((ext_vector_type(8))) __bf16 bf8v;
typedef __attribute__((ext_vector_type(16))) float f32x16;

// ---------------------------------------------------------------------------
// k_pqprep (Path A): P/Q GEMMs + bf16 xT rows + f32 xTf rows + xx/xxf norms.
// x staged ONCE in LDS via float4 (was: 8 o-groups each re-loading the same
// 32 columns with 64-deep strided chains -> 8x redundant L1 traffic).
// ---------------------------------------------------------------------------
__global__ __launch_bounds__(256) void k_pqprep(const float* __restrict__ x,
                                                const float* __restrict__ W,
                                                float* __restrict__ P,
                                                float* __restrict__ Q,
                                                ushort* __restrict__ xT,
                                                float* __restrict__ xTf,
                                                double* __restrict__ xx,
                                                float* __restrict__ xxf) {
  __shared__ float xs[32][CC + 1];                 // 8.3 KB
  __shared__ float tile[32][OO + 1];               // 16.5 KB
  const int t = threadIdx.x;
  const int jj = t & 31, og = t >> 5;              // 8 o-groups of 16
  const int pt0 = blockIdx.x * 32;
  const int b = pt0 >> 11;
  const int n0 = pt0 & (NN - 1);

  // stage x[b][*][n0..n0+31] -> xs[pt][c]  (512 float4 segs, 2/thread)
#pragma unroll
  for (int r = 0; r < 2; ++r) {
    int seg = t + r * 256;
    int c = seg >> 3, n4 = (seg & 7) * 4;
    float4 v = *(const float4*)(x + ((size_t)(b * CC + c) << 11) + n0 + n4);
    xs[n4 + 0][c] = v.x; xs[n4 + 1][c] = v.y;
    xs[n4 + 2][c] = v.z; xs[n4 + 3][c] = v.w;
  }
  __syncthreads();

  if (t < 32) {                                    // prep outputs (1 pt/thread)
    int i = pt0 + t;
    ushort* rowp = xT + (size_t)i * CC;
    float* rowf = xTf + (size_t)i * CC;
    double s = 0.0;
#pragma unroll
    for (int c8 = 0; c8 < 8; ++c8) {
      unsigned tmp[8];
      float f[8];
#pragma unroll
      for (int e = 0; e < 8; ++e) {
        float v = xs[t][c8 * 8 + e];
        f[e] = v;
        double dv = (double)v; s = fma(dv, dv, s);
        __bf16 h = (__bf16)v;
        ushort us; __builtin_memcpy(&us, &h, 2);
        tmp[e] = us;
      }
      uint4 pk;
      pk.x = tmp[0] | (tmp[1] << 16);
      pk.y = tmp[2] | (tmp[3] << 16);
      pk.z = tmp[4] | (tmp[5] << 16);
      pk.w = tmp[6] | (tmp[7] << 16);
      *(uint4*)(rowp + c8 * 8) = pk;
      *(float4*)(rowf + c8 * 8)     = make_float4(f[0], f[1], f[2], f[3]);
      *(float4*)(rowf + c8 * 8 + 4) = make_float4(f[4], f[5], f[6], f[7]);
    }
    xx[i] = s;
    xxf[i] = (float)s;
  }

  for (int oo = 0; oo < 16; ++oo) {
    int o = og * 16 + oo;
    const float* wr = W + (size_t)o * (2 * CC);
    float sp = 0.f;
#pragma unroll
    for (int c = 0; c < CC; ++c) sp = fmaf(wr[c], xs[jj][c], sp);
    tile[jj][o] = sp;
  }
  __syncthreads();
  for (int it = 0; it < 16; ++it) {
    int r = it * 2 + (t >> 7);
    P[((size_t)(pt0 + r)) * OO + (t & 127)] = tile[r][t & 127];
  }
  __syncthreads();
  for (int oo = 0; oo < 16; ++oo) {
    int o = og * 16 + oo;
    const float* wr = W + (size_t)o * (2 * CC);
    float sq = 0.f;
#pragma unroll
    for (int c = 0; c < CC; ++c) sq = fmaf(wr[CC + c] - wr[c], xs[jj][c], sq);
    tile[jj][o] = sq;
  }
  __syncthreads();
  for (int it = 0; it < 16; ++it) {
    int r = it * 2 + (t >> 7);
    Q[((size_t)(pt0 + r)) * OO + (t & 127)] = tile[r][t & 127];
  }
}

// ---------------------------------------------------------------------------
// k_prep (Path B fallback): standalone prep pass.
// ---------------------------------------------------------------------------
__global__ __launch_bounds__(256) void k_prep(const float* __restrict__ x,
                                              ushort* __restrict__ xT,
                                              float* __restrict__ xTf,
                                              double* __restrict__ xx,
                                              float* __restrict__ xxf) {
  int i = blockIdx.x * 256 + threadIdx.x;
  int b = i >> 11, n = i & (NN - 1);
  const float* p = x + ((size_t)b * CC) * NN + n;
  ushort* rowp = xT + (size_t)i * CC;
  float* rowf = xTf + (size_t)i * CC;
  double s = 0.0;
#pragma unroll
  for (int c8 = 0; c8 < 8; ++c8) {
    float f[8];
    unsigned tmp[8];
#pragma unroll
    for (int e = 0; e < 8; ++e) {
      float v = p[(size_t)(c8 * 8 + e) * NN];
      f[e] = v;
      double dv = (double)v; s = fma(dv, dv, s);
      __bf16 h = (__bf16)v;
      ushort us; __builtin_memcpy(&us, &h, 2);
      tmp[e] = us;
    }
    uint4 pk;
    pk.x = tmp[0] | (tmp[1] << 16);
    pk.y = tmp[2] | (tmp[3] << 16);
    pk.z = tmp[4] | (tmp[5] << 16);
    pk.w = tmp[6] | (tmp[7] << 16);
    *(uint4*)(rowp + c8 * 8) = pk;
    *(float4*)(rowf + c8 * 8)     = make_float4(f[0], f[1], f[2], f[3]);
    *(float4*)(rowf + c8 * 8 + 4) = make_float4(f[4], f[5], f[6], f[7]);
  }
  xx[i] = s;
  xxf[i] = (float)s;
}

// ---------------------------------------------------------------------------
// k_pq (Path B fallback): P/Q GEMMs only.
// ---------------------------------------------------------------------------
__global__ __launch_bounds__(256) void k_pq(const float* __restrict__ x,
                                            const float* __restrict__ W,
                                            float* __restrict__ P,
                                            float* __restrict__ Q) {
  __shared__ float tile[64][OO + 1];
  const int t = threadIdx.x;
  const int jj = t & 63, og = t >> 6;
  const int pt0 = blockIdx.x * 64;
  const int b = pt0 >> 11;
  const int jn = (pt0 & (NN - 1)) + jj;

  float xcol[CC];
#pragma unroll
  for (int c = 0; c < CC; ++c) xcol[c] = x[((size_t)(b * CC + c) << 11) + jn];

  for (int oo = 0; oo < 32; ++oo) {
    int o = og * 32 + oo;
    const float* wr = W + (size_t)o * (2 * CC);
    float sp = 0.f;
#pragma unroll
    for (int c = 0; c < CC; ++c) sp = fmaf(wr[c], xcol[c], sp);
    tile[jj][o] = sp;
  }
  __syncthreads();
  for (int it = 0; it < 32; ++it) {
    int r = it * 2 + (t >> 7);
    P[((size_t)(pt0 + r)) * OO + (t & 127)] = tile[r][t & 127];
  }
  __syncthreads();
  for (int oo = 0; oo < 32; ++oo) {
    int o = og * 32 + oo;
    const float* wr = W + (size_t)o * (2 * CC);
    float sq = 0.f;
#pragma unroll
    for (int c = 0; c < CC; ++c) sq = fmaf(wr[CC + c] - wr[c], xcol[c], sq);
    tile[jj][o] = sq;
  }
  __syncthreads();
  for (int it = 0; it < 32; ++it) {
    int r = it * 2 + (t >> 7);
    Q[((size_t)(pt0 + r)) * OO + (t & 127)] = tile[r][t & 127];
  }
}

// ---------------------------------------------------------------------------
// k_knn (R10 phase-C restored — spill-free; R11 fusion was neutral + 6.4MB
// spill). 512 blocks x 1024 thr; 32 rows/block; 32x32x16 MFMA; 2 rows/wave.
// ---------------------------------------------------------------------------
__global__ __launch_bounds__(1024, 4) void k_knn(
    const ushort* __restrict__ xT, const float* __restrict__ xxf,
    const float* __restrict__ xTf, const double* __restrict__ xx,
    int* __restrict__ idx) {
  extern __shared__ char smem[];
  ushort (*Sb)[NN] = (ushort(*)[NN])smem;          // [32][2048] u16 keys 128KB
  int* Cj = (int*)(smem + 32 * NN * 2);            // [16][64] 4KB
  double* Sd = (double*)(smem + 32 * NN * 2 + 4096); // [16][64] 8KB
  const int t = threadIdx.x;
  const int w = t >> 6, lane = t & 63;
  const int bidswz = ((blockIdx.x & 7) << 6) + (blockIdx.x >> 3); // batch/XCD
  const int b = bidswz >> 6;
  const int i0 = (bidswz & 63) << 5;
  const int lr = lane & 31, lh = lane >> 5;
  const ushort* xTb = xT + (((size_t)b) << 11) * CC;

  // ---- Phase A: MFMA 32x32x16 ----
  f32x16 acc[4];
#pragma unroll
  for (int tt = 0; tt < 4; ++tt)
#pragma unroll
    for (int q = 0; q < 16; ++q) acc[tt][q] = 0.f;

  const ushort* Ap = xTb + (size_t)(i0 + lr) * CC + lh * 8;
  bf8v a0 = *(const bf8v*)(Ap);
  bf8v a1 = *(const bf8v*)(Ap + 16);
  bf8v a2 = *(const bf8v*)(Ap + 32);
  bf8v a3 = *(const bf8v*)(Ap + 48);
  const int j0w = w << 7;
#pragma unroll
  for (int tt = 0; tt < 4; ++tt) {
    const ushort* Bp = xTb + (size_t)(j0w + tt * 32 + lr) * CC + lh * 8;
    bf8v b0 = *(const bf8v*)(Bp);
    bf8v b1 = *(const bf8v*)(Bp + 16);
    bf8v b2 = *(const bf8v*)(Bp + 32);
    bf8v b3 = *(const bf8v*)(Bp + 48);
    acc[tt] = __builtin_amdgcn_mfma_f32_32x32x16_bf16(a0, b0, acc[tt], 0, 0, 0);
    acc[tt] = __builtin_amdgcn_mfma_f32_32x32x16_bf16(a1, b1, acc[tt], 0, 0, 0);
    acc[tt] = __builtin_amdgcn_mfma_f32_32x32x16_bf16(a2, b2, acc[tt], 0, 0, 0);
    acc[tt] = __builtin_amdgcn_mfma_f32_32x32x16_bf16(a3, b3, acc[tt], 0, 0, 0);
  }

  // ---- Phase B: f32 score -> monotone u16 key -> LDS ----
  const float* xxfb = xxf + (b << 11);
#pragma unroll
  for (int tt = 0; tt < 4; ++tt) {
    int j = j0w + tt * 32 + lr;
    float xv = xxfb[j];
#pragma unroll
    for (int q = 0; q < 16; ++q) {
      int rr = (q & 3) + 8 * (q >> 2) + 4 * lh;    // 32x32 C/D map (m74/m101)
      float sv = fmaf(2.f, acc[tt][q], -xv);
      unsigned u = __float_as_uint(sv);
      u ^= (0x80000000u | (unsigned)((int)u >> 31)); // monotone u32
      Sb[rr][j] = (ushort)(u >> 16);
    }
  }
  __syncthreads();

  // ---- Phase C: 2 rows per wave ----
  const float* xTfb = xTf + (((size_t)b) << 11) * CC;
  const double* xxb = xx + (b << 11);
#pragma unroll 1
  for (int rw = 0; rw < 2; ++rw) {
    const int rr = w + 16 * rw;
    const int irow = i0 + rr;
    unsigned keys32[16];
    unsigned t0 = 0, t1 = 0, t2 = 0, t3 = 0;
#pragma unroll
    for (int g = 0; g < 16; ++g) {
      unsigned raw = *(const unsigned*)(&Sb[rr][lane * 2 + g * 128]);
      keys32[g] = raw;
      unsigned k0 = raw & 0xffffu, k1 = raw >> 16;
      unsigned mx, mn;
      mx = k0 > t0 ? k0 : t0; mn = k0 > t0 ? t0 : k0; t0 = mx;
      mx = mn > t1 ? mn : t1; mn = mn > t1 ? t1 : mn; t1 = mx;
      mx = mn > t2 ? mn : t2; mn = mn > t2 ? t2 : mn; t2 = mx;
      t3 = mn > t3 ? mn : t3;
      mx = k1 > t0 ? k1 : t0; mn = k1 > t0 ? t0 : k1; t0 = mx;
      mx = mn > t1 ? mn : t1; mn = mn > t1 ? t1 : mn; t1 = mx;
      mx = mn > t2 ? mn : t2; mn = mn > t2 ? t2 : mn; t2 = mx;
      t3 = mn > t3 ? mn : t3;
    }
    unsigned tau = 0;
    for (int bit = 15; bit >= 0; --bit) {
      unsigned cnd = tau | (1u << bit);
      int tot = __popcll(__ballot(t0 >= cnd)) + __popcll(__ballot(t1 >= cnd)) +
                __popcll(__ballot(t2 >= cnd)) + __popcll(__ballot(t3 >= cnd));
      if (tot >= CANDT) tau = cnd;
    }
    unsigned mask = 0;
#pragma unroll
    for (int g = 0; g < 16; ++g) {
      mask |= ((keys32[g] & 0xffffu) >= tau ? 1u : 0u) << (2 * g);
      mask |= ((keys32[g] >> 16) >= tau ? 1u : 0u) << (2 * g + 1);
    }
    int myc = __popc(mask);
    int pre = myc;
#pragma unroll
    for (int off = 1; off < 64; off <<= 1) {
      int o = __shfl_up(pre, off, 64);
      pre += (lane >= off) ? o : 0;
    }
    int tot = __shfl(pre, 63, 64);
    if (tot > 64) {                                // cold exact-radix fallback
      tau = 0;
      for (int bit = 15; bit >= 0; --bit) {
        unsigned cnd = tau | (1u << bit);
        int cc = 0;
#pragma unroll
        for (int g = 0; g < 16; ++g) {
          cc += ((keys32[g] & 0xffffu) >= cnd) ? 1 : 0;
          cc += ((keys32[g] >> 16) >= cnd) ? 1 : 0;
        }
#pragma unroll
        for (int off = 1; off < 64; off <<= 1) cc += __shfl_xor(cc, off, 64);
        if (cc >= CANDT) tau = cnd;
      }
      mask = 0;
#pragma unroll
      for (int g = 0; g < 16; ++g) {
        mask |= ((keys32[g] & 0xffffu) >= tau ? 1u : 0u) << (2 * g);
        mask |= ((keys32[g] >> 16) >= tau ? 1u : 0u) << (2 * g + 1);
      }
      myc = __popc(mask);
      pre = myc;
#pragma unroll
      for (int off = 1; off < 64; off <<= 1) {
        int o = __shfl_up(pre, off, 64);
        pre += (lane >= off) ? o : 0;
      }
      tot = __shfl(pre, 63, 64);
    }
    {
      int slot = pre - myc;
      unsigned m2 = mask;
      while (m2) {
        int bp = __builtin_ctz(m2); m2 &= m2 - 1;
        if (slot < 64) Cj[w * 64 + slot] = lane * 2 + ((bp >> 1) << 7) + (bp & 1);
        ++slot;
      }
    }
    int cnt = tot > 64 ? 64 : tot;
    int j = Cj[w * 64 + (lane < cnt ? lane : 0)];
    const float* xi = xTfb + (size_t)irow * CC;
    const float* xj = xTfb + (size_t)j * CC;
    double d0 = 0, d1 = 0, d2 = 0, d3 = 0;
#pragma unroll
    for (int c = 0; c < CC; c += 4) {
      float4 fi = *(const float4*)(xi + c);
      float4 fj = *(const float4*)(xj + c);
      d0 = fma((double)fi.x, (double)fj.x, d0);
      d1 = fma((double)fi.y, (double)fj.y, d1);
      d2 = fma((double)fi.z, (double)fj.z, d2);
      d3 = fma((double)fi.w, (double)fj.w, d3);
    }
    double sc = 2.0 * ((d0 + d1) + (d2 + d3)) - xxb[j];
    Sd[w * 64 + lane] = sc;
    int rank = 0;
#pragma unroll 4
    for (int mm = 0; mm < cnt; ++mm) {
      double sm = Sd[w * 64 + mm];
      int jm = Cj[w * 64 + mm];
      rank += (sm > sc || (sm == sc && jm < j)) ? 1 : 0;
    }
    if (lane < cnt && rank < KK)
      idx[(size_t)((b << 11) + irow) * KK + rank] = j;
  }
}

// ---------------------------------------------------------------------------
// k_stats: per-o sum & sumsq of h = P[gather]+Q (+ vmax/vmin emit).
// idx staged in LDS once per block (was: every thread re-loading the same 20
// ints per point -> 41K loads/block where 320 suffice).
// ---------------------------------------------------------------------------
__global__ __launch_bounds__(256) void k_stats(const float* __restrict__ P,
                                               const float* __restrict__ Q,
                                               const int* __restrict__ idx,
                                               float* __restrict__ partial,
                                               float* __restrict__ vmaxA,
                                               float* __restrict__ vminA) {
  __shared__ int sIdx[16 * KK];                    // 320 ints
  __shared__ float red[512];
  const int t = threadIdx.x;
  const int o = t & 127, half = t >> 7;
  const int bid = (blockIdx.x & 7) * 128 + (blockIdx.x >> 3);
  const int pt0 = bid * 16;
  const int b = pt0 >> 11;
  if (t < 160)
    *(int2*)(sIdx + t * 2) = *(const int2*)(idx + (size_t)pt0 * KK + t * 2);
  __syncthreads();

  float s = 0.f, s2 = 0.f;
  for (int it = 0; it < 8; ++it) {
    int pl = it * 2 + half;
    int pt = pt0 + pl;
    float qv = Q[(size_t)pt * OO + o];
    const int* ip = sIdx + pl * KK;
    float vmax = -3.0e38f, vmin = 3.0e38f;
#pragma unroll
    for (int k = 0; k < KK; ++k) {
      float v = P[((size_t)((b << 11) + ip[k])) * OO + o] + qv;
      s += v;
      s2 = fmaf(v, v, s2);
      vmax = fmaxf(vmax, v);
      vmin = fminf(vmin, v);
    }
    if (vmaxA) {
      vmaxA[(size_t)pt * OO + o] = vmax;
      vminA[(size_t)pt * OO + o] = vmin;
    }
  }
  red[t] = s; red[256 + t] = s2;
  __syncthreads();
  if (t < 128) {
    partial[bid * 128 + o]               = red[t] + red[t + 128];
    partial[NPART * 128 + bid * 128 + o] = red[256 + t] + red[256 + t + 128];
  }
}

// ---------------------------------------------------------------------------
// k_fin: single-kernel BN finalize. 128 blocks (one per o).
// ---------------------------------------------------------------------------
__global__ __launch_bounds__(256) void k_fin(const float* __restrict__ partial,
                                             const float* __restrict__ gamma,
                                             const float* __restrict__ beta,
                                             float* __restrict__ ss) {
  __shared__ float red[2][256];
  const int o = blockIdx.x;
  const int t = threadIdx.x;
  float s = 0.f, s2 = 0.f;
  for (int blk = t; blk < NPART; blk += 256) {
    s  += partial[(size_t)blk * 128 + o];
    s2 += partial[(size_t)NPART * 128 + (size_t)blk * 128 + o];
  }
  red[0][t] = s; red[1][t] = s2;
  __syncthreads();
  for (int st = 128; st >= 1; st >>= 1) {
    if (t < st) { red[0][t] += red[0][t + st]; red[1][t] += red[1][t + st]; }
    __syncthreads();
  }
  if (t == 0) {
    float mean = red[0][0] * (1.0f / M_TOT);
    float var  = red[1][0] * (1.0f / M_TOT) - mean * mean;
    float rs = 1.0f / sqrtf(var + 1e-5f);
    float scale = gamma[o] * rs;
    ss[o] = scale;
    ss[128 + o] = beta[o] - mean * scale;
  }
}

// ---------------------------------------------------------------------------
// k_out: BN affine -> exact GELU -> max over k -> out[b][o][n].
// ---------------------------------------------------------------------------
__global__ __launch_bounds__(256) void k_out(const float* __restrict__ P,
                                             const float* __restrict__ Q,
                                             const int* __restrict__ idx,
                                             const float* __restrict__ ss,
                                             const float* __restrict__ vmaxA,
                                             const float* __restrict__ vminA,
                                             int use_minmax,
                                             float* __restrict__ out) {
  __shared__ float tile[64][OO + 1];
  const int t = threadIdx.x;
  const int o = t & 127, half = t >> 7;
  const int bid = (blockIdx.x & 7) * 32 + (blockIdx.x >> 3);
  const float scale = ss[o], shift = ss[128 + o];
  const int pt0 = bid * 64;
  const int b = pt0 >> 11;
  const float inv_sqrt2 = 0.70710678118654752f;
  for (int it = 0; it < 32; ++it) {
    int pl = it * 2 + half;
    int pt = pt0 + pl;
    float vmax, vmin;
    if (use_minmax) {
      vmax = vmaxA[(size_t)pt * OO + o];
      vmin = vminA[(size_t)pt * OO + o];
    } else {
      float qv = Q[(size_t)pt * OO + o];
      const int* ip = idx + (size_t)pt * KK;
      vmax = -3.0e38f; vmin = 3.0e38f;
#pragma unroll
      for (int k = 0; k < KK; ++k) {
        float v = P[((size_t)((b << 11) + ip[k])) * OO + o] + qv;
        vmax = fmaxf(vmax, v);
        vmin = fminf(vmin, v);
      }
    }
    float ymax, ymin;
    if (scale >= 0.f) { ymax = fmaf(vmax, scale, shift); ymin = fmaf(vmin, scale, shift); }
    else              { ymax = fmaf(vmin, scale, shift); ymin = fmaf(vmax, scale, shift); }
    float g;
    if (ymax > 0.f) {
      g = 0.5f * ymax * (1.0f + erff(ymax * inv_sqrt2));
    } else {
      float g1 = 0.5f * ymax * (1.0f + erff(ymax * inv_sqrt2));
      float g2 = 0.5f * ymin * (1.0f + erff(ymin * inv_sqrt2));
      g = fmaxf(g1, g2);
    }
    tile[pl][o] = g;
  }
  __syncthreads();
  const int n0 = pt0 & (NN - 1);
  for (int rep = 0; rep < 32; ++rep) {
    int oo = rep * 4 + (t >> 6);
    int nn = t & 63;
    out[((size_t)(b * OO + oo) << 11) + n0 + nn] = tile[nn][oo];
  }
}

// ---------------------------------------------------------------------------
extern "C" void kernel_launch(void* const* d_in, const int* in_sizes, int n_in,
                              void* d_out, int out_size, void* d_ws, size_t ws_size,
                              hipStream_t stream) {
  const float* x     = (const float*)d_in[0];
  const float* W     = (const float*)d_in[1];
  const float* gamma = (const float*)d_in[2];
  const float* beta  = (const float*)d_in[3];
  float* out = (float*)d_out;

  const int knn_lds = 32 * NN * 2 + 4096 + 8192;       // 143360 B
  hipFuncSetAttribute((const void*)k_knn,
                      hipFuncAttributeMaxDynamicSharedMemorySize, knn_lds);

  const size_t needA = 131072 + 65536 + 1310720 + (size_t)2 * NPART * 128 * 4 +
                       1024 + 4ull * 8388608;

  if (ws_size >= needA) {
    // Path A layout
    double* xx   = (double*)d_ws;                      // 131072 B
    float*  xxf  = (float*)(xx + BB * NN);             // 65536 B
    int*    idxp = (int*)(xxf + BB * NN);              // 1310720 B
    float*  part = (float*)(idxp + (size_t)BB * NN * KK); // 1 MB
    float*  ss   = part + 2 * NPART * 128;             // 1024 B
    float*  P    = ss + 256;                           // 8 MB
    float*  Q    = P + (size_t)BB * NN * OO;           // 8 MB
    float*  vmax = Q + (size_t)BB * NN * OO;           // 8 MB
    float*  vmin = vmax + (size_t)BB * NN * OO;        // 8 MB
    ushort* xT   = (ushort*)vmax;                      // 2 MB alias (pre-stats)
    float*  xTf  = vmax + (size_t)BB * NN * (CC / 2);  // 4 MB alias

    hipLaunchKernelGGL(k_pqprep, dim3(BB * NN / 32), dim3(256), 0, stream,
                       x, W, P, Q, xT, xTf, xx, xxf);
    hipLaunchKernelGGL(k_knn, dim3(BB * NN / 32), dim3(1024), knn_lds, stream,
                       xT, xxf, xTf, xx, idxp);
    hipLaunchKernelGGL(k_stats, dim3(NPART), dim3(256), 0, stream,
                       P, Q, idxp, part, vmax, vmin);
    hipLaunchKernelGGL(k_fin, dim3(128), dim3(256), 0, stream, part, gamma, beta, ss);
    hipLaunchKernelGGL(k_out, dim3(BB * NN / 64), dim3(256), 0, stream,
                       P, Q, idxp, ss, vmax, vmin, 1, out);
  } else {
    // Path B layout
    double* xx   = (double*)d_ws;
    int*    idxp = (int*)(xx + BB * NN);
    float*  P    = (float*)(idxp + (size_t)BB * NN * KK);
    float*  Q    = P + (size_t)BB * NN * OO;
    float*  part = Q + (size_t)BB * NN * OO;
    float*  ss   = part + 2 * NPART * 128;
    ushort* xT   = (ushort*)P;
    float*  xTf  = P + (size_t)BB * NN * (CC / 2);
    float*  xxf  = Q;

    hipLaunchKernelGGL(k_prep, dim3(BB * NN / 256), dim3(256), 0, stream,
                       x, xT, xTf, xx, xxf);
    hipLaunchKernelGGL(k_knn, dim3(BB * NN / 32), dim3(1024), knn_lds, stream,
                       xT, xxf, xTf, xx, idxp);
    hipLaunchKernelGGL(k_pq, dim3(BB * NN / 64), dim3(256), 0, stream, x, W, P, Q);
    hipLaunchKernelGGL(k_stats, dim3(NPART), dim3(256), 0, stream,
                       P, Q, idxp, part, (float*)nullptr, (float*)nullptr);
    hipLaunchKernelGGL(k_fin, dim3(128), dim3(256), 0, stream, part, gamma, beta, ss);
    hipLaunchKernelGGL(k_out, dim3(BB * NN / 64), dim3(256), 0, stream,
                       P, Q, idxp, ss, (const float*)nullptr, (const float*)nullptr, 0, out);
  }
}

// Round 13
// 167.296 us; speedup vs baseline: 2.5438x; 1.0060x over previous
//
#include <hip/hip_runtime.h>
#include <math.h>

#define BB 8
#define CC 64
#define NN 2048
#define KK 20
#define OO 128
#define CANDT 40
#define NPART 1024
#define M_TOT 327680.0f    // B*N*K

typedef __attribute__((ext_vector_type(8))) __bf16 bf8v;
typedef __attribute__((ext_vector_type(16))) float f32x16;

// ---------------------------------------------------------------------------
// k_pqprep (Path A): P/Q GEMMs + bf16 xT rows + f32 xTf rows + xx/xxf norms.
// ---------------------------------------------------------------------------
__global__ __launch_bounds__(256) void k_pqprep(const float* __restrict__ x,
                                                const float* __restrict__ W,
                                                float* __restrict__ P,
                                                float* __restrict__ Q,
                                                ushort* __restrict__ xT,
                                                float* __restrict__ xTf,
                                                double* __restrict__ xx,
                                                float* __restrict__ xxf) {
  __shared__ float xs[32][CC + 1];                 // 8.3 KB
  __shared__ float tile[32][OO + 1];               // 16.5 KB
  const int t = threadIdx.x;
  const int jj = t & 31, og = t >> 5;              // 8 o-groups of 16
  const int pt0 = blockIdx.x * 32;
  const int b = pt0 >> 11;
  const int n0 = pt0 & (NN - 1);

#pragma unroll
  for (int r = 0; r < 2; ++r) {
    int seg = t + r * 256;
    int c = seg >> 3, n4 = (seg & 7) * 4;
    float4 v = *(const float4*)(x + ((size_t)(b * CC + c) << 11) + n0 + n4);
    xs[n4 + 0][c] = v.x; xs[n4 + 1][c] = v.y;
    xs[n4 + 2][c] = v.z; xs[n4 + 3][c] = v.w;
  }
  __syncthreads();

  if (t < 32) {                                    // prep outputs (1 pt/thread)
    int i = pt0 + t;
    ushort* rowp = xT + (size_t)i * CC;
    float* rowf = xTf + (size_t)i * CC;
    double s = 0.0;
#pragma unroll
    for (int c8 = 0; c8 < 8; ++c8) {
      unsigned tmp[8];
      float f[8];
#pragma unroll
      for (int e = 0; e < 8; ++e) {
        float v = xs[t][c8 * 8 + e];
        f[e] = v;
        double dv = (double)v; s = fma(dv, dv, s);
        __bf16 h = (__bf16)v;
        ushort us; __builtin_memcpy(&us, &h, 2);
        tmp[e] = us;
      }
      uint4 pk;
      pk.x = tmp[0] | (tmp[1] << 16);
      pk.y = tmp[2] | (tmp[3] << 16);
      pk.z = tmp[4] | (tmp[5] << 16);
      pk.w = tmp[6] | (tmp[7] << 16);
      *(uint4*)(rowp + c8 * 8) = pk;
      *(float4*)(rowf + c8 * 8)     = make_float4(f[0], f[1], f[2], f[3]);
      *(float4*)(rowf + c8 * 8 + 4) = make_float4(f[4], f[5], f[6], f[7]);
    }
    xx[i] = s;
    xxf[i] = (float)s;
  }

  for (int oo = 0; oo < 16; ++oo) {
    int o = og * 16 + oo;
    const float* wr = W + (size_t)o * (2 * CC);
    float sp = 0.f;
#pragma unroll
    for (int c = 0; c < CC; ++c) sp = fmaf(wr[c], xs[jj][c], sp);
    tile[jj][o] = sp;
  }
  __syncthreads();
  for (int it = 0; it < 16; ++it) {
    int r = it * 2 + (t >> 7);
    P[((size_t)(pt0 + r)) * OO + (t & 127)] = tile[r][t & 127];
  }
  __syncthreads();
  for (int oo = 0; oo < 16; ++oo) {
    int o = og * 16 + oo;
    const float* wr = W + (size_t)o * (2 * CC);
    float sq = 0.f;
#pragma unroll
    for (int c = 0; c < CC; ++c) sq = fmaf(wr[CC + c] - wr[c], xs[jj][c], sq);
    tile[jj][o] = sq;
  }
  __syncthreads();
  for (int it = 0; it < 16; ++it) {
    int r = it * 2 + (t >> 7);
    Q[((size_t)(pt0 + r)) * OO + (t & 127)] = tile[r][t & 127];
  }
}

// ---------------------------------------------------------------------------
// k_prep (Path B fallback): standalone prep pass.
// ---------------------------------------------------------------------------
__global__ __launch_bounds__(256) void k_prep(const float* __restrict__ x,
                                              ushort* __restrict__ xT,
                                              float* __restrict__ xTf,
                                              double* __restrict__ xx,
                                              float* __restrict__ xxf) {
  int i = blockIdx.x * 256 + threadIdx.x;
  int b = i >> 11, n = i & (NN - 1);
  const float* p = x + ((size_t)b * CC) * NN + n;
  ushort* rowp = xT + (size_t)i * CC;
  float* rowf = xTf + (size_t)i * CC;
  double s = 0.0;
#pragma unroll
  for (int c8 = 0; c8 < 8; ++c8) {
    float f[8];
    unsigned tmp[8];
#pragma unroll
    for (int e = 0; e < 8; ++e) {
      float v = p[(size_t)(c8 * 8 + e) * NN];
      f[e] = v;
      double dv = (double)v; s = fma(dv, dv, s);
      __bf16 h = (__bf16)v;
      ushort us; __builtin_memcpy(&us, &h, 2);
      tmp[e] = us;
    }
    uint4 pk;
    pk.x = tmp[0] | (tmp[1] << 16);
    pk.y = tmp[2] | (tmp[3] << 16);
    pk.z = tmp[4] | (tmp[5] << 16);
    pk.w = tmp[6] | (tmp[7] << 16);
    *(uint4*)(rowp + c8 * 8) = pk;
    *(float4*)(rowf + c8 * 8)     = make_float4(f[0], f[1], f[2], f[3]);
    *(float4*)(rowf + c8 * 8 + 4) = make_float4(f[4], f[5], f[6], f[7]);
  }
  xx[i] = s;
  xxf[i] = (float)s;
}

// ---------------------------------------------------------------------------
// k_pq (Path B fallback): P/Q GEMMs only.
// ---------------------------------------------------------------------------
__global__ __launch_bounds__(256) void k_pq(const float* __restrict__ x,
                                            const float* __restrict__ W,
                                            float* __restrict__ P,
                                            float* __restrict__ Q) {
  __shared__ float tile[64][OO + 1];
  const int t = threadIdx.x;
  const int jj = t & 63, og = t >> 6;
  const int pt0 = blockIdx.x * 64;
  const int b = pt0 >> 11;
  const int jn = (pt0 & (NN - 1)) + jj;

  float xcol[CC];
#pragma unroll
  for (int c = 0; c < CC; ++c) xcol[c] = x[((size_t)(b * CC + c) << 11) + jn];

  for (int oo = 0; oo < 32; ++oo) {
    int o = og * 32 + oo;
    const float* wr = W + (size_t)o * (2 * CC);
    float sp = 0.f;
#pragma unroll
    for (int c = 0; c < CC; ++c) sp = fmaf(wr[c], xcol[c], sp);
    tile[jj][o] = sp;
  }
  __syncthreads();
  for (int it = 0; it < 32; ++it) {
    int r = it * 2 + (t >> 7);
    P[((size_t)(pt0 + r)) * OO + (t & 127)] = tile[r][t & 127];
  }
  __syncthreads();
  for (int oo = 0; oo < 32; ++oo) {
    int o = og * 32 + oo;
    const float* wr = W + (size_t)o * (2 * CC);
    float sq = 0.f;
#pragma unroll
    for (int c = 0; c < CC; ++c) sq = fmaf(wr[CC + c] - wr[c], xcol[c], sq);
    tile[jj][o] = sq;
  }
  __syncthreads();
  for (int it = 0; it < 32; ++it) {
    int r = it * 2 + (t >> 7);
    Q[((size_t)(pt0 + r)) * OO + (t & 127)] = tile[r][t & 127];
  }
}

// ---------------------------------------------------------------------------
// k_knn: dual-row fused phase C (R11 structure) with __launch_bounds__(1024,2)
// — LDS caps residency at 16 waves/CU anyway, so relax the VGPR cap to let the
// dual key arrays + dual fp64 accs live in registers (R11 @ (1024,4) chose 64
// VGPR and spilled 6.4MB, nullifying the ILP).
// ---------------------------------------------------------------------------
#define TOP4(k, u0, u1, u2, u3) do { unsigned mx_, mn_;                 \
    mx_ = (k) > u0 ? (k) : u0; mn_ = (k) > u0 ? u0 : (k); u0 = mx_;     \
    mx_ = mn_ > u1 ? mn_ : u1; mn_ = mn_ > u1 ? u1 : mn_; u1 = mx_;     \
    mx_ = mn_ > u2 ? mn_ : u2; mn_ = mn_ > u2 ? u2 : mn_; u2 = mx_;     \
    u3 = mn_ > u3 ? mn_ : u3; } while (0)

#define EXACT_RADIX(keys, tau, mask, myc, pre, tot) do {                \
    tau = 0;                                                            \
    for (int bit_ = 15; bit_ >= 0; --bit_) {                            \
      unsigned cnd_ = tau | (1u << bit_);                               \
      int cc_ = 0;                                                      \
      _Pragma("unroll") for (int g_ = 0; g_ < 16; ++g_) {               \
        cc_ += ((keys[g_] & 0xffffu) >= cnd_) ? 1 : 0;                  \
        cc_ += ((keys[g_] >> 16) >= cnd_) ? 1 : 0;                      \
      }                                                                 \
      _Pragma("unroll") for (int off_ = 1; off_ < 64; off_ <<= 1)       \
        cc_ += __shfl_xor(cc_, off_, 64);                               \
      if (cc_ >= CANDT) tau = cnd_;                                     \
    }                                                                   \
    mask = 0;                                                           \
    _Pragma("unroll") for (int g_ = 0; g_ < 16; ++g_) {                 \
      mask |= ((keys[g_] & 0xffffu) >= tau ? 1u : 0u) << (2 * g_);      \
      mask |= ((keys[g_] >> 16) >= tau ? 1u : 0u) << (2 * g_ + 1);      \
    }                                                                   \
    myc = __popc(mask); pre = myc;                                      \
    _Pragma("unroll") for (int off_ = 1; off_ < 64; off_ <<= 1) {       \
      int o_ = __shfl_up(pre, off_, 64);                                \
      pre += (lane >= off_) ? o_ : 0;                                   \
    }                                                                   \
    tot = __shfl(pre, 63, 64); } while (0)

#define COMPACT(row, pre, myc, mask) do {                               \
    int slot_ = (pre) - (myc); unsigned m2_ = (mask);                   \
    while (m2_) {                                                       \
      int bp_ = __builtin_ctz(m2_); m2_ &= m2_ - 1;                     \
      if (slot_ < 64) CjS[row][slot_] = lane * 2 + ((bp_ >> 1) << 7) + (bp_ & 1); \
      ++slot_;                                                          \
    } } while (0)

__global__ __launch_bounds__(1024, 2) void k_knn(
    const ushort* __restrict__ xT, const float* __restrict__ xxf,
    const float* __restrict__ xTf, const double* __restrict__ xx,
    int* __restrict__ idx) {
  extern __shared__ char smem[];
  ushort (*Sb)[NN] = (ushort(*)[NN])smem;          // [32][2048] u16 keys 128KB
  int (*CjS)[64] = (int(*)[64])(smem + 32 * NN * 2);        // [32][64] 8KB
  double (*SdS)[64] = (double(*)[64])(smem + 32 * NN * 2 + 8192); // [32][64] 16KB
  const int t = threadIdx.x;
  const int w = t >> 6, lane = t & 63;
  const int bidswz = ((blockIdx.x & 7) << 6) + (blockIdx.x >> 3); // batch/XCD
  const int b = bidswz >> 6;
  const int i0 = (bidswz & 63) << 5;
  const int lr = lane & 31, lh = lane >> 5;
  const ushort* xTb = xT + (((size_t)b) << 11) * CC;

  // ---- Phase A: MFMA 32x32x16 ----
  f32x16 acc[4];
#pragma unroll
  for (int tt = 0; tt < 4; ++tt)
#pragma unroll
    for (int q = 0; q < 16; ++q) acc[tt][q] = 0.f;

  const ushort* Ap = xTb + (size_t)(i0 + lr) * CC + lh * 8;
  bf8v a0 = *(const bf8v*)(Ap);
  bf8v a1 = *(const bf8v*)(Ap + 16);
  bf8v a2 = *(const bf8v*)(Ap + 32);
  bf8v a3 = *(const bf8v*)(Ap + 48);
  const int j0w = w << 7;
#pragma unroll
  for (int tt = 0; tt < 4; ++tt) {
    const ushort* Bp = xTb + (size_t)(j0w + tt * 32 + lr) * CC + lh * 8;
    bf8v b0 = *(const bf8v*)(Bp);
    bf8v b1 = *(const bf8v*)(Bp + 16);
    bf8v b2 = *(const bf8v*)(Bp + 32);
    bf8v b3 = *(const bf8v*)(Bp + 48);
    acc[tt] = __builtin_amdgcn_mfma_f32_32x32x16_bf16(a0, b0, acc[tt], 0, 0, 0);
    acc[tt] = __builtin_amdgcn_mfma_f32_32x32x16_bf16(a1, b1, acc[tt], 0, 0, 0);
    acc[tt] = __builtin_amdgcn_mfma_f32_32x32x16_bf16(a2, b2, acc[tt], 0, 0, 0);
    acc[tt] = __builtin_amdgcn_mfma_f32_32x32x16_bf16(a3, b3, acc[tt], 0, 0, 0);
  }

  // ---- Phase B: f32 score -> monotone u16 key -> LDS ----
  const float* xxfb = xxf + (b << 11);
#pragma unroll
  for (int tt = 0; tt < 4; ++tt) {
    int j = j0w + tt * 32 + lr;
    float xv = xxfb[j];
#pragma unroll
    for (int q = 0; q < 16; ++q) {
      int rr = (q & 3) + 8 * (q >> 2) + 4 * lh;    // 32x32 C/D map (m74/m101)
      float sv = fmaf(2.f, acc[tt][q], -xv);
      unsigned u = __float_as_uint(sv);
      u ^= (0x80000000u | (unsigned)((int)u >> 31)); // monotone u32
      Sb[rr][j] = (ushort)(u >> 16);
    }
  }
  __syncthreads();

  // ---- Phase C: rows rrA=w, rrB=w+16 fully interleaved ----
  const float* xTfb = xTf + (((size_t)b) << 11) * CC;
  const double* xxb = xx + (b << 11);
  const int rrA = w, rrB = w + 16;
  const int irowA = i0 + rrA, irowB = i0 + rrB;

  unsigned keysA[16], keysB[16];
  unsigned tA0 = 0, tA1 = 0, tA2 = 0, tA3 = 0;
  unsigned tB0 = 0, tB1 = 0, tB2 = 0, tB3 = 0;
#pragma unroll
  for (int g = 0; g < 16; ++g) {
    unsigned rawA = *(const unsigned*)(&Sb[rrA][lane * 2 + g * 128]);
    unsigned rawB = *(const unsigned*)(&Sb[rrB][lane * 2 + g * 128]);
    keysA[g] = rawA; keysB[g] = rawB;
    unsigned kA0 = rawA & 0xffffu, kA1 = rawA >> 16;
    unsigned kB0 = rawB & 0xffffu, kB1 = rawB >> 16;
    TOP4(kA0, tA0, tA1, tA2, tA3);
    TOP4(kB0, tB0, tB1, tB2, tB3);
    TOP4(kA1, tA0, tA1, tA2, tA3);
    TOP4(kB1, tB0, tB1, tB2, tB3);
  }
  // dual MSB radix with capped (top-4) ballot counts
  unsigned tauA = 0, tauB = 0;
  for (int bit = 15; bit >= 0; --bit) {
    unsigned cA = tauA | (1u << bit), cB = tauB | (1u << bit);
    int totA_ = __popcll(__ballot(tA0 >= cA)) + __popcll(__ballot(tA1 >= cA)) +
                __popcll(__ballot(tA2 >= cA)) + __popcll(__ballot(tA3 >= cA));
    int totB_ = __popcll(__ballot(tB0 >= cB)) + __popcll(__ballot(tB1 >= cB)) +
                __popcll(__ballot(tB2 >= cB)) + __popcll(__ballot(tB3 >= cB));
    if (totA_ >= CANDT) tauA = cA;
    if (totB_ >= CANDT) tauB = cB;
  }
  // masks + dual prefix scan
  unsigned maskA = 0, maskB = 0;
#pragma unroll
  for (int g = 0; g < 16; ++g) {
    maskA |= ((keysA[g] & 0xffffu) >= tauA ? 1u : 0u) << (2 * g);
    maskA |= ((keysA[g] >> 16) >= tauA ? 1u : 0u) << (2 * g + 1);
    maskB |= ((keysB[g] & 0xffffu) >= tauB ? 1u : 0u) << (2 * g);
    maskB |= ((keysB[g] >> 16) >= tauB ? 1u : 0u) << (2 * g + 1);
  }
  int mycA = __popc(maskA), mycB = __popc(maskB);
  int preA = mycA, preB = mycB;
#pragma unroll
  for (int off = 1; off < 64; off <<= 1) {
    int oA = __shfl_up(preA, off, 64);
    int oB = __shfl_up(preB, off, 64);
    preA += (lane >= off) ? oA : 0;
    preB += (lane >= off) ? oB : 0;
  }
  int totA = __shfl(preA, 63, 64);
  int totB = __shfl(preB, 63, 64);
  if (totA > 64) EXACT_RADIX(keysA, tauA, maskA, mycA, preA, totA);  // cold
  if (totB > 64) EXACT_RADIX(keysB, tauB, maskB, mycB, preB, totB);  // cold
  COMPACT(rrA, preA, mycA, maskA);
  COMPACT(rrB, preB, mycB, maskB);
  const int cntA = totA > 64 ? 64 : totA;
  const int cntB = totB > 64 ? 64 : totB;

  // dual fp64 rescore (accumulation order identical to R3..R12)
  int jA = CjS[rrA][lane < cntA ? lane : 0];
  int jB = CjS[rrB][lane < cntB ? lane : 0];
  const float* xiA = xTfb + (size_t)irowA * CC;
  const float* xiB = xTfb + (size_t)irowB * CC;
  const float* xjA = xTfb + (size_t)jA * CC;
  const float* xjB = xTfb + (size_t)jB * CC;
  double dA0 = 0, dA1 = 0, dA2 = 0, dA3 = 0;
  double dB0 = 0, dB1 = 0, dB2 = 0, dB3 = 0;
#pragma unroll
  for (int c = 0; c < CC; c += 4) {
    float4 fiA = *(const float4*)(xiA + c);
    float4 fjA = *(const float4*)(xjA + c);
    float4 fiB = *(const float4*)(xiB + c);
    float4 fjB = *(const float4*)(xjB + c);
    dA0 = fma((double)fiA.x, (double)fjA.x, dA0);
    dB0 = fma((double)fiB.x, (double)fjB.x, dB0);
    dA1 = fma((double)fiA.y, (double)fjA.y, dA1);
    dB1 = fma((double)fiB.y, (double)fjB.y, dB1);
    dA2 = fma((double)fiA.z, (double)fjA.z, dA2);
    dB2 = fma((double)fiB.z, (double)fjB.z, dB2);
    dA3 = fma((double)fiA.w, (double)fjA.w, dA3);
    dB3 = fma((double)fiB.w, (double)fjB.w, dB3);
  }
  double scA = 2.0 * ((dA0 + dA1) + (dA2 + dA3)) - xxb[jA];
  double scB = 2.0 * ((dB0 + dB1) + (dB2 + dB3)) - xxb[jB];

  // dual rank via LDS broadcast reads (same-wave write->read, no barrier)
  SdS[rrA][lane] = scA;
  SdS[rrB][lane] = scB;
  int rankA = 0, rankB = 0;
  const int cmax = cntA > cntB ? cntA : cntB;
  for (int mm = 0; mm < cmax; ++mm) {
    int mA = mm < cntA ? mm : 0;
    int mB = mm < cntB ? mm : 0;
    double smA = SdS[rrA][mA]; int jmA = CjS[rrA][mA];
    double smB = SdS[rrB][mB]; int jmB = CjS[rrB][mB];
    if (mm < cntA) rankA += (smA > scA || (smA == scA && jmA < jA)) ? 1 : 0;
    if (mm < cntB) rankB += (smB > scB || (smB == scB && jmB < jB)) ? 1 : 0;
  }
  if (lane < cntA && rankA < KK)
    idx[(size_t)((b << 11) + irowA) * KK + rankA] = jA;
  if (lane < cntB && rankB < KK)
    idx[(size_t)((b << 11) + irowB) * KK + rankB] = jB;
}

// ---------------------------------------------------------------------------
// k_stats: per-o sum & sumsq of h = P[gather]+Q (+ vmax/vmin emit).
// ---------------------------------------------------------------------------
__global__ __launch_bounds__(256) void k_stats(const float* __restrict__ P,
                                               const float* __restrict__ Q,
                                               const int* __restrict__ idx,
                                               float* __restrict__ partial,
                                               float* __restrict__ vmaxA,
                                               float* __restrict__ vminA) {
  __shared__ int sIdx[16 * KK];                    // 320 ints
  __shared__ float red[512];
  const int t = threadIdx.x;
  const int o = t & 127, half = t >> 7;
  const int bid = (blockIdx.x & 7) * 128 + (blockIdx.x >> 3);
  const int pt0 = bid * 16;
  const int b = pt0 >> 11;
  if (t < 160)
    *(int2*)(sIdx + t * 2) = *(const int2*)(idx + (size_t)pt0 * KK + t * 2);
  __syncthreads();

  float s = 0.f, s2 = 0.f;
  for (int it = 0; it < 8; ++it) {
    int pl = it * 2 + half;
    int pt = pt0 + pl;
    float qv = Q[(size_t)pt * OO + o];
    const int* ip = sIdx + pl * KK;
    float vmax = -3.0e38f, vmin = 3.0e38f;
#pragma unroll
    for (int k = 0; k < KK; ++k) {
      float v = P[((size_t)((b << 11) + ip[k])) * OO + o] + qv;
      s += v;
      s2 = fmaf(v, v, s2);
      vmax = fmaxf(vmax, v);
      vmin = fminf(vmin, v);
    }
    if (vmaxA) {
      vmaxA[(size_t)pt * OO + o] = vmax;
      vminA[(size_t)pt * OO + o] = vmin;
    }
  }
  red[t] = s; red[256 + t] = s2;
  __syncthreads();
  if (t < 128) {
    partial[bid * 128 + o]               = red[t] + red[t + 128];
    partial[NPART * 128 + bid * 128 + o] = red[256 + t] + red[256 + t + 128];
  }
}

// ---------------------------------------------------------------------------
// k_fin: single-kernel BN finalize. 128 blocks (one per o).
// ---------------------------------------------------------------------------
__global__ __launch_bounds__(256) void k_fin(const float* __restrict__ partial,
                                             const float* __restrict__ gamma,
                                             const float* __restrict__ beta,
                                             float* __restrict__ ss) {
  __shared__ float red[2][256];
  const int o = blockIdx.x;
  const int t = threadIdx.x;
  float s = 0.f, s2 = 0.f;
  for (int blk = t; blk < NPART; blk += 256) {
    s  += partial[(size_t)blk * 128 + o];
    s2 += partial[(size_t)NPART * 128 + (size_t)blk * 128 + o];
  }
  red[0][t] = s; red[1][t] = s2;
  __syncthreads();
  for (int st = 128; st >= 1; st >>= 1) {
    if (t < st) { red[0][t] += red[0][t + st]; red[1][t] += red[1][t + st]; }
    __syncthreads();
  }
  if (t == 0) {
    float mean = red[0][0] * (1.0f / M_TOT);
    float var  = red[1][0] * (1.0f / M_TOT) - mean * mean;
    float rs = 1.0f / sqrtf(var + 1e-5f);
    float scale = gamma[o] * rs;
    ss[o] = scale;
    ss[128 + o] = beta[o] - mean * scale;
  }
}

// ---------------------------------------------------------------------------
// k_out: BN affine -> exact GELU -> max over k -> out[b][o][n].
// ---------------------------------------------------------------------------
__global__ __launch_bounds__(256) void k_out(const float* __restrict__ P,
                                             const float* __restrict__ Q,
                                             const int* __restrict__ idx,
                                             const float* __restrict__ ss,
                                             const float* __restrict__ vmaxA,
                                             const float* __restrict__ vminA,
                                             int use_minmax,
                                             float* __restrict__ out) {
  __shared__ float tile[64][OO + 1];
  const int t = threadIdx.x;
  const int o = t & 127, half = t >> 7;
  const int bid = (blockIdx.x & 7) * 32 + (blockIdx.x >> 3);
  const float scale = ss[o], shift = ss[128 + o];
  const int pt0 = bid * 64;
  const int b = pt0 >> 11;
  const float inv_sqrt2 = 0.70710678118654752f;
  for (int it = 0; it < 32; ++it) {
    int pl = it * 2 + half;
    int pt = pt0 + pl;
    float vmax, vmin;
    if (use_minmax) {
      vmax = vmaxA[(size_t)pt * OO + o];
      vmin = vminA[(size_t)pt * OO + o];
    } else {
      float qv = Q[(size_t)pt * OO + o];
      const int* ip = idx + (size_t)pt * KK;
      vmax = -3.0e38f; vmin = 3.0e38f;
#pragma unroll
      for (int k = 0; k < KK; ++k) {
        float v = P[((size_t)((b << 11) + ip[k])) * OO + o] + qv;
        vmax = fmaxf(vmax, v);
        vmin = fminf(vmin, v);
      }
    }
    float ymax, ymin;
    if (scale >= 0.f) { ymax = fmaf(vmax, scale, shift); ymin = fmaf(vmin, scale, shift); }
    else              { ymax = fmaf(vmin, scale, shift); ymin = fmaf(vmax, scale, shift); }
    float g;
    if (ymax > 0.f) {
      g = 0.5f * ymax * (1.0f + erff(ymax * inv_sqrt2));
    } else {
      float g1 = 0.5f * ymax * (1.0f + erff(ymax * inv_sqrt2));
      float g2 = 0.5f * ymin * (1.0f + erff(ymin * inv_sqrt2));
      g = fmaxf(g1, g2);
    }
    tile[pl][o] = g;
  }
  __syncthreads();
  const int n0 = pt0 & (NN - 1);
  for (int rep = 0; rep < 32; ++rep) {
    int oo = rep * 4 + (t >> 6);
    int nn = t & 63;
    out[((size_t)(b * OO + oo) << 11) + n0 + nn] = tile[nn][oo];
  }
}

// ---------------------------------------------------------------------------
extern "C" void kernel_launch(void* const* d_in, const int* in_sizes, int n_in,
                              void* d_out, int out_size, void* d_ws, size_t ws_size,
                              hipStream_t stream) {
  const float* x     = (const float*)d_in[0];
  const float* W     = (const float*)d_in[1];
  const float* gamma = (const float*)d_in[2];
  const float* beta  = (const float*)d_in[3];
  float* out = (float*)d_out;

  const int knn_lds = 32 * NN * 2 + 8192 + 16384;      // 155648 B
  hipFuncSetAttribute((const void*)k_knn,
                      hipFuncAttributeMaxDynamicSharedMemorySize, knn_lds);

  const size_t needA = 131072 + 65536 + 1310720 + (size_t)2 * NPART * 128 * 4 +
                       1024 + 4ull * 8388608;

  if (ws_size >= needA) {
    // Path A layout
    double* xx   = (double*)d_ws;                      // 131072 B
    float*  xxf  = (float*)(xx + BB * NN);             // 65536 B
    int*    idxp = (int*)(xxf + BB * NN);              // 1310720 B
    float*  part = (float*)(idxp + (size_t)BB * NN * KK); // 1 MB
    float*  ss   = part + 2 * NPART * 128;             // 1024 B
    float*  P    = ss + 256;                           // 8 MB
    float*  Q    = P + (size_t)BB * NN * OO;           // 8 MB
    float*  vmax = Q + (size_t)BB * NN * OO;           // 8 MB
    float*  vmin = vmax + (size_t)BB * NN * OO;        // 8 MB
    ushort* xT   = (ushort*)vmax;                      // 2 MB alias (pre-stats)
    float*  xTf  = vmax + (size_t)BB * NN * (CC / 2);  // 4 MB alias

    hipLaunchKernelGGL(k_pqprep, dim3(BB * NN / 32), dim3(256), 0, stream,
                       x, W, P, Q, xT, xTf, xx, xxf);
    hipLaunchKernelGGL(k_knn, dim3(BB * NN / 32), dim3(1024), knn_lds, stream,
                       xT, xxf, xTf, xx, idxp);
    hipLaunchKernelGGL(k_stats, dim3(NPART), dim3(256), 0, stream,
                       P, Q, idxp, part, vmax, vmin);
    hipLaunchKernelGGL(k_fin, dim3(128), dim3(256), 0, stream, part, gamma, beta, ss);
    hipLaunchKernelGGL(k_out, dim3(BB * NN / 64), dim3(256), 0, stream,
                       P, Q, idxp, ss, vmax, vmin, 1, out);
  } else {
    // Path B layout
    double* xx   = (double*)d_ws;
    int*    idxp = (int*)(xx + BB * NN);
    float*  P    = (float*)(idxp + (size_t)BB * NN * KK);
    float*  Q    = P + (size_t)BB * NN * OO;
    float*  part = Q + (size_t)BB * NN * OO;
    float*  ss   = part + 2 * NPART * 128;
    ushort* xT   = (ushort*)P;
    float*  xTf  = P + (size_t)BB * NN * (CC / 2);
    float*  xxf  = Q;

    hipLaunchKernelGGL(k_prep, dim3(BB * NN / 256), dim3(256), 0, stream,
                       x, xT, xTf, xx, xxf);
    hipLaunchKernelGGL(k_knn, dim3(BB * NN / 32), dim3(1024), knn_lds, stream,
                       xT, xxf, xTf, xx, idxp);
    hipLaunchKernelGGL(k_pq, dim3(BB * NN / 64), dim3(256), 0, stream, x, W, P, Q);
    hipLaunchKernelGGL(k_stats, dim3(NPART), dim3(256), 0, stream,
                       P, Q, idxp, part, (float*)nullptr, (float*)nullptr);
    hipLaunchKernelGGL(k_fin, dim3(128), dim3(256), 0, stream, part, gamma, beta, ss);
    hipLaunchKernelGGL(k_out, dim3(BB * NN / 64), dim3(256), 0, stream,
                       P, Q, idxp, ss, (const float*)nullptr, (const float*)nullptr, 0, out);
  }
}

// Round 14
// 163.028 us; speedup vs baseline: 2.6103x; 1.0262x over previous
//
#include <hip/hip_runtime.h>
#include <math.h>

#define BB 8
#define CC 64
#define NN 2048
#define KK 20
#define OO 128
#define CANDT 40
#define NPART 512          // = k_knn grid (stats fused there)
#define NPARTB 1024        // Path-B standalone k_stats grid
#define M_TOT 327680.0f    // B*N*K

typedef __attribute__((ext_vector_type(8))) __bf16 bf8v;
typedef __attribute__((ext_vector_type(16))) float f32x16;

// ---------------------------------------------------------------------------
// k_pqprep (Path A): P/Q GEMMs + bf16 xT rows + f32 xTf rows + xx/xxf norms.
// ---------------------------------------------------------------------------
__global__ __launch_bounds__(256) void k_pqprep(const float* __restrict__ x,
                                                const float* __restrict__ W,
                                                float* __restrict__ P,
                                                float* __restrict__ Q,
                                                ushort* __restrict__ xT,
                                                float* __restrict__ xTf,
                                                double* __restrict__ xx,
                                                float* __restrict__ xxf) {
  __shared__ float xs[32][CC + 1];                 // 8.3 KB
  __shared__ float tile[32][OO + 1];               // 16.5 KB
  const int t = threadIdx.x;
  const int jj = t & 31, og = t >> 5;              // 8 o-groups of 16
  const int pt0 = blockIdx.x * 32;
  const int b = pt0 >> 11;
  const int n0 = pt0 & (NN - 1);

#pragma unroll
  for (int r = 0; r < 2; ++r) {
    int seg = t + r * 256;
    int c = seg >> 3, n4 = (seg & 7) * 4;
    float4 v = *(const float4*)(x + ((size_t)(b * CC + c) << 11) + n0 + n4);
    xs[n4 + 0][c] = v.x; xs[n4 + 1][c] = v.y;
    xs[n4 + 2][c] = v.z; xs[n4 + 3][c] = v.w;
  }
  __syncthreads();

  if (t < 32) {                                    // prep outputs (1 pt/thread)
    int i = pt0 + t;
    ushort* rowp = xT + (size_t)i * CC;
    float* rowf = xTf + (size_t)i * CC;
    double s = 0.0;
#pragma unroll
    for (int c8 = 0; c8 < 8; ++c8) {
      unsigned tmp[8];
      float f[8];
#pragma unroll
      for (int e = 0; e < 8; ++e) {
        float v = xs[t][c8 * 8 + e];
        f[e] = v;
        double dv = (double)v; s = fma(dv, dv, s);
        __bf16 h = (__bf16)v;
        ushort us; __builtin_memcpy(&us, &h, 2);
        tmp[e] = us;
      }
      uint4 pk;
      pk.x = tmp[0] | (tmp[1] << 16);
      pk.y = tmp[2] | (tmp[3] << 16);
      pk.z = tmp[4] | (tmp[5] << 16);
      pk.w = tmp[6] | (tmp[7] << 16);
      *(uint4*)(rowp + c8 * 8) = pk;
      *(float4*)(rowf + c8 * 8)     = make_float4(f[0], f[1], f[2], f[3]);
      *(float4*)(rowf + c8 * 8 + 4) = make_float4(f[4], f[5], f[6], f[7]);
    }
    xx[i] = s;
    xxf[i] = (float)s;
  }

  for (int oo = 0; oo < 16; ++oo) {
    int o = og * 16 + oo;
    const float* wr = W + (size_t)o * (2 * CC);
    float sp = 0.f;
#pragma unroll
    for (int c = 0; c < CC; ++c) sp = fmaf(wr[c], xs[jj][c], sp);
    tile[jj][o] = sp;
  }
  __syncthreads();
  for (int it = 0; it < 16; ++it) {
    int r = it * 2 + (t >> 7);
    P[((size_t)(pt0 + r)) * OO + (t & 127)] = tile[r][t & 127];
  }
  __syncthreads();
  for (int oo = 0; oo < 16; ++oo) {
    int o = og * 16 + oo;
    const float* wr = W + (size_t)o * (2 * CC);
    float sq = 0.f;
#pragma unroll
    for (int c = 0; c < CC; ++c) sq = fmaf(wr[CC + c] - wr[c], xs[jj][c], sq);
    tile[jj][o] = sq;
  }
  __syncthreads();
  for (int it = 0; it < 16; ++it) {
    int r = it * 2 + (t >> 7);
    Q[((size_t)(pt0 + r)) * OO + (t & 127)] = tile[r][t & 127];
  }
}

// ---------------------------------------------------------------------------
// k_prep (Path B fallback): standalone prep pass.
// ---------------------------------------------------------------------------
__global__ __launch_bounds__(256) void k_prep(const float* __restrict__ x,
                                              ushort* __restrict__ xT,
                                              float* __restrict__ xTf,
                                              double* __restrict__ xx,
                                              float* __restrict__ xxf) {
  int i = blockIdx.x * 256 + threadIdx.x;
  int b = i >> 11, n = i & (NN - 1);
  const float* p = x + ((size_t)b * CC) * NN + n;
  ushort* rowp = xT + (size_t)i * CC;
  float* rowf = xTf + (size_t)i * CC;
  double s = 0.0;
#pragma unroll
  for (int c8 = 0; c8 < 8; ++c8) {
    float f[8];
    unsigned tmp[8];
#pragma unroll
    for (int e = 0; e < 8; ++e) {
      float v = p[(size_t)(c8 * 8 + e) * NN];
      f[e] = v;
      double dv = (double)v; s = fma(dv, dv, s);
      __bf16 h = (__bf16)v;
      ushort us; __builtin_memcpy(&us, &h, 2);
      tmp[e] = us;
    }
    uint4 pk;
    pk.x = tmp[0] | (tmp[1] << 16);
    pk.y = tmp[2] | (tmp[3] << 16);
    pk.z = tmp[4] | (tmp[5] << 16);
    pk.w = tmp[6] | (tmp[7] << 16);
    *(uint4*)(rowp + c8 * 8) = pk;
    *(float4*)(rowf + c8 * 8)     = make_float4(f[0], f[1], f[2], f[3]);
    *(float4*)(rowf + c8 * 8 + 4) = make_float4(f[4], f[5], f[6], f[7]);
  }
  xx[i] = s;
  xxf[i] = (float)s;
}

// ---------------------------------------------------------------------------
// k_pq (Path B fallback): P/Q GEMMs only.
// ---------------------------------------------------------------------------
__global__ __launch_bounds__(256) void k_pq(const float* __restrict__ x,
                                            const float* __restrict__ W,
                                            float* __restrict__ P,
                                            float* __restrict__ Q) {
  __shared__ float tile[64][OO + 1];
  const int t = threadIdx.x;
  const int jj = t & 63, og = t >> 6;
  const int pt0 = blockIdx.x * 64;
  const int b = pt0 >> 11;
  const int jn = (pt0 & (NN - 1)) + jj;

  float xcol[CC];
#pragma unroll
  for (int c = 0; c < CC; ++c) xcol[c] = x[((size_t)(b * CC + c) << 11) + jn];

  for (int oo = 0; oo < 32; ++oo) {
    int o = og * 32 + oo;
    const float* wr = W + (size_t)o * (2 * CC);
    float sp = 0.f;
#pragma unroll
    for (int c = 0; c < CC; ++c) sp = fmaf(wr[c], xcol[c], sp);
    tile[jj][o] = sp;
  }
  __syncthreads();
  for (int it = 0; it < 32; ++it) {
    int r = it * 2 + (t >> 7);
    P[((size_t)(pt0 + r)) * OO + (t & 127)] = tile[r][t & 127];
  }
  __syncthreads();
  for (int oo = 0; oo < 32; ++oo) {
    int o = og * 32 + oo;
    const float* wr = W + (size_t)o * (2 * CC);
    float sq = 0.f;
#pragma unroll
    for (int c = 0; c < CC; ++c) sq = fmaf(wr[CC + c] - wr[c], xcol[c], sq);
    tile[jj][o] = sq;
  }
  __syncthreads();
  for (int it = 0; it < 32; ++it) {
    int r = it * 2 + (t >> 7);
    Q[((size_t)(pt0 + r)) * OO + (t & 127)] = tile[r][t & 127];
  }
}

// ---------------------------------------------------------------------------
// k_knn (serial R12 phase C, spill-free) + FUSED gather-stats phase D.
// After phase C ranks the block's 32 rows, indices are also recorded in LDS
// (sIdxL); phase D gathers P[idx]+Q for those 32 points, emits vmax/vmin and
// the per-block BN partial sums — eliminating the standalone k_stats pass.
// Phase D overlaps k_knn's 62% idle issue slack (R10-R13: VALUBusy ~38%).
// ---------------------------------------------------------------------------
__global__ __launch_bounds__(1024, 4) void k_knn(
    const ushort* __restrict__ xT, const float* __restrict__ xxf,
    const float* __restrict__ xTf, const double* __restrict__ xx,
    int* __restrict__ idx, const float* __restrict__ P,
    const float* __restrict__ Q, float* __restrict__ partial,
    float* __restrict__ vmaxA, float* __restrict__ vminA) {
  extern __shared__ char smem[];
  ushort (*Sb)[NN] = (ushort(*)[NN])smem;          // [32][2048] u16 keys 128KB
  int* Cj = (int*)(smem + 32 * NN * 2);            // [16][64] 4KB
  double* Sd = (double*)(smem + 32 * NN * 2 + 4096); // [16][64] 8KB
  float* redF = (float*)Sd;                        // reuse as [2][8][128] in D
  int (*sIdxL)[KK] = (int(*)[KK])(smem + 32 * NN * 2 + 4096 + 8192); // 2.5KB
  const int t = threadIdx.x;
  const int w = t >> 6, lane = t & 63;
  const int bidswz = ((blockIdx.x & 7) << 6) + (blockIdx.x >> 3); // batch/XCD
  const int b = bidswz >> 6;
  const int i0 = (bidswz & 63) << 5;
  const int lr = lane & 31, lh = lane >> 5;
  const ushort* xTb = xT + (((size_t)b) << 11) * CC;

  // ---- Phase A: MFMA 32x32x16 ----
  f32x16 acc[4];
#pragma unroll
  for (int tt = 0; tt < 4; ++tt)
#pragma unroll
    for (int q = 0; q < 16; ++q) acc[tt][q] = 0.f;

  const ushort* Ap = xTb + (size_t)(i0 + lr) * CC + lh * 8;
  bf8v a0 = *(const bf8v*)(Ap);
  bf8v a1 = *(const bf8v*)(Ap + 16);
  bf8v a2 = *(const bf8v*)(Ap + 32);
  bf8v a3 = *(const bf8v*)(Ap + 48);
  const int j0w = w << 7;
#pragma unroll
  for (int tt = 0; tt < 4; ++tt) {
    const ushort* Bp = xTb + (size_t)(j0w + tt * 32 + lr) * CC + lh * 8;
    bf8v b0 = *(const bf8v*)(Bp);
    bf8v b1 = *(const bf8v*)(Bp + 16);
    bf8v b2 = *(const bf8v*)(Bp + 32);
    bf8v b3 = *(const bf8v*)(Bp + 48);
    acc[tt] = __builtin_amdgcn_mfma_f32_32x32x16_bf16(a0, b0, acc[tt], 0, 0, 0);
    acc[tt] = __builtin_amdgcn_mfma_f32_32x32x16_bf16(a1, b1, acc[tt], 0, 0, 0);
    acc[tt] = __builtin_amdgcn_mfma_f32_32x32x16_bf16(a2, b2, acc[tt], 0, 0, 0);
    acc[tt] = __builtin_amdgcn_mfma_f32_32x32x16_bf16(a3, b3, acc[tt], 0, 0, 0);
  }

  // ---- Phase B: f32 score -> monotone u16 key -> LDS ----
  const float* xxfb = xxf + (b << 11);
#pragma unroll
  for (int tt = 0; tt < 4; ++tt) {
    int j = j0w + tt * 32 + lr;
    float xv = xxfb[j];
#pragma unroll
    for (int q = 0; q < 16; ++q) {
      int rr = (q & 3) + 8 * (q >> 2) + 4 * lh;    // 32x32 C/D map (m74/m101)
      float sv = fmaf(2.f, acc[tt][q], -xv);
      unsigned u = __float_as_uint(sv);
      u ^= (0x80000000u | (unsigned)((int)u >> 31)); // monotone u32
      Sb[rr][j] = (ushort)(u >> 16);
    }
  }
  __syncthreads();

  // ---- Phase C: 2 rows per wave (serial, spill-free) ----
  const float* xTfb = xTf + (((size_t)b) << 11) * CC;
  const double* xxb = xx + (b << 11);
#pragma unroll 1
  for (int rw = 0; rw < 2; ++rw) {
    const int rr = w + 16 * rw;
    const int irow = i0 + rr;
    unsigned keys32[16];
    unsigned t0 = 0, t1 = 0, t2 = 0, t3 = 0;
#pragma unroll
    for (int g = 0; g < 16; ++g) {
      unsigned raw = *(const unsigned*)(&Sb[rr][lane * 2 + g * 128]);
      keys32[g] = raw;
      unsigned k0 = raw & 0xffffu, k1 = raw >> 16;
      unsigned mx, mn;
      mx = k0 > t0 ? k0 : t0; mn = k0 > t0 ? t0 : k0; t0 = mx;
      mx = mn > t1 ? mn : t1; mn = mn > t1 ? t1 : mn; t1 = mx;
      mx = mn > t2 ? mn : t2; mn = mn > t2 ? t2 : mn; t2 = mx;
      t3 = mn > t3 ? mn : t3;
      mx = k1 > t0 ? k1 : t0; mn = k1 > t0 ? t0 : k1; t0 = mx;
      mx = mn > t1 ? mn : t1; mn = mn > t1 ? t1 : mn; t1 = mx;
      mx = mn > t2 ? mn : t2; mn = mn > t2 ? t2 : mn; t2 = mx;
      t3 = mn > t3 ? mn : t3;
    }
    unsigned tau = 0;
    for (int bit = 15; bit >= 0; --bit) {
      unsigned cnd = tau | (1u << bit);
      int tot = __popcll(__ballot(t0 >= cnd)) + __popcll(__ballot(t1 >= cnd)) +
                __popcll(__ballot(t2 >= cnd)) + __popcll(__ballot(t3 >= cnd));
      if (tot >= CANDT) tau = cnd;
    }
    unsigned mask = 0;
#pragma unroll
    for (int g = 0; g < 16; ++g) {
      mask |= ((keys32[g] & 0xffffu) >= tau ? 1u : 0u) << (2 * g);
      mask |= ((keys32[g] >> 16) >= tau ? 1u : 0u) << (2 * g + 1);
    }
    int myc = __popc(mask);
    int pre = myc;
#pragma unroll
    for (int off = 1; off < 64; off <<= 1) {
      int o = __shfl_up(pre, off, 64);
      pre += (lane >= off) ? o : 0;
    }
    int tot = __shfl(pre, 63, 64);
    if (tot > 64) {                                // cold exact-radix fallback
      tau = 0;
      for (int bit = 15; bit >= 0; --bit) {
        unsigned cnd = tau | (1u << bit);
        int cc = 0;
#pragma unroll
        for (int g = 0; g < 16; ++g) {
          cc += ((keys32[g] & 0xffffu) >= cnd) ? 1 : 0;
          cc += ((keys32[g] >> 16) >= cnd) ? 1 : 0;
        }
#pragma unroll
        for (int off = 1; off < 64; off <<= 1) cc += __shfl_xor(cc, off, 64);
        if (cc >= CANDT) tau = cnd;
      }
      mask = 0;
#pragma unroll
      for (int g = 0; g < 16; ++g) {
        mask |= ((keys32[g] & 0xffffu) >= tau ? 1u : 0u) << (2 * g);
        mask |= ((keys32[g] >> 16) >= tau ? 1u : 0u) << (2 * g + 1);
      }
      myc = __popc(mask);
      pre = myc;
#pragma unroll
      for (int off = 1; off < 64; off <<= 1) {
        int o = __shfl_up(pre, off, 64);
        pre += (lane >= off) ? o : 0;
      }
      tot = __shfl(pre, 63, 64);
    }
    {
      int slot = pre - myc;
      unsigned m2 = mask;
      while (m2) {
        int bp = __builtin_ctz(m2); m2 &= m2 - 1;
        if (slot < 64) Cj[w * 64 + slot] = lane * 2 + ((bp >> 1) << 7) + (bp & 1);
        ++slot;
      }
    }
    int cnt = tot > 64 ? 64 : tot;
    int j = Cj[w * 64 + (lane < cnt ? lane : 0)];
    const float* xi = xTfb + (size_t)irow * CC;
    const float* xj = xTfb + (size_t)j * CC;
    double d0 = 0, d1 = 0, d2 = 0, d3 = 0;
#pragma unroll
    for (int c = 0; c < CC; c += 4) {
      float4 fi = *(const float4*)(xi + c);
      float4 fj = *(const float4*)(xj + c);
      d0 = fma((double)fi.x, (double)fj.x, d0);
      d1 = fma((double)fi.y, (double)fj.y, d1);
      d2 = fma((double)fi.z, (double)fj.z, d2);
      d3 = fma((double)fi.w, (double)fj.w, d3);
    }
    double sc = 2.0 * ((d0 + d1) + (d2 + d3)) - xxb[j];
    Sd[w * 64 + lane] = sc;
    int rank = 0;
#pragma unroll 4
    for (int mm = 0; mm < cnt; ++mm) {
      double sm = Sd[w * 64 + mm];
      int jm = Cj[w * 64 + mm];
      rank += (sm > sc || (sm == sc && jm < j)) ? 1 : 0;
    }
    if (lane < cnt && rank < KK) {
      idx[(size_t)((b << 11) + irow) * KK + rank] = j;
      sIdxL[rr][rank] = j;                         // for fused stats
    }
  }

  // ---- Phase D: fused gather-stats (skipped when P==nullptr, Path B) ----
  if (P != nullptr) {
    __syncthreads();                               // sIdxL complete; Sd free
    const int grp = t >> 7;                        // 0..7 (4 points each)
    const int o = t & 127;
    float s = 0.f, s2 = 0.f;
#pragma unroll
    for (int pp = 0; pp < 4; ++pp) {
      const int pl = grp * 4 + pp;                 // local row 0..31
      const int pt = (b << 11) + i0 + pl;          // global point
      float qv = Q[(size_t)pt * OO + o];
      float vmax = -3.0e38f, vmin = 3.0e38f;
#pragma unroll
      for (int k = 0; k < KK; ++k) {
        float v = P[((size_t)((b << 11) + sIdxL[pl][k])) * OO + o] + qv;
        s += v;
        s2 = fmaf(v, v, s2);
        vmax = fmaxf(vmax, v);
        vmin = fminf(vmin, v);
      }
      vmaxA[(size_t)pt * OO + o] = vmax;
      vminA[(size_t)pt * OO + o] = vmin;
    }
    redF[grp * 128 + o] = s;
    redF[1024 + grp * 128 + o] = s2;
    __syncthreads();
    if (t < 128) {
      float as = 0.f, as2 = 0.f;
#pragma unroll
      for (int g = 0; g < 8; ++g) {                // fixed order: deterministic
        as  += redF[g * 128 + t];
        as2 += redF[1024 + g * 128 + t];
      }
      partial[(size_t)bidswz * 128 + t]               = as;
      partial[(size_t)NPART * 128 + (size_t)bidswz * 128 + t] = as2;
    }
  }
}

// ---------------------------------------------------------------------------
// k_stats (Path B fallback): standalone gather-stats.
// ---------------------------------------------------------------------------
__global__ __launch_bounds__(256) void k_stats(const float* __restrict__ P,
                                               const float* __restrict__ Q,
                                               const int* __restrict__ idx,
                                               float* __restrict__ partial) {
  __shared__ int sIdx[16 * KK];
  __shared__ float red[512];
  const int t = threadIdx.x;
  const int o = t & 127, half = t >> 7;
  const int bid = (blockIdx.x & 7) * 128 + (blockIdx.x >> 3);
  const int pt0 = bid * 16;
  const int b = pt0 >> 11;
  if (t < 160)
    *(int2*)(sIdx + t * 2) = *(const int2*)(idx + (size_t)pt0 * KK + t * 2);
  __syncthreads();

  float s = 0.f, s2 = 0.f;
  for (int it = 0; it < 8; ++it) {
    int pl = it * 2 + half;
    int pt = pt0 + pl;
    float qv = Q[(size_t)pt * OO + o];
    const int* ip = sIdx + pl * KK;
#pragma unroll
    for (int k = 0; k < KK; ++k) {
      float v = P[((size_t)((b << 11) + ip[k])) * OO + o] + qv;
      s += v;
      s2 = fmaf(v, v, s2);
    }
  }
  red[t] = s; red[256 + t] = s2;
  __syncthreads();
  if (t < 128) {
    partial[bid * 128 + o]                = red[t] + red[t + 128];
    partial[NPARTB * 128 + bid * 128 + o] = red[256 + t] + red[256 + t + 128];
  }
}

// ---------------------------------------------------------------------------
// k_fin: single-kernel BN finalize. 128 blocks (one per o); npart variable.
// ---------------------------------------------------------------------------
__global__ __launch_bounds__(256) void k_fin(const float* __restrict__ partial,
                                             const float* __restrict__ gamma,
                                             const float* __restrict__ beta,
                                             float* __restrict__ ss, int npart) {
  __shared__ float red[2][256];
  const int o = blockIdx.x;
  const int t = threadIdx.x;
  float s = 0.f, s2 = 0.f;
  for (int blk = t; blk < npart; blk += 256) {
    s  += partial[(size_t)blk * 128 + o];
    s2 += partial[(size_t)npart * 128 + (size_t)blk * 128 + o];
  }
  red[0][t] = s; red[1][t] = s2;
  __syncthreads();
  for (int st = 128; st >= 1; st >>= 1) {
    if (t < st) { red[0][t] += red[0][t + st]; red[1][t] += red[1][t + st]; }
    __syncthreads();
  }
  if (t == 0) {
    float mean = red[0][0] * (1.0f / M_TOT);
    float var  = red[1][0] * (1.0f / M_TOT) - mean * mean;
    float rs = 1.0f / sqrtf(var + 1e-5f);
    float scale = gamma[o] * rs;
    ss[o] = scale;
    ss[128 + o] = beta[o] - mean * scale;
  }
}

// ---------------------------------------------------------------------------
// k_out: BN affine -> exact GELU -> max over k -> out[b][o][n].
// ---------------------------------------------------------------------------
__global__ __launch_bounds__(256) void k_out(const float* __restrict__ P,
                                             const float* __restrict__ Q,
                                             const int* __restrict__ idx,
                                             const float* __restrict__ ss,
                                             const float* __restrict__ vmaxA,
                                             const float* __restrict__ vminA,
                                             int use_minmax,
                                             float* __restrict__ out) {
  __shared__ float tile[64][OO + 1];
  const int t = threadIdx.x;
  const int o = t & 127, half = t >> 7;
  const int bid = (blockIdx.x & 7) * 32 + (blockIdx.x >> 3);
  const float scale = ss[o], shift = ss[128 + o];
  const int pt0 = bid * 64;
  const int b = pt0 >> 11;
  const float inv_sqrt2 = 0.70710678118654752f;
  for (int it = 0; it < 32; ++it) {
    int pl = it * 2 + half;
    int pt = pt0 + pl;
    float vmax, vmin;
    if (use_minmax) {
      vmax = vmaxA[(size_t)pt * OO + o];
      vmin = vminA[(size_t)pt * OO + o];
    } else {
      float qv = Q[(size_t)pt * OO + o];
      const int* ip = idx + (size_t)pt * KK;
      vmax = -3.0e38f; vmin = 3.0e38f;
#pragma unroll
      for (int k = 0; k < KK; ++k) {
        float v = P[((size_t)((b << 11) + ip[k])) * OO + o] + qv;
        vmax = fmaxf(vmax, v);
        vmin = fminf(vmin, v);
      }
    }
    float ymax, ymin;
    if (scale >= 0.f) { ymax = fmaf(vmax, scale, shift); ymin = fmaf(vmin, scale, shift); }
    else              { ymax = fmaf(vmin, scale, shift); ymin = fmaf(vmax, scale, shift); }
    float g;
    if (ymax > 0.f) {
      g = 0.5f * ymax * (1.0f + erff(ymax * inv_sqrt2));
    } else {
      float g1 = 0.5f * ymax * (1.0f + erff(ymax * inv_sqrt2));
      float g2 = 0.5f * ymin * (1.0f + erff(ymin * inv_sqrt2));
      g = fmaxf(g1, g2);
    }
    tile[pl][o] = g;
  }
  __syncthreads();
  const int n0 = pt0 & (NN - 1);
  for (int rep = 0; rep < 32; ++rep) {
    int oo = rep * 4 + (t >> 6);
    int nn = t & 63;
    out[((size_t)(b * OO + oo) << 11) + n0 + nn] = tile[nn][oo];
  }
}

// ---------------------------------------------------------------------------
extern "C" void kernel_launch(void* const* d_in, const int* in_sizes, int n_in,
                              void* d_out, int out_size, void* d_ws, size_t ws_size,
                              hipStream_t stream) {
  const float* x     = (const float*)d_in[0];
  const float* W     = (const float*)d_in[1];
  const float* gamma = (const float*)d_in[2];
  const float* beta  = (const float*)d_in[3];
  float* out = (float*)d_out;

  const int knn_lds = 32 * NN * 2 + 4096 + 8192 + 32 * KK * 4;  // 145920 B
  hipFuncSetAttribute((const void*)k_knn,
                      hipFuncAttributeMaxDynamicSharedMemorySize, knn_lds);

  const size_t needA = 131072 + 65536 + 1310720 + (size_t)2 * NPARTB * 128 * 4 +
                       1024 + 4ull * 8388608;

  if (ws_size >= needA) {
    // Path A layout
    double* xx   = (double*)d_ws;                      // 131072 B
    float*  xxf  = (float*)(xx + BB * NN);             // 65536 B
    int*    idxp = (int*)(xxf + BB * NN);              // 1310720 B
    float*  part = (float*)(idxp + (size_t)BB * NN * KK); // 1 MB (>= 2*512*128*4)
    float*  ss   = part + 2 * NPARTB * 128;            // 1024 B
    float*  P    = ss + 256;                           // 8 MB
    float*  Q    = P + (size_t)BB * NN * OO;           // 8 MB
    float*  vmax = Q + (size_t)BB * NN * OO;           // 8 MB
    float*  vmin = vmax + (size_t)BB * NN * OO;        // 8 MB
    ushort* xT   = (ushort*)vmax;                      // 2 MB alias (pre-knn-D)
    float*  xTf  = vmax + (size_t)BB * NN * (CC / 2);  // 4 MB alias

    // NOTE: k_knn phase D writes vmax/vmin which alias xT/xTf — but phases
    // A-C consume xT/xTf before D writes, and D only runs after C within the
    // same block... cross-block hazard! Block X's D could overwrite xT rows
    // that block Y's A still needs. => vmax/vmin must NOT alias xT/xTf.
    // Shift vmax/vmin past the alias region instead (ws is large enough:
    // idx(1.25MB)+part(1MB)+P,Q(16MB)+xT/xTf(6MB)+vmax/vmin(16MB) ~= 40.5MB).
    float* safe  = xTf + (size_t)BB * NN * CC;         // after xTf
    vmax = safe;
    vmin = vmax + (size_t)BB * NN * OO;
    const size_t needSafe = (size_t)((char*)(vmin + (size_t)BB * NN * OO) - (char*)d_ws);
    if (ws_size >= needSafe) {
      hipLaunchKernelGGL(k_pqprep, dim3(BB * NN / 32), dim3(256), 0, stream,
                         x, W, P, Q, xT, xTf, xx, xxf);
      hipLaunchKernelGGL(k_knn, dim3(BB * NN / 32), dim3(1024), knn_lds, stream,
                         xT, xxf, xTf, xx, idxp, P, Q, part, vmax, vmin);
      hipLaunchKernelGGL(k_fin, dim3(128), dim3(256), 0, stream, part, gamma, beta, ss, NPART);
      hipLaunchKernelGGL(k_out, dim3(BB * NN / 64), dim3(256), 0, stream,
                         P, Q, idxp, ss, vmax, vmin, 1, out);
      return;
    }
    // ws too small for safe vmax/vmin: fall through to gather-k_out variant
    hipLaunchKernelGGL(k_pqprep, dim3(BB * NN / 32), dim3(256), 0, stream,
                       x, W, P, Q, xT, xTf, xx, xxf);
    hipLaunchKernelGGL(k_knn, dim3(BB * NN / 32), dim3(1024), knn_lds, stream,
                       xT, xxf, xTf, xx, idxp,
                       (const float*)nullptr, (const float*)nullptr,
                       (float*)nullptr, (float*)nullptr, (float*)nullptr);
    hipLaunchKernelGGL(k_stats, dim3(NPARTB), dim3(256), 0, stream,
                       P, Q, idxp, part);
    hipLaunchKernelGGL(k_fin, dim3(128), dim3(256), 0, stream, part, gamma, beta, ss, NPARTB);
    hipLaunchKernelGGL(k_out, dim3(BB * NN / 64), dim3(256), 0, stream,
                       P, Q, idxp, ss, (const float*)nullptr, (const float*)nullptr, 0, out);
  } else {
    // Path B layout (minimal ws)
    double* xx   = (double*)d_ws;
    int*    idxp = (int*)(xx + BB * NN);
    float*  P    = (float*)(idxp + (size_t)BB * NN * KK);
    float*  Q    = P + (size_t)BB * NN * OO;
    float*  part = Q + (size_t)BB * NN * OO;
    float*  ss   = part + 2 * NPARTB * 128;
    ushort* xT   = (ushort*)P;
    float*  xTf  = P + (size_t)BB * NN * (CC / 2);
    float*  xxf  = Q;

    hipLaunchKernelGGL(k_prep, dim3(BB * NN / 256), dim3(256), 0, stream,
                       x, xT, xTf, xx, xxf);
    hipLaunchKernelGGL(k_knn, dim3(BB * NN / 32), dim3(1024), knn_lds, stream,
                       xT, xxf, xTf, xx, idxp,
                       (const float*)nullptr, (const float*)nullptr,
                       (float*)nullptr, (float*)nullptr, (float*)nullptr);
    hipLaunchKernelGGL(k_pq, dim3(BB * NN / 64), dim3(256), 0, stream, x, W, P, Q);
    hipLaunchKernelGGL(k_stats, dim3(NPARTB), dim3(256), 0, stream,
                       P, Q, idxp, part);
    hipLaunchKernelGGL(k_fin, dim3(128), dim3(256), 0, stream, part, gamma, beta, ss, NPARTB);
    hipLaunchKernelGGL(k_out, dim3(BB * NN / 64), dim3(256), 0, stream,
                       P, Q, idxp, ss, (const float*)nullptr, (const float*)nullptr, 0, out);
  }
}

// Round 15
// 129.664 us; speedup vs baseline: 3.2820x; 1.2573x over previous
//
#include <hip/hip_runtime.h>
#include <math.h>

#define BB 8
#define CC 64
#define NN 2048
#define KK 20
#define OO 128
#define CANDT 40
#define NPART 512          // = k_knn grid (stats fused there)
#define NPARTB 1024        // Path-B standalone k_stats grid
#define M_TOT 327680.0f    // B*N*K

typedef __attribute__((ext_vector_type(8))) __bf16 bf8v;
typedef __attribute__((ext_vector_type(16))) float f32x16;

// ---------------------------------------------------------------------------
// k_pqprep (Path A): P/Q GEMMs + bf16 xT rows + f32 xTf rows + xx/xxf norms.
// R15: GEMM loops read NOTHING per-element from LDS/L1 except a broadcast
// ds_read_b128 of W: xcol lives in 64 VGPRs (one-time b128 copy), W staged
// per-pass in LDS [o][c] (b128-aligned rows). R12-R14 version issued 2048
// scalar ds_read + 2048 L1 loads per thread (~27us LDS-issue-bound).
// FMA chain order (c=0..63 per o) preserved -> P/Q bit-identical.
// ---------------------------------------------------------------------------
__global__ __launch_bounds__(256, 4) void k_pqprep(const float* __restrict__ x,
                                                   const float* __restrict__ W,
                                                   float* __restrict__ P,
                                                   float* __restrict__ Q,
                                                   ushort* __restrict__ xT,
                                                   float* __restrict__ xTf,
                                                   double* __restrict__ xx,
                                                   float* __restrict__ xxf) {
  __shared__ float xs[32][68];                     // 8.7 KB (68 = 17*4, b128 ok)
  __shared__ float Wl[OO][68];                     // 34 KB (only [*][0..63] used)
  __shared__ float tile[32][OO + 1];               // 16.5 KB
  const int t = threadIdx.x;
  const int jj = t & 31, og = t >> 5;              // 8 o-groups of 16
  const int pt0 = blockIdx.x * 32;
  const int b = pt0 >> 11;
  const int n0 = pt0 & (NN - 1);

  // stage x[b][*][n0..n0+31] -> xs[pt][c]  (512 float4 segs, 2/thread)
#pragma unroll
  for (int r = 0; r < 2; ++r) {
    int seg = t + r * 256;
    int c = seg >> 3, n4 = (seg & 7) * 4;
    float4 v = *(const float4*)(x + ((size_t)(b * CC + c) << 11) + n0 + n4);
    xs[n4 + 0][c] = v.x; xs[n4 + 1][c] = v.y;
    xs[n4 + 2][c] = v.z; xs[n4 + 3][c] = v.w;
  }
  // stage W1 -> Wl[o][c] (2048 float4 segs, 8/thread)
#pragma unroll
  for (int r = 0; r < 8; ++r) {
    int seg = t + r * 256;                         // seg = o*16 + c4
    int o = seg >> 4, c4 = (seg & 15) * 4;
    *(float4*)(&Wl[o][c4]) = *(const float4*)(W + (size_t)o * (2 * CC) + c4);
  }
  __syncthreads();

  // xcol -> registers (16x ds_read_b128, one-time)
  float xcol[CC];
#pragma unroll
  for (int c = 0; c < CC; c += 4) {
    float4 v = *(const float4*)(&xs[jj][c]);
    xcol[c] = v.x; xcol[c + 1] = v.y; xcol[c + 2] = v.z; xcol[c + 3] = v.w;
  }

  if (t < 32) {                                    // prep outputs (1 pt/thread)
    int i = pt0 + t;
    ushort* rowp = xT + (size_t)i * CC;
    float* rowf = xTf + (size_t)i * CC;
    double s = 0.0;
#pragma unroll
    for (int c8 = 0; c8 < 8; ++c8) {
      unsigned tmp[8];
      float f[8];
#pragma unroll
      for (int e = 0; e < 8; ++e) {
        float v = xs[t][c8 * 8 + e];
        f[e] = v;
        double dv = (double)v; s = fma(dv, dv, s);
        __bf16 h = (__bf16)v;
        ushort us; __builtin_memcpy(&us, &h, 2);
        tmp[e] = us;
      }
      uint4 pk;
      pk.x = tmp[0] | (tmp[1] << 16);
      pk.y = tmp[2] | (tmp[3] << 16);
      pk.z = tmp[4] | (tmp[5] << 16);
      pk.w = tmp[6] | (tmp[7] << 16);
      *(uint4*)(rowp + c8 * 8) = pk;
      *(float4*)(rowf + c8 * 8)     = make_float4(f[0], f[1], f[2], f[3]);
      *(float4*)(rowf + c8 * 8 + 4) = make_float4(f[4], f[5], f[6], f[7]);
    }
    xx[i] = s;
    xxf[i] = (float)s;
  }

  // pass 1: P (Wl = W1; broadcast b128 reads; chain order c=0..63 preserved)
  for (int oo = 0; oo < 16; ++oo) {
    int o = og * 16 + oo;
    float sp = 0.f;
#pragma unroll
    for (int c = 0; c < CC; c += 4) {
      float4 wv = *(const float4*)(&Wl[o][c]);
      sp = fmaf(wv.x, xcol[c], sp);
      sp = fmaf(wv.y, xcol[c + 1], sp);
      sp = fmaf(wv.z, xcol[c + 2], sp);
      sp = fmaf(wv.w, xcol[c + 3], sp);
    }
    tile[jj][o] = sp;
  }
  __syncthreads();
  // P write (reads tile) + refill Wl with Wd = W2 - W1 (disjoint)
  for (int it = 0; it < 16; ++it) {
    int r = it * 2 + (t >> 7);
    P[((size_t)(pt0 + r)) * OO + (t & 127)] = tile[r][t & 127];
  }
#pragma unroll
  for (int r = 0; r < 8; ++r) {
    int seg = t + r * 256;
    int o = seg >> 4, c4 = (seg & 15) * 4;
    const float* wr = W + (size_t)o * (2 * CC);
    float4 w1 = *(const float4*)(wr + c4);
    float4 w2 = *(const float4*)(wr + CC + c4);
    float4 wd = make_float4(w2.x - w1.x, w2.y - w1.y, w2.z - w1.z, w2.w - w1.w);
    *(float4*)(&Wl[o][c4]) = wd;
  }
  __syncthreads();
  // pass 2: Q
  for (int oo = 0; oo < 16; ++oo) {
    int o = og * 16 + oo;
    float sq = 0.f;
#pragma unroll
    for (int c = 0; c < CC; c += 4) {
      float4 wv = *(const float4*)(&Wl[o][c]);
      sq = fmaf(wv.x, xcol[c], sq);
      sq = fmaf(wv.y, xcol[c + 1], sq);
      sq = fmaf(wv.z, xcol[c + 2], sq);
      sq = fmaf(wv.w, xcol[c + 3], sq);
    }
    tile[jj][o] = sq;
  }
  __syncthreads();
  for (int it = 0; it < 16; ++it) {
    int r = it * 2 + (t >> 7);
    Q[((size_t)(pt0 + r)) * OO + (t & 127)] = tile[r][t & 127];
  }
}

// ---------------------------------------------------------------------------
// k_prep (Path B fallback): standalone prep pass.
// ---------------------------------------------------------------------------
__global__ __launch_bounds__(256) void k_prep(const float* __restrict__ x,
                                              ushort* __restrict__ xT,
                                              float* __restrict__ xTf,
                                              double* __restrict__ xx,
                                              float* __restrict__ xxf) {
  int i = blockIdx.x * 256 + threadIdx.x;
  int b = i >> 11, n = i & (NN - 1);
  const float* p = x + ((size_t)b * CC) * NN + n;
  ushort* rowp = xT + (size_t)i * CC;
  float* rowf = xTf + (size_t)i * CC;
  double s = 0.0;
#pragma unroll
  for (int c8 = 0; c8 < 8; ++c8) {
    float f[8];
    unsigned tmp[8];
#pragma unroll
    for (int e = 0; e < 8; ++e) {
      float v = p[(size_t)(c8 * 8 + e) * NN];
      f[e] = v;
      double dv = (double)v; s = fma(dv, dv, s);
      __bf16 h = (__bf16)v;
      ushort us; __builtin_memcpy(&us, &h, 2);
      tmp[e] = us;
    }
    uint4 pk;
    pk.x = tmp[0] | (tmp[1] << 16);
    pk.y = tmp[2] | (tmp[3] << 16);
    pk.z = tmp[4] | (tmp[5] << 16);
    pk.w = tmp[6] | (tmp[7] << 16);
    *(uint4*)(rowp + c8 * 8) = pk;
    *(float4*)(rowf + c8 * 8)     = make_float4(f[0], f[1], f[2], f[3]);
    *(float4*)(rowf + c8 * 8 + 4) = make_float4(f[4], f[5], f[6], f[7]);
  }
  xx[i] = s;
  xxf[i] = (float)s;
}

// ---------------------------------------------------------------------------
// k_pq (Path B fallback): P/Q GEMMs only.
// ---------------------------------------------------------------------------
__global__ __launch_bounds__(256) void k_pq(const float* __restrict__ x,
                                            const float* __restrict__ W,
                                            float* __restrict__ P,
                                            float* __restrict__ Q) {
  __shared__ float tile[64][OO + 1];
  const int t = threadIdx.x;
  const int jj = t & 63, og = t >> 6;
  const int pt0 = blockIdx.x * 64;
  const int b = pt0 >> 11;
  const int jn = (pt0 & (NN - 1)) + jj;

  float xcol[CC];
#pragma unroll
  for (int c = 0; c < CC; ++c) xcol[c] = x[((size_t)(b * CC + c) << 11) + jn];

  for (int oo = 0; oo < 32; ++oo) {
    int o = og * 32 + oo;
    const float* wr = W + (size_t)o * (2 * CC);
    float sp = 0.f;
#pragma unroll
    for (int c = 0; c < CC; ++c) sp = fmaf(wr[c], xcol[c], sp);
    tile[jj][o] = sp;
  }
  __syncthreads();
  for (int it = 0; it < 32; ++it) {
    int r = it * 2 + (t >> 7);
    P[((size_t)(pt0 + r)) * OO + (t & 127)] = tile[r][t & 127];
  }
  __syncthreads();
  for (int oo = 0; oo < 32; ++oo) {
    int o = og * 32 + oo;
    const float* wr = W + (size_t)o * (2 * CC);
    float sq = 0.f;
#pragma unroll
    for (int c = 0; c < CC; ++c) sq = fmaf(wr[CC + c] - wr[c], xcol[c], sq);
    tile[jj][o] = sq;
  }
  __syncthreads();
  for (int it = 0; it < 32; ++it) {
    int r = it * 2 + (t >> 7);
    Q[((size_t)(pt0 + r)) * OO + (t & 127)] = tile[r][t & 127];
  }
}

// ---------------------------------------------------------------------------
// k_knn (R14: serial phase C + fused gather-stats phase D). UNCHANGED.
// ---------------------------------------------------------------------------
__global__ __launch_bounds__(1024, 4) void k_knn(
    const ushort* __restrict__ xT, const float* __restrict__ xxf,
    const float* __restrict__ xTf, const double* __restrict__ xx,
    int* __restrict__ idx, const float* __restrict__ P,
    const float* __restrict__ Q, float* __restrict__ partial,
    float* __restrict__ vmaxA, float* __restrict__ vminA) {
  extern __shared__ char smem[];
  ushort (*Sb)[NN] = (ushort(*)[NN])smem;          // [32][2048] u16 keys 128KB
  int* Cj = (int*)(smem + 32 * NN * 2);            // [16][64] 4KB
  double* Sd = (double*)(smem + 32 * NN * 2 + 4096); // [16][64] 8KB
  float* redF = (float*)Sd;                        // reuse as [2][8][128] in D
  int (*sIdxL)[KK] = (int(*)[KK])(smem + 32 * NN * 2 + 4096 + 8192); // 2.5KB
  const int t = threadIdx.x;
  const int w = t >> 6, lane = t & 63;
  const int bidswz = ((blockIdx.x & 7) << 6) + (blockIdx.x >> 3); // batch/XCD
  const int b = bidswz >> 6;
  const int i0 = (bidswz & 63) << 5;
  const int lr = lane & 31, lh = lane >> 5;
  const ushort* xTb = xT + (((size_t)b) << 11) * CC;

  // ---- Phase A: MFMA 32x32x16 ----
  f32x16 acc[4];
#pragma unroll
  for (int tt = 0; tt < 4; ++tt)
#pragma unroll
    for (int q = 0; q < 16; ++q) acc[tt][q] = 0.f;

  const ushort* Ap = xTb + (size_t)(i0 + lr) * CC + lh * 8;
  bf8v a0 = *(const bf8v*)(Ap);
  bf8v a1 = *(const bf8v*)(Ap + 16);
  bf8v a2 = *(const bf8v*)(Ap + 32);
  bf8v a3 = *(const bf8v*)(Ap + 48);
  const int j0w = w << 7;
#pragma unroll
  for (int tt = 0; tt < 4; ++tt) {
    const ushort* Bp = xTb + (size_t)(j0w + tt * 32 + lr) * CC + lh * 8;
    bf8v b0 = *(const bf8v*)(Bp);
    bf8v b1 = *(const bf8v*)(Bp + 16);
    bf8v b2 = *(const bf8v*)(Bp + 32);
    bf8v b3 = *(const bf8v*)(Bp + 48);
    acc[tt] = __builtin_amdgcn_mfma_f32_32x32x16_bf16(a0, b0, acc[tt], 0, 0, 0);
    acc[tt] = __builtin_amdgcn_mfma_f32_32x32x16_bf16(a1, b1, acc[tt], 0, 0, 0);
    acc[tt] = __builtin_amdgcn_mfma_f32_32x32x16_bf16(a2, b2, acc[tt], 0, 0, 0);
    acc[tt] = __builtin_amdgcn_mfma_f32_32x32x16_bf16(a3, b3, acc[tt], 0, 0, 0);
  }

  // ---- Phase B: f32 score -> monotone u16 key -> LDS ----
  const float* xxfb = xxf + (b << 11);
#pragma unroll
  for (int tt = 0; tt < 4; ++tt) {
    int j = j0w + tt * 32 + lr;
    float xv = xxfb[j];
#pragma unroll
    for (int q = 0; q < 16; ++q) {
      int rr = (q & 3) + 8 * (q >> 2) + 4 * lh;    // 32x32 C/D map (m74/m101)
      float sv = fmaf(2.f, acc[tt][q], -xv);
      unsigned u = __float_as_uint(sv);
      u ^= (0x80000000u | (unsigned)((int)u >> 31)); // monotone u32
      Sb[rr][j] = (ushort)(u >> 16);
    }
  }
  __syncthreads();

  // ---- Phase C: 2 rows per wave (serial, spill-free) ----
  const float* xTfb = xTf + (((size_t)b) << 11) * CC;
  const double* xxb = xx + (b << 11);
#pragma unroll 1
  for (int rw = 0; rw < 2; ++rw) {
    const int rr = w + 16 * rw;
    const int irow = i0 + rr;
    unsigned keys32[16];
    unsigned t0 = 0, t1 = 0, t2 = 0, t3 = 0;
#pragma unroll
    for (int g = 0; g < 16; ++g) {
      unsigned raw = *(const unsigned*)(&Sb[rr][lane * 2 + g * 128]);
      keys32[g] = raw;
      unsigned k0 = raw & 0xffffu, k1 = raw >> 16;
      unsigned mx, mn;
      mx = k0 > t0 ? k0 : t0; mn = k0 > t0 ? t0 : k0; t0 = mx;
      mx = mn > t1 ? mn : t1; mn = mn > t1 ? t1 : mn; t1 = mx;
      mx = mn > t2 ? mn : t2; mn = mn > t2 ? t2 : mn; t2 = mx;
      t3 = mn > t3 ? mn : t3;
      mx = k1 > t0 ? k1 : t0; mn = k1 > t0 ? t0 : k1; t0 = mx;
      mx = mn > t1 ? mn : t1; mn = mn > t1 ? t1 : mn; t1 = mx;
      mx = mn > t2 ? mn : t2; mn = mn > t2 ? t2 : mn; t2 = mx;
      t3 = mn > t3 ? mn : t3;
    }
    unsigned tau = 0;
    for (int bit = 15; bit >= 0; --bit) {
      unsigned cnd = tau | (1u << bit);
      int tot = __popcll(__ballot(t0 >= cnd)) + __popcll(__ballot(t1 >= cnd)) +
                __popcll(__ballot(t2 >= cnd)) + __popcll(__ballot(t3 >= cnd));
      if (tot >= CANDT) tau = cnd;
    }
    unsigned mask = 0;
#pragma unroll
    for (int g = 0; g < 16; ++g) {
      mask |= ((keys32[g] & 0xffffu) >= tau ? 1u : 0u) << (2 * g);
      mask |= ((keys32[g] >> 16) >= tau ? 1u : 0u) << (2 * g + 1);
    }
    int myc = __popc(mask);
    int pre = myc;
#pragma unroll
    for (int off = 1; off < 64; off <<= 1) {
      int o = __shfl_up(pre, off, 64);
      pre += (lane >= off) ? o : 0;
    }
    int tot = __shfl(pre, 63, 64);
    if (tot > 64) {                                // cold exact-radix fallback
      tau = 0;
      for (int bit = 15; bit >= 0; --bit) {
        unsigned cnd = tau | (1u << bit);
        int cc = 0;
#pragma unroll
        for (int g = 0; g < 16; ++g) {
          cc += ((keys32[g] & 0xffffu) >= cnd) ? 1 : 0;
          cc += ((keys32[g] >> 16) >= cnd) ? 1 : 0;
        }
#pragma unroll
        for (int off = 1; off < 64; off <<= 1) cc += __shfl_xor(cc, off, 64);
        if (cc >= CANDT) tau = cnd;
      }
      mask = 0;
#pragma unroll
      for (int g = 0; g < 16; ++g) {
        mask |= ((keys32[g] & 0xffffu) >= tau ? 1u : 0u) << (2 * g);
        mask |= ((keys32[g] >> 16) >= tau ? 1u : 0u) << (2 * g + 1);
      }
      myc = __popc(mask);
      pre = myc;
#pragma unroll
      for (int off = 1; off < 64; off <<= 1) {
        int o = __shfl_up(pre, off, 64);
        pre += (lane >= off) ? o : 0;
      }
      tot = __shfl(pre, 63, 64);
    }
    {
      int slot = pre - myc;
      unsigned m2 = mask;
      while (m2) {
        int bp = __builtin_ctz(m2); m2 &= m2 - 1;
        if (slot < 64) Cj[w * 64 + slot] = lane * 2 + ((bp >> 1) << 7) + (bp & 1);
        ++slot;
      }
    }
    int cnt = tot > 64 ? 64 : tot;
    int j = Cj[w * 64 + (lane < cnt ? lane : 0)];
    const float* xi = xTfb + (size_t)irow * CC;
    const float* xj = xTfb + (size_t)j * CC;
    double d0 = 0, d1 = 0, d2 = 0, d3 = 0;
#pragma unroll
    for (int c = 0; c < CC; c += 4) {
      float4 fi = *(const float4*)(xi + c);
      float4 fj = *(const float4*)(xj + c);
      d0 = fma((double)fi.x, (double)fj.x, d0);
      d1 = fma((double)fi.y, (double)fj.y, d1);
      d2 = fma((double)fi.z, (double)fj.z, d2);
      d3 = fma((double)fi.w, (double)fj.w, d3);
    }
    double sc = 2.0 * ((d0 + d1) + (d2 + d3)) - xxb[j];
    Sd[w * 64 + lane] = sc;
    int rank = 0;
#pragma unroll 4
    for (int mm = 0; mm < cnt; ++mm) {
      double sm = Sd[w * 64 + mm];
      int jm = Cj[w * 64 + mm];
      rank += (sm > sc || (sm == sc && jm < j)) ? 1 : 0;
    }
    if (lane < cnt && rank < KK) {
      idx[(size_t)((b << 11) + irow) * KK + rank] = j;
      sIdxL[rr][rank] = j;                         // for fused stats
    }
  }

  // ---- Phase D: fused gather-stats (skipped when P==nullptr, Path B) ----
  if (P != nullptr) {
    __syncthreads();                               // sIdxL complete; Sd free
    const int grp = t >> 7;                        // 0..7 (4 points each)
    const int o = t & 127;
    float s = 0.f, s2 = 0.f;
#pragma unroll
    for (int pp = 0; pp < 4; ++pp) {
      const int pl = grp * 4 + pp;                 // local row 0..31
      const int pt = (b << 11) + i0 + pl;          // global point
      float qv = Q[(size_t)pt * OO + o];
      float vmax = -3.0e38f, vmin = 3.0e38f;
#pragma unroll
      for (int k = 0; k < KK; ++k) {
        float v = P[((size_t)((b << 11) + sIdxL[pl][k])) * OO + o] + qv;
        s += v;
        s2 = fmaf(v, v, s2);
        vmax = fmaxf(vmax, v);
        vmin = fminf(vmin, v);
      }
      vmaxA[(size_t)pt * OO + o] = vmax;
      vminA[(size_t)pt * OO + o] = vmin;
    }
    redF[grp * 128 + o] = s;
    redF[1024 + grp * 128 + o] = s2;
    __syncthreads();
    if (t < 128) {
      float as = 0.f, as2 = 0.f;
#pragma unroll
      for (int g = 0; g < 8; ++g) {                // fixed order: deterministic
        as  += redF[g * 128 + t];
        as2 += redF[1024 + g * 128 + t];
      }
      partial[(size_t)bidswz * 128 + t]               = as;
      partial[(size_t)NPART * 128 + (size_t)bidswz * 128 + t] = as2;
    }
  }
}

// ---------------------------------------------------------------------------
// k_stats (Path B fallback): standalone gather-stats.
// ---------------------------------------------------------------------------
__global__ __launch_bounds__(256) void k_stats(const float* __restrict__ P,
                                               const float* __restrict__ Q,
                                               const int* __restrict__ idx,
                                               float* __restrict__ partial) {
  __shared__ int sIdx[16 * KK];
  __shared__ float red[512];
  const int t = threadIdx.x;
  const int o = t & 127, half = t >> 7;
  const int bid = (blockIdx.x & 7) * 128 + (blockIdx.x >> 3);
  const int pt0 = bid * 16;
  const int b = pt0 >> 11;
  if (t < 160)
    *(int2*)(sIdx + t * 2) = *(const int2*)(idx + (size_t)pt0 * KK + t * 2);
  __syncthreads();

  float s = 0.f, s2 = 0.f;
  for (int it = 0; it < 8; ++it) {
    int pl = it * 2 + half;
    int pt = pt0 + pl;
    float qv = Q[(size_t)pt * OO + o];
    const int* ip = sIdx + pl * KK;
#pragma unroll
    for (int k = 0; k < KK; ++k) {
      float v = P[((size_t)((b << 11) + ip[k])) * OO + o] + qv;
      s += v;
      s2 = fmaf(v, v, s2);
    }
  }
  red[t] = s; red[256 + t] = s2;
  __syncthreads();
  if (t < 128) {
    partial[bid * 128 + o]                = red[t] + red[t + 128];
    partial[NPARTB * 128 + bid * 128 + o] = red[256 + t] + red[256 + t + 128];
  }
}

// ---------------------------------------------------------------------------
// k_fin: single-kernel BN finalize. 128 blocks (one per o); npart variable.
// ---------------------------------------------------------------------------
__global__ __launch_bounds__(256) void k_fin(const float* __restrict__ partial,
                                             const float* __restrict__ gamma,
                                             const float* __restrict__ beta,
                                             float* __restrict__ ss, int npart) {
  __shared__ float red[2][256];
  const int o = blockIdx.x;
  const int t = threadIdx.x;
  float s = 0.f, s2 = 0.f;
  for (int blk = t; blk < npart; blk += 256) {
    s  += partial[(size_t)blk * 128 + o];
    s2 += partial[(size_t)npart * 128 + (size_t)blk * 128 + o];
  }
  red[0][t] = s; red[1][t] = s2;
  __syncthreads();
  for (int st = 128; st >= 1; st >>= 1) {
    if (t < st) { red[0][t] += red[0][t + st]; red[1][t] += red[1][t + st]; }
    __syncthreads();
  }
  if (t == 0) {
    float mean = red[0][0] * (1.0f / M_TOT);
    float var  = red[1][0] * (1.0f / M_TOT) - mean * mean;
    float rs = 1.0f / sqrtf(var + 1e-5f);
    float scale = gamma[o] * rs;
    ss[o] = scale;
    ss[128 + o] = beta[o] - mean * scale;
  }
}

// ---------------------------------------------------------------------------
// k_out: BN affine -> exact GELU -> max over k -> out[b][o][n].
// ---------------------------------------------------------------------------
__global__ __launch_bounds__(256) void k_out(const float* __restrict__ P,
                                             const float* __restrict__ Q,
                                             const int* __restrict__ idx,
                                             const float* __restrict__ ss,
                                             const float* __restrict__ vmaxA,
                                             const float* __restrict__ vminA,
                                             int use_minmax,
                                             float* __restrict__ out) {
  __shared__ float tile[64][OO + 1];
  const int t = threadIdx.x;
  const int o = t & 127, half = t >> 7;
  const int bid = (blockIdx.x & 7) * 32 + (blockIdx.x >> 3);
  const float scale = ss[o], shift = ss[128 + o];
  const int pt0 = bid * 64;
  const int b = pt0 >> 11;
  const float inv_sqrt2 = 0.70710678118654752f;
  for (int it = 0; it < 32; ++it) {
    int pl = it * 2 + half;
    int pt = pt0 + pl;
    float vmax, vmin;
    if (use_minmax) {
      vmax = vmaxA[(size_t)pt * OO + o];
      vmin = vminA[(size_t)pt * OO + o];
    } else {
      float qv = Q[(size_t)pt * OO + o];
      const int* ip = idx + (size_t)pt * KK;
      vmax = -3.0e38f; vmin = 3.0e38f;
#pragma unroll
      for (int k = 0; k < KK; ++k) {
        float v = P[((size_t)((b << 11) + ip[k])) * OO + o] + qv;
        vmax = fmaxf(vmax, v);
        vmin = fminf(vmin, v);
      }
    }
    float ymax, ymin;
    if (scale >= 0.f) { ymax = fmaf(vmax, scale, shift); ymin = fmaf(vmin, scale, shift); }
    else              { ymax = fmaf(vmin, scale, shift); ymin = fmaf(vmax, scale, shift); }
    float g;
    if (ymax > 0.f) {
      g = 0.5f * ymax * (1.0f + erff(ymax * inv_sqrt2));
    } else {
      float g1 = 0.5f * ymax * (1.0f + erff(ymax * inv_sqrt2));
      float g2 = 0.5f * ymin * (1.0f + erff(ymin * inv_sqrt2));
      g = fmaxf(g1, g2);
    }
    tile[pl][o] = g;
  }
  __syncthreads();
  const int n0 = pt0 & (NN - 1);
  for (int rep = 0; rep < 32; ++rep) {
    int oo = rep * 4 + (t >> 6);
    int nn = t & 63;
    out[((size_t)(b * OO + oo) << 11) + n0 + nn] = tile[nn][oo];
  }
}

// ---------------------------------------------------------------------------
extern "C" void kernel_launch(void* const* d_in, const int* in_sizes, int n_in,
                              void* d_out, int out_size, void* d_ws, size_t ws_size,
                              hipStream_t stream) {
  const float* x     = (const float*)d_in[0];
  const float* W     = (const float*)d_in[1];
  const float* gamma = (const float*)d_in[2];
  const float* beta  = (const float*)d_in[3];
  float* out = (float*)d_out;

  const int knn_lds = 32 * NN * 2 + 4096 + 8192 + 32 * KK * 4;  // 145920 B
  hipFuncSetAttribute((const void*)k_knn,
                      hipFuncAttributeMaxDynamicSharedMemorySize, knn_lds);

  const size_t needA = 131072 + 65536 + 1310720 + (size_t)2 * NPARTB * 128 * 4 +
                       1024 + 4ull * 8388608;

  if (ws_size >= needA) {
    // Path A layout
    double* xx   = (double*)d_ws;                      // 131072 B
    float*  xxf  = (float*)(xx + BB * NN);             // 65536 B
    int*    idxp = (int*)(xxf + BB * NN);              // 1310720 B
    float*  part = (float*)(idxp + (size_t)BB * NN * KK); // 1 MB
    float*  ss   = part + 2 * NPARTB * 128;            // 1024 B
    float*  P    = ss + 256;                           // 8 MB
    float*  Q    = P + (size_t)BB * NN * OO;           // 8 MB
    ushort* xT   = (ushort*)(Q + (size_t)BB * NN * OO);// 2 MB
    float*  xTf  = (float*)(xT + (size_t)BB * NN * CC);// 4 MB
    float*  vmax = xTf + (size_t)BB * NN * CC;         // 8 MB (no alias: knn-D)
    float*  vmin = vmax + (size_t)BB * NN * OO;        // 8 MB
    const size_t needSafe = (size_t)((char*)(vmin + (size_t)BB * NN * OO) - (char*)d_ws);
    if (ws_size >= needSafe) {
      hipLaunchKernelGGL(k_pqprep, dim3(BB * NN / 32), dim3(256), 0, stream,
                         x, W, P, Q, xT, xTf, xx, xxf);
      hipLaunchKernelGGL(k_knn, dim3(BB * NN / 32), dim3(1024), knn_lds, stream,
                         xT, xxf, xTf, xx, idxp, P, Q, part, vmax, vmin);
      hipLaunchKernelGGL(k_fin, dim3(128), dim3(256), 0, stream, part, gamma, beta, ss, NPART);
      hipLaunchKernelGGL(k_out, dim3(BB * NN / 64), dim3(256), 0, stream,
                         P, Q, idxp, ss, vmax, vmin, 1, out);
      return;
    }
    // ws too small for safe vmax/vmin: alias xT/xTf region, no fused stats
    ushort* xTa  = (ushort*)(Q + (size_t)BB * NN * OO);
    float*  xTfa = (float*)(xTa + (size_t)BB * NN * CC);
    hipLaunchKernelGGL(k_pqprep, dim3(BB * NN / 32), dim3(256), 0, stream,
                       x, W, P, Q, xTa, xTfa, xx, xxf);
    hipLaunchKernelGGL(k_knn, dim3(BB * NN / 32), dim3(1024), knn_lds, stream,
                       xTa, xxf, xTfa, xx, idxp,
                       (const float*)nullptr, (const float*)nullptr,
                       (float*)nullptr, (float*)nullptr, (float*)nullptr);
    hipLaunchKernelGGL(k_stats, dim3(NPARTB), dim3(256), 0, stream,
                       P, Q, idxp, part);
    hipLaunchKernelGGL(k_fin, dim3(128), dim3(256), 0, stream, part, gamma, beta, ss, NPARTB);
    hipLaunchKernelGGL(k_out, dim3(BB * NN / 64), dim3(256), 0, stream,
                       P, Q, idxp, ss, (const float*)nullptr, (const float*)nullptr, 0, out);
  } else {
    // Path B layout (minimal ws)
    double* xx   = (double*)d_ws;
    int*    idxp = (int*)(xx + BB * NN);
    float*  P    = (float*)(idxp + (size_t)BB * NN * KK);
    float*  Q    = P + (size_t)BB * NN * OO;
    float*  part = Q + (size_t)BB * NN * OO;
    float*  ss   = part + 2 * NPARTB * 128;
    ushort* xT   = (ushort*)P;
    float*  xTf  = P + (size_t)BB * NN * (CC / 2);
    float*  xxf  = Q;

    hipLaunchKernelGGL(k_prep, dim3(BB * NN / 256), dim3(256), 0, stream,
                       x, xT, xTf, xx, xxf);
    hipLaunchKernelGGL(k_knn, dim3(BB * NN / 32), dim3(1024), knn_lds, stream,
                       xT, xxf, xTf, xx, idxp,
                       (const float*)nullptr, (const float*)nullptr,
                       (float*)nullptr, (float*)nullptr, (float*)nullptr);
    hipLaunchKernelGGL(k_pq, dim3(BB * NN / 64), dim3(256), 0, stream, x, W, P, Q);
    hipLaunchKernelGGL(k_stats, dim3(NPARTB), dim3(256), 0, stream,
                       P, Q, idxp, part);
    hipLaunchKernelGGL(k_fin, dim3(128), dim3(256), 0, stream, part, gamma, beta, ss, NPARTB);
    hipLaunchKernelGGL(k_out, dim3(BB * NN / 64), dim3(256), 0, stream,
                       P, Q, idxp, ss, (const float*)nullptr, (const float*)nullptr, 0, out);
  }
}

// Round 16
// 121.814 us; speedup vs baseline: 3.4935x; 1.0644x over previous
//
#include <hip/hip_runtime.h>
#include <math.h>

#define BB 8
#define CC 64
#define NN 2048
#define KK 20
#define OO 128
#define CANDT 40
#define NPART 512          // = k_knn grid (stats fused there)
#define NPARTB 1024        // Path-B standalone k_stats grid
#define M_TOT 327680.0f    // B*N*K

typedef __attribute__((ext_vector_type(8))) __bf16 bf8v;
typedef __attribute__((ext_vector_type(16))) float f32x16;

// ---------------------------------------------------------------------------
// k_pqprep (Path A): P/Q GEMMs + bf16 xT rows + f32 xTf rows + xx/xxf norms.
// R15 form: xcol in regs, W staged in LDS (broadcast b128), chain order kept.
// ---------------------------------------------------------------------------
__global__ __launch_bounds__(256, 4) void k_pqprep(const float* __restrict__ x,
                                                   const float* __restrict__ W,
                                                   float* __restrict__ P,
                                                   float* __restrict__ Q,
                                                   ushort* __restrict__ xT,
                                                   float* __restrict__ xTf,
                                                   double* __restrict__ xx,
                                                   float* __restrict__ xxf) {
  __shared__ float xs[32][68];                     // 8.7 KB
  __shared__ float Wl[OO][68];                     // 34 KB
  __shared__ float tile[32][OO + 1];               // 16.5 KB
  const int t = threadIdx.x;
  const int jj = t & 31, og = t >> 5;              // 8 o-groups of 16
  const int pt0 = blockIdx.x * 32;
  const int b = pt0 >> 11;
  const int n0 = pt0 & (NN - 1);

#pragma unroll
  for (int r = 0; r < 2; ++r) {
    int seg = t + r * 256;
    int c = seg >> 3, n4 = (seg & 7) * 4;
    float4 v = *(const float4*)(x + ((size_t)(b * CC + c) << 11) + n0 + n4);
    xs[n4 + 0][c] = v.x; xs[n4 + 1][c] = v.y;
    xs[n4 + 2][c] = v.z; xs[n4 + 3][c] = v.w;
  }
#pragma unroll
  for (int r = 0; r < 8; ++r) {
    int seg = t + r * 256;                         // seg = o*16 + c4
    int o = seg >> 4, c4 = (seg & 15) * 4;
    *(float4*)(&Wl[o][c4]) = *(const float4*)(W + (size_t)o * (2 * CC) + c4);
  }
  __syncthreads();

  float xcol[CC];
#pragma unroll
  for (int c = 0; c < CC; c += 4) {
    float4 v = *(const float4*)(&xs[jj][c]);
    xcol[c] = v.x; xcol[c + 1] = v.y; xcol[c + 2] = v.z; xcol[c + 3] = v.w;
  }

  if (t < 32) {                                    // prep outputs (1 pt/thread)
    int i = pt0 + t;
    ushort* rowp = xT + (size_t)i * CC;
    float* rowf = xTf + (size_t)i * CC;
    double s = 0.0;
#pragma unroll
    for (int c8 = 0; c8 < 8; ++c8) {
      unsigned tmp[8];
      float f[8];
#pragma unroll
      for (int e = 0; e < 8; ++e) {
        float v = xs[t][c8 * 8 + e];
        f[e] = v;
        double dv = (double)v; s = fma(dv, dv, s);
        __bf16 h = (__bf16)v;
        ushort us; __builtin_memcpy(&us, &h, 2);
        tmp[e] = us;
      }
      uint4 pk;
      pk.x = tmp[0] | (tmp[1] << 16);
      pk.y = tmp[2] | (tmp[3] << 16);
      pk.z = tmp[4] | (tmp[5] << 16);
      pk.w = tmp[6] | (tmp[7] << 16);
      *(uint4*)(rowp + c8 * 8) = pk;
      *(float4*)(rowf + c8 * 8)     = make_float4(f[0], f[1], f[2], f[3]);
      *(float4*)(rowf + c8 * 8 + 4) = make_float4(f[4], f[5], f[6], f[7]);
    }
    xx[i] = s;
    xxf[i] = (float)s;
  }

  for (int oo = 0; oo < 16; ++oo) {
    int o = og * 16 + oo;
    float sp = 0.f;
#pragma unroll
    for (int c = 0; c < CC; c += 4) {
      float4 wv = *(const float4*)(&Wl[o][c]);
      sp = fmaf(wv.x, xcol[c], sp);
      sp = fmaf(wv.y, xcol[c + 1], sp);
      sp = fmaf(wv.z, xcol[c + 2], sp);
      sp = fmaf(wv.w, xcol[c + 3], sp);
    }
    tile[jj][o] = sp;
  }
  __syncthreads();
  for (int it = 0; it < 16; ++it) {
    int r = it * 2 + (t >> 7);
    P[((size_t)(pt0 + r)) * OO + (t & 127)] = tile[r][t & 127];
  }
#pragma unroll
  for (int r = 0; r < 8; ++r) {
    int seg = t + r * 256;
    int o = seg >> 4, c4 = (seg & 15) * 4;
    const float* wr = W + (size_t)o * (2 * CC);
    float4 w1 = *(const float4*)(wr + c4);
    float4 w2 = *(const float4*)(wr + CC + c4);
    float4 wd = make_float4(w2.x - w1.x, w2.y - w1.y, w2.z - w1.z, w2.w - w1.w);
    *(float4*)(&Wl[o][c4]) = wd;
  }
  __syncthreads();
  for (int oo = 0; oo < 16; ++oo) {
    int o = og * 16 + oo;
    float sq = 0.f;
#pragma unroll
    for (int c = 0; c < CC; c += 4) {
      float4 wv = *(const float4*)(&Wl[o][c]);
      sq = fmaf(wv.x, xcol[c], sq);
      sq = fmaf(wv.y, xcol[c + 1], sq);
      sq = fmaf(wv.z, xcol[c + 2], sq);
      sq = fmaf(wv.w, xcol[c + 3], sq);
    }
    tile[jj][o] = sq;
  }
  __syncthreads();
  for (int it = 0; it < 16; ++it) {
    int r = it * 2 + (t >> 7);
    Q[((size_t)(pt0 + r)) * OO + (t & 127)] = tile[r][t & 127];
  }
}

// ---------------------------------------------------------------------------
// k_prep (Path B fallback): standalone prep pass.
// ---------------------------------------------------------------------------
__global__ __launch_bounds__(256) void k_prep(const float* __restrict__ x,
                                              ushort* __restrict__ xT,
                                              float* __restrict__ xTf,
                                              double* __restrict__ xx,
                                              float* __restrict__ xxf) {
  int i = blockIdx.x * 256 + threadIdx.x;
  int b = i >> 11, n = i & (NN - 1);
  const float* p = x + ((size_t)b * CC) * NN + n;
  ushort* rowp = xT + (size_t)i * CC;
  float* rowf = xTf + (size_t)i * CC;
  double s = 0.0;
#pragma unroll
  for (int c8 = 0; c8 < 8; ++c8) {
    float f[8];
    unsigned tmp[8];
#pragma unroll
    for (int e = 0; e < 8; ++e) {
      float v = p[(size_t)(c8 * 8 + e) * NN];
      f[e] = v;
      double dv = (double)v; s = fma(dv, dv, s);
      __bf16 h = (__bf16)v;
      ushort us; __builtin_memcpy(&us, &h, 2);
      tmp[e] = us;
    }
    uint4 pk;
    pk.x = tmp[0] | (tmp[1] << 16);
    pk.y = tmp[2] | (tmp[3] << 16);
    pk.z = tmp[4] | (tmp[5] << 16);
    pk.w = tmp[6] | (tmp[7] << 16);
    *(uint4*)(rowp + c8 * 8) = pk;
    *(float4*)(rowf + c8 * 8)     = make_float4(f[0], f[1], f[2], f[3]);
    *(float4*)(rowf + c8 * 8 + 4) = make_float4(f[4], f[5], f[6], f[7]);
  }
  xx[i] = s;
  xxf[i] = (float)s;
}

// ---------------------------------------------------------------------------
// k_pq (Path B fallback): P/Q GEMMs only.
// ---------------------------------------------------------------------------
__global__ __launch_bounds__(256) void k_pq(const float* __restrict__ x,
                                            const float* __restrict__ W,
                                            float* __restrict__ P,
                                            float* __restrict__ Q) {
  __shared__ float tile[64][OO + 1];
  const int t = threadIdx.x;
  const int jj = t & 63, og = t >> 6;
  const int pt0 = blockIdx.x * 64;
  const int b = pt0 >> 11;
  const int jn = (pt0 & (NN - 1)) + jj;

  float xcol[CC];
#pragma unroll
  for (int c = 0; c < CC; ++c) xcol[c] = x[((size_t)(b * CC + c) << 11) + jn];

  for (int oo = 0; oo < 32; ++oo) {
    int o = og * 32 + oo;
    const float* wr = W + (size_t)o * (2 * CC);
    float sp = 0.f;
#pragma unroll
    for (int c = 0; c < CC; ++c) sp = fmaf(wr[c], xcol[c], sp);
    tile[jj][o] = sp;
  }
  __syncthreads();
  for (int it = 0; it < 32; ++it) {
    int r = it * 2 + (t >> 7);
    P[((size_t)(pt0 + r)) * OO + (t & 127)] = tile[r][t & 127];
  }
  __syncthreads();
  for (int oo = 0; oo < 32; ++oo) {
    int o = og * 32 + oo;
    const float* wr = W + (size_t)o * (2 * CC);
    float sq = 0.f;
#pragma unroll
    for (int c = 0; c < CC; ++c) sq = fmaf(wr[CC + c] - wr[c], xcol[c], sq);
    tile[jj][o] = sq;
  }
  __syncthreads();
  for (int it = 0; it < 32; ++it) {
    int r = it * 2 + (t >> 7);
    Q[((size_t)(pt0 + r)) * OO + (t & 127)] = tile[r][t & 127];
  }
}

// ---------------------------------------------------------------------------
// k_knn (R14: serial phase C + fused gather-stats phase D). UNCHANGED.
// ---------------------------------------------------------------------------
__global__ __launch_bounds__(1024, 4) void k_knn(
    const ushort* __restrict__ xT, const float* __restrict__ xxf,
    const float* __restrict__ xTf, const double* __restrict__ xx,
    int* __restrict__ idx, const float* __restrict__ P,
    const float* __restrict__ Q, float* __restrict__ partial,
    float* __restrict__ vmaxA, float* __restrict__ vminA) {
  extern __shared__ char smem[];
  ushort (*Sb)[NN] = (ushort(*)[NN])smem;          // [32][2048] u16 keys 128KB
  int* Cj = (int*)(smem + 32 * NN * 2);            // [16][64] 4KB
  double* Sd = (double*)(smem + 32 * NN * 2 + 4096); // [16][64] 8KB
  float* redF = (float*)Sd;                        // reuse as [2][8][128] in D
  int (*sIdxL)[KK] = (int(*)[KK])(smem + 32 * NN * 2 + 4096 + 8192); // 2.5KB
  const int t = threadIdx.x;
  const int w = t >> 6, lane = t & 63;
  const int bidswz = ((blockIdx.x & 7) << 6) + (blockIdx.x >> 3); // batch/XCD
  const int b = bidswz >> 6;
  const int i0 = (bidswz & 63) << 5;
  const int lr = lane & 31, lh = lane >> 5;
  const ushort* xTb = xT + (((size_t)b) << 11) * CC;

  // ---- Phase A: MFMA 32x32x16 ----
  f32x16 acc[4];
#pragma unroll
  for (int tt = 0; tt < 4; ++tt)
#pragma unroll
    for (int q = 0; q < 16; ++q) acc[tt][q] = 0.f;

  const ushort* Ap = xTb + (size_t)(i0 + lr) * CC + lh * 8;
  bf8v a0 = *(const bf8v*)(Ap);
  bf8v a1 = *(const bf8v*)(Ap + 16);
  bf8v a2 = *(const bf8v*)(Ap + 32);
  bf8v a3 = *(const bf8v*)(Ap + 48);
  const int j0w = w << 7;
#pragma unroll
  for (int tt = 0; tt < 4; ++tt) {
    const ushort* Bp = xTb + (size_t)(j0w + tt * 32 + lr) * CC + lh * 8;
    bf8v b0 = *(const bf8v*)(Bp);
    bf8v b1 = *(const bf8v*)(Bp + 16);
    bf8v b2 = *(const bf8v*)(Bp + 32);
    bf8v b3 = *(const bf8v*)(Bp + 48);
    acc[tt] = __builtin_amdgcn_mfma_f32_32x32x16_bf16(a0, b0, acc[tt], 0, 0, 0);
    acc[tt] = __builtin_amdgcn_mfma_f32_32x32x16_bf16(a1, b1, acc[tt], 0, 0, 0);
    acc[tt] = __builtin_amdgcn_mfma_f32_32x32x16_bf16(a2, b2, acc[tt], 0, 0, 0);
    acc[tt] = __builtin_amdgcn_mfma_f32_32x32x16_bf16(a3, b3, acc[tt], 0, 0, 0);
  }

  // ---- Phase B: f32 score -> monotone u16 key -> LDS ----
  const float* xxfb = xxf + (b << 11);
#pragma unroll
  for (int tt = 0; tt < 4; ++tt) {
    int j = j0w + tt * 32 + lr;
    float xv = xxfb[j];
#pragma unroll
    for (int q = 0; q < 16; ++q) {
      int rr = (q & 3) + 8 * (q >> 2) + 4 * lh;    // 32x32 C/D map (m74/m101)
      float sv = fmaf(2.f, acc[tt][q], -xv);
      unsigned u = __float_as_uint(sv);
      u ^= (0x80000000u | (unsigned)((int)u >> 31)); // monotone u32
      Sb[rr][j] = (ushort)(u >> 16);
    }
  }
  __syncthreads();

  // ---- Phase C: 2 rows per wave (serial, spill-free) ----
  const float* xTfb = xTf + (((size_t)b) << 11) * CC;
  const double* xxb = xx + (b << 11);
#pragma unroll 1
  for (int rw = 0; rw < 2; ++rw) {
    const int rr = w + 16 * rw;
    const int irow = i0 + rr;
    unsigned keys32[16];
    unsigned t0 = 0, t1 = 0, t2 = 0, t3 = 0;
#pragma unroll
    for (int g = 0; g < 16; ++g) {
      unsigned raw = *(const unsigned*)(&Sb[rr][lane * 2 + g * 128]);
      keys32[g] = raw;
      unsigned k0 = raw & 0xffffu, k1 = raw >> 16;
      unsigned mx, mn;
      mx = k0 > t0 ? k0 : t0; mn = k0 > t0 ? t0 : k0; t0 = mx;
      mx = mn > t1 ? mn : t1; mn = mn > t1 ? t1 : mn; t1 = mx;
      mx = mn > t2 ? mn : t2; mn = mn > t2 ? t2 : mn; t2 = mx;
      t3 = mn > t3 ? mn : t3;
      mx = k1 > t0 ? k1 : t0; mn = k1 > t0 ? t0 : k1; t0 = mx;
      mx = mn > t1 ? mn : t1; mn = mn > t1 ? t1 : mn; t1 = mx;
      mx = mn > t2 ? mn : t2; mn = mn > t2 ? t2 : mn; t2 = mx;
      t3 = mn > t3 ? mn : t3;
    }
    unsigned tau = 0;
    for (int bit = 15; bit >= 0; --bit) {
      unsigned cnd = tau | (1u << bit);
      int tot = __popcll(__ballot(t0 >= cnd)) + __popcll(__ballot(t1 >= cnd)) +
                __popcll(__ballot(t2 >= cnd)) + __popcll(__ballot(t3 >= cnd));
      if (tot >= CANDT) tau = cnd;
    }
    unsigned mask = 0;
#pragma unroll
    for (int g = 0; g < 16; ++g) {
      mask |= ((keys32[g] & 0xffffu) >= tau ? 1u : 0u) << (2 * g);
      mask |= ((keys32[g] >> 16) >= tau ? 1u : 0u) << (2 * g + 1);
    }
    int myc = __popc(mask);
    int pre = myc;
#pragma unroll
    for (int off = 1; off < 64; off <<= 1) {
      int o = __shfl_up(pre, off, 64);
      pre += (lane >= off) ? o : 0;
    }
    int tot = __shfl(pre, 63, 64);
    if (tot > 64) {                                // cold exact-radix fallback
      tau = 0;
      for (int bit = 15; bit >= 0; --bit) {
        unsigned cnd = tau | (1u << bit);
        int cc = 0;
#pragma unroll
        for (int g = 0; g < 16; ++g) {
          cc += ((keys32[g] & 0xffffu) >= cnd) ? 1 : 0;
          cc += ((keys32[g] >> 16) >= cnd) ? 1 : 0;
        }
#pragma unroll
        for (int off = 1; off < 64; off <<= 1) cc += __shfl_xor(cc, off, 64);
        if (cc >= CANDT) tau = cnd;
      }
      mask = 0;
#pragma unroll
      for (int g = 0; g < 16; ++g) {
        mask |= ((keys32[g] & 0xffffu) >= tau ? 1u : 0u) << (2 * g);
        mask |= ((keys32[g] >> 16) >= tau ? 1u : 0u) << (2 * g + 1);
      }
      myc = __popc(mask);
      pre = myc;
#pragma unroll
      for (int off = 1; off < 64; off <<= 1) {
        int o = __shfl_up(pre, off, 64);
        pre += (lane >= off) ? o : 0;
      }
      tot = __shfl(pre, 63, 64);
    }
    {
      int slot = pre - myc;
      unsigned m2 = mask;
      while (m2) {
        int bp = __builtin_ctz(m2); m2 &= m2 - 1;
        if (slot < 64) Cj[w * 64 + slot] = lane * 2 + ((bp >> 1) << 7) + (bp & 1);
        ++slot;
      }
    }
    int cnt = tot > 64 ? 64 : tot;
    int j = Cj[w * 64 + (lane < cnt ? lane : 0)];
    const float* xi = xTfb + (size_t)irow * CC;
    const float* xj = xTfb + (size_t)j * CC;
    double d0 = 0, d1 = 0, d2 = 0, d3 = 0;
#pragma unroll
    for (int c = 0; c < CC; c += 4) {
      float4 fi = *(const float4*)(xi + c);
      float4 fj = *(const float4*)(xj + c);
      d0 = fma((double)fi.x, (double)fj.x, d0);
      d1 = fma((double)fi.y, (double)fj.y, d1);
      d2 = fma((double)fi.z, (double)fj.z, d2);
      d3 = fma((double)fi.w, (double)fj.w, d3);
    }
    double sc = 2.0 * ((d0 + d1) + (d2 + d3)) - xxb[j];
    Sd[w * 64 + lane] = sc;
    int rank = 0;
#pragma unroll 4
    for (int mm = 0; mm < cnt; ++mm) {
      double sm = Sd[w * 64 + mm];
      int jm = Cj[w * 64 + mm];
      rank += (sm > sc || (sm == sc && jm < j)) ? 1 : 0;
    }
    if (lane < cnt && rank < KK) {
      idx[(size_t)((b << 11) + irow) * KK + rank] = j;
      sIdxL[rr][rank] = j;                         // for fused stats
    }
  }

  // ---- Phase D: fused gather-stats (skipped when P==nullptr, Path B) ----
  if (P != nullptr) {
    __syncthreads();                               // sIdxL complete; Sd free
    const int grp = t >> 7;                        // 0..7 (4 points each)
    const int o = t & 127;
    float s = 0.f, s2 = 0.f;
#pragma unroll
    for (int pp = 0; pp < 4; ++pp) {
      const int pl = grp * 4 + pp;                 // local row 0..31
      const int pt = (b << 11) + i0 + pl;          // global point
      float qv = Q[(size_t)pt * OO + o];
      float vmax = -3.0e38f, vmin = 3.0e38f;
#pragma unroll
      for (int k = 0; k < KK; ++k) {
        float v = P[((size_t)((b << 11) + sIdxL[pl][k])) * OO + o] + qv;
        s += v;
        s2 = fmaf(v, v, s2);
        vmax = fmaxf(vmax, v);
        vmin = fminf(vmin, v);
      }
      vmaxA[(size_t)pt * OO + o] = vmax;
      vminA[(size_t)pt * OO + o] = vmin;
    }
    redF[grp * 128 + o] = s;
    redF[1024 + grp * 128 + o] = s2;
    __syncthreads();
    if (t < 128) {
      float as = 0.f, as2 = 0.f;
#pragma unroll
      for (int g = 0; g < 8; ++g) {                // fixed order: deterministic
        as  += redF[g * 128 + t];
        as2 += redF[1024 + g * 128 + t];
      }
      partial[(size_t)bidswz * 128 + t]               = as;
      partial[(size_t)NPART * 128 + (size_t)bidswz * 128 + t] = as2;
    }
  }
}

// ---------------------------------------------------------------------------
// k_stats (Path B fallback): standalone gather-stats.
// ---------------------------------------------------------------------------
__global__ __launch_bounds__(256) void k_stats(const float* __restrict__ P,
                                               const float* __restrict__ Q,
                                               const int* __restrict__ idx,
                                               float* __restrict__ partial) {
  __shared__ int sIdx[16 * KK];
  __shared__ float red[512];
  const int t = threadIdx.x;
  const int o = t & 127, half = t >> 7;
  const int bid = (blockIdx.x & 7) * 128 + (blockIdx.x >> 3);
  const int pt0 = bid * 16;
  const int b = pt0 >> 11;
  if (t < 160)
    *(int2*)(sIdx + t * 2) = *(const int2*)(idx + (size_t)pt0 * KK + t * 2);
  __syncthreads();

  float s = 0.f, s2 = 0.f;
  for (int it = 0; it < 8; ++it) {
    int pl = it * 2 + half;
    int pt = pt0 + pl;
    float qv = Q[(size_t)pt * OO + o];
    const int* ip = sIdx + pl * KK;
#pragma unroll
    for (int k = 0; k < KK; ++k) {
      float v = P[((size_t)((b << 11) + ip[k])) * OO + o] + qv;
      s += v;
      s2 = fmaf(v, v, s2);
    }
  }
  red[t] = s; red[256 + t] = s2;
  __syncthreads();
  if (t < 128) {
    partial[bid * 128 + o]                = red[t] + red[t + 128];
    partial[NPARTB * 128 + bid * 128 + o] = red[256 + t] + red[256 + t + 128];
  }
}

// ---------------------------------------------------------------------------
// k_fin: single-kernel BN finalize. 128 blocks (one per o); npart variable.
// ---------------------------------------------------------------------------
__global__ __launch_bounds__(256) void k_fin(const float* __restrict__ partial,
                                             const float* __restrict__ gamma,
                                             const float* __restrict__ beta,
                                             float* __restrict__ ss, int npart) {
  __shared__ float red[2][256];
  const int o = blockIdx.x;
  const int t = threadIdx.x;
  float s = 0.f, s2 = 0.f;
  for (int blk = t; blk < npart; blk += 256) {
    s  += partial[(size_t)blk * 128 + o];
    s2 += partial[(size_t)npart * 128 + (size_t)blk * 128 + o];
  }
  red[0][t] = s; red[1][t] = s2;
  __syncthreads();
  for (int st = 128; st >= 1; st >>= 1) {
    if (t < st) { red[0][t] += red[0][t + st]; red[1][t] += red[1][t + st]; }
    __syncthreads();
  }
  if (t == 0) {
    float mean = red[0][0] * (1.0f / M_TOT);
    float var  = red[1][0] * (1.0f / M_TOT) - mean * mean;
    float rs = 1.0f / sqrtf(var + 1e-5f);
    float scale = gamma[o] * rs;
    ss[o] = scale;
    ss[128 + o] = beta[o] - mean * scale;
  }
}

// ---------------------------------------------------------------------------
// k_out: BN affine -> exact GELU -> max over k -> out[b][o][n].
// R16: 512 blocks x 32-pt tiles, __launch_bounds__(256,8) — 16.5KB LDS lets
// up to 8 blocks/CU reside vs R15's 1 (256 blocks, 33KB, 4 waves/SIMD):
// the serial {2 loads -> BN -> erf} chain was latency-bound at low occupancy.
// ---------------------------------------------------------------------------
__global__ __launch_bounds__(256, 8) void k_out(const float* __restrict__ P,
                                                const float* __restrict__ Q,
                                                const int* __restrict__ idx,
                                                const float* __restrict__ ss,
                                                const float* __restrict__ vmaxA,
                                                const float* __restrict__ vminA,
                                                int use_minmax,
                                                float* __restrict__ out) {
  __shared__ float tile[32][OO + 1];               // 16.5 KB
  const int t = threadIdx.x;
  const int o = t & 127, half = t >> 7;
  const int bid = (blockIdx.x & 7) * 64 + (blockIdx.x >> 3);   // batch/XCD
  const float scale = ss[o], shift = ss[128 + o];
  const int pt0 = bid * 32;
  const int b = pt0 >> 11;
  const float inv_sqrt2 = 0.70710678118654752f;
  for (int it = 0; it < 16; ++it) {
    int pl = it * 2 + half;
    int pt = pt0 + pl;
    float vmax, vmin;
    if (use_minmax) {
      vmax = vmaxA[(size_t)pt * OO + o];
      vmin = vminA[(size_t)pt * OO + o];
    } else {
      float qv = Q[(size_t)pt * OO + o];
      const int* ip = idx + (size_t)pt * KK;
      vmax = -3.0e38f; vmin = 3.0e38f;
#pragma unroll
      for (int k = 0; k < KK; ++k) {
        float v = P[((size_t)((b << 11) + ip[k])) * OO + o] + qv;
        vmax = fmaxf(vmax, v);
        vmin = fminf(vmin, v);
      }
    }
    float ymax, ymin;
    if (scale >= 0.f) { ymax = fmaf(vmax, scale, shift); ymin = fmaf(vmin, scale, shift); }
    else              { ymax = fmaf(vmin, scale, shift); ymin = fmaf(vmax, scale, shift); }
    float g;
    if (ymax > 0.f) {
      g = 0.5f * ymax * (1.0f + erff(ymax * inv_sqrt2));
    } else {
      float g1 = 0.5f * ymax * (1.0f + erff(ymax * inv_sqrt2));
      float g2 = 0.5f * ymin * (1.0f + erff(ymin * inv_sqrt2));
      g = fmaxf(g1, g2);
    }
    tile[pl][o] = g;
  }
  __syncthreads();
  const int n0 = pt0 & (NN - 1);
  for (int rep = 0; rep < 16; ++rep) {
    int oo = rep * 8 + (t >> 5);
    int nn = t & 31;
    out[((size_t)(b * OO + oo) << 11) + n0 + nn] = tile[nn][oo];
  }
}

// ---------------------------------------------------------------------------
extern "C" void kernel_launch(void* const* d_in, const int* in_sizes, int n_in,
                              void* d_out, int out_size, void* d_ws, size_t ws_size,
                              hipStream_t stream) {
  const float* x     = (const float*)d_in[0];
  const float* W     = (const float*)d_in[1];
  const float* gamma = (const float*)d_in[2];
  const float* beta  = (const float*)d_in[3];
  float* out = (float*)d_out;

  const int knn_lds = 32 * NN * 2 + 4096 + 8192 + 32 * KK * 4;  // 145920 B
  hipFuncSetAttribute((const void*)k_knn,
                      hipFuncAttributeMaxDynamicSharedMemorySize, knn_lds);

  const size_t needA = 131072 + 65536 + 1310720 + (size_t)2 * NPARTB * 128 * 4 +
                       1024 + 4ull * 8388608;

  if (ws_size >= needA) {
    // Path A layout
    double* xx   = (double*)d_ws;                      // 131072 B
    float*  xxf  = (float*)(xx + BB * NN);             // 65536 B
    int*    idxp = (int*)(xxf + BB * NN);              // 1310720 B
    float*  part = (float*)(idxp + (size_t)BB * NN * KK); // 1 MB
    float*  ss   = part + 2 * NPARTB * 128;            // 1024 B
    float*  P    = ss + 256;                           // 8 MB
    float*  Q    = P + (size_t)BB * NN * OO;           // 8 MB
    ushort* xT   = (ushort*)(Q + (size_t)BB * NN * OO);// 2 MB
    float*  xTf  = (float*)(xT + (size_t)BB * NN * CC);// 4 MB
    float*  vmax = xTf + (size_t)BB * NN * CC;         // 8 MB (no alias: knn-D)
    float*  vmin = vmax + (size_t)BB * NN * OO;        // 8 MB
    const size_t needSafe = (size_t)((char*)(vmin + (size_t)BB * NN * OO) - (char*)d_ws);
    if (ws_size >= needSafe) {
      hipLaunchKernelGGL(k_pqprep, dim3(BB * NN / 32), dim3(256), 0, stream,
                         x, W, P, Q, xT, xTf, xx, xxf);
      hipLaunchKernelGGL(k_knn, dim3(BB * NN / 32), dim3(1024), knn_lds, stream,
                         xT, xxf, xTf, xx, idxp, P, Q, part, vmax, vmin);
      hipLaunchKernelGGL(k_fin, dim3(128), dim3(256), 0, stream, part, gamma, beta, ss, NPART);
      hipLaunchKernelGGL(k_out, dim3(BB * NN / 32), dim3(256), 0, stream,
                         P, Q, idxp, ss, vmax, vmin, 1, out);
      return;
    }
    // ws too small for safe vmax/vmin: alias xT/xTf region, no fused stats
    ushort* xTa  = (ushort*)(Q + (size_t)BB * NN * OO);
    float*  xTfa = (float*)(xTa + (size_t)BB * NN * CC);
    hipLaunchKernelGGL(k_pqprep, dim3(BB * NN / 32), dim3(256), 0, stream,
                       x, W, P, Q, xTa, xTfa, xx, xxf);
    hipLaunchKernelGGL(k_knn, dim3(BB * NN / 32), dim3(1024), knn_lds, stream,
                       xTa, xxf, xTfa, xx, idxp,
                       (const float*)nullptr, (const float*)nullptr,
                       (float*)nullptr, (float*)nullptr, (float*)nullptr);
    hipLaunchKernelGGL(k_stats, dim3(NPARTB), dim3(256), 0, stream,
                       P, Q, idxp, part);
    hipLaunchKernelGGL(k_fin, dim3(128), dim3(256), 0, stream, part, gamma, beta, ss, NPARTB);
    hipLaunchKernelGGL(k_out, dim3(BB * NN / 32), dim3(256), 0, stream,
                       P, Q, idxp, ss, (const float*)nullptr, (const float*)nullptr, 0, out);
  } else {
    // Path B layout (minimal ws)
    double* xx   = (double*)d_ws;
    int*    idxp = (int*)(xx + BB * NN);
    float*  P    = (float*)(idxp + (size_t)BB * NN * KK);
    float*  Q    = P + (size_t)BB * NN * OO;
    float*  part = Q + (size_t)BB * NN * OO;
    float*  ss   = part + 2 * NPARTB * 128;
    ushort* xT   = (ushort*)P;
    float*  xTf  = P + (size_t)BB * NN * (CC / 2);
    float*  xxf  = Q;

    hipLaunchKernelGGL(k_prep, dim3(BB * NN / 256), dim3(256), 0, stream,
                       x, xT, xTf, xx, xxf);
    hipLaunchKernelGGL(k_knn, dim3(BB * NN / 32), dim3(1024), knn_lds, stream,
                       xT, xxf, xTf, xx, idxp,
                       (const float*)nullptr, (const float*)nullptr,
                       (float*)nullptr, (float*)nullptr, (float*)nullptr);
    hipLaunchKernelGGL(k_pq, dim3(BB * NN / 64), dim3(256), 0, stream, x, W, P, Q);
    hipLaunchKernelGGL(k_stats, dim3(NPARTB), dim3(256), 0, stream,
                       P, Q, idxp, part);
    hipLaunchKernelGGL(k_fin, dim3(128), dim3(256), 0, stream, part, gamma, beta, ss, NPARTB);
    hipLaunchKernelGGL(k_out, dim3(BB * NN / 32), dim3(256), 0, stream,
                       P, Q, idxp, ss, (const float*)nullptr, (const float*)nullptr, 0, out);
  }
}

// Round 17
// 115.575 us; speedup vs baseline: 3.6821x; 1.0540x over previous
//
#include <hip/hip_runtime.h>
#include <math.h>

#define BB 8
#define CC 64
#define NN 2048
#define KK 20
#define OO 128
#define CANDT 28
#define NPART 512          // = k_knn grid (stats fused there)
#define NPARTB 1024        // Path-B standalone k_stats grid
#define M_TOT 327680.0f    // B*N*K

typedef __attribute__((ext_vector_type(8))) __bf16 bf8v;
typedef __attribute__((ext_vector_type(16))) float f32x16;

// ---------------------------------------------------------------------------
// k_pqprep (Path A): P/Q GEMMs + bf16 xT rows + f32 xTf rows + xx/xxf norms.
// R15 form: xcol in regs, W staged in LDS (broadcast b128), chain order kept.
// ---------------------------------------------------------------------------
__global__ __launch_bounds__(256, 4) void k_pqprep(const float* __restrict__ x,
                                                   const float* __restrict__ W,
                                                   float* __restrict__ P,
                                                   float* __restrict__ Q,
                                                   ushort* __restrict__ xT,
                                                   float* __restrict__ xTf,
                                                   double* __restrict__ xx,
                                                   float* __restrict__ xxf) {
  __shared__ float xs[32][68];                     // 8.7 KB
  __shared__ float Wl[OO][68];                     // 34 KB
  __shared__ float tile[32][OO + 1];               // 16.5 KB
  const int t = threadIdx.x;
  const int jj = t & 31, og = t >> 5;              // 8 o-groups of 16
  const int pt0 = blockIdx.x * 32;
  const int b = pt0 >> 11;
  const int n0 = pt0 & (NN - 1);

#pragma unroll
  for (int r = 0; r < 2; ++r) {
    int seg = t + r * 256;
    int c = seg >> 3, n4 = (seg & 7) * 4;
    float4 v = *(const float4*)(x + ((size_t)(b * CC + c) << 11) + n0 + n4);
    xs[n4 + 0][c] = v.x; xs[n4 + 1][c] = v.y;
    xs[n4 + 2][c] = v.z; xs[n4 + 3][c] = v.w;
  }
#pragma unroll
  for (int r = 0; r < 8; ++r) {
    int seg = t + r * 256;                         // seg = o*16 + c4
    int o = seg >> 4, c4 = (seg & 15) * 4;
    *(float4*)(&Wl[o][c4]) = *(const float4*)(W + (size_t)o * (2 * CC) + c4);
  }
  __syncthreads();

  float xcol[CC];
#pragma unroll
  for (int c = 0; c < CC; c += 4) {
    float4 v = *(const float4*)(&xs[jj][c]);
    xcol[c] = v.x; xcol[c + 1] = v.y; xcol[c + 2] = v.z; xcol[c + 3] = v.w;
  }

  if (t < 32) {                                    // prep outputs (1 pt/thread)
    int i = pt0 + t;
    ushort* rowp = xT + (size_t)i * CC;
    float* rowf = xTf + (size_t)i * CC;
    double s = 0.0;
#pragma unroll
    for (int c8 = 0; c8 < 8; ++c8) {
      unsigned tmp[8];
      float f[8];
#pragma unroll
      for (int e = 0; e < 8; ++e) {
        float v = xs[t][c8 * 8 + e];
        f[e] = v;
        double dv = (double)v; s = fma(dv, dv, s);
        __bf16 h = (__bf16)v;
        ushort us; __builtin_memcpy(&us, &h, 2);
        tmp[e] = us;
      }
      uint4 pk;
      pk.x = tmp[0] | (tmp[1] << 16);
      pk.y = tmp[2] | (tmp[3] << 16);
      pk.z = tmp[4] | (tmp[5] << 16);
      pk.w = tmp[6] | (tmp[7] << 16);
      *(uint4*)(rowp + c8 * 8) = pk;
      *(float4*)(rowf + c8 * 8)     = make_float4(f[0], f[1], f[2], f[3]);
      *(float4*)(rowf + c8 * 8 + 4) = make_float4(f[4], f[5], f[6], f[7]);
    }
    xx[i] = s;
    xxf[i] = (float)s;
  }

  for (int oo = 0; oo < 16; ++oo) {
    int o = og * 16 + oo;
    float sp = 0.f;
#pragma unroll
    for (int c = 0; c < CC; c += 4) {
      float4 wv = *(const float4*)(&Wl[o][c]);
      sp = fmaf(wv.x, xcol[c], sp);
      sp = fmaf(wv.y, xcol[c + 1], sp);
      sp = fmaf(wv.z, xcol[c + 2], sp);
      sp = fmaf(wv.w, xcol[c + 3], sp);
    }
    tile[jj][o] = sp;
  }
  __syncthreads();
  for (int it = 0; it < 16; ++it) {
    int r = it * 2 + (t >> 7);
    P[((size_t)(pt0 + r)) * OO + (t & 127)] = tile[r][t & 127];
  }
#pragma unroll
  for (int r = 0; r < 8; ++r) {
    int seg = t + r * 256;
    int o = seg >> 4, c4 = (seg & 15) * 4;
    const float* wr = W + (size_t)o * (2 * CC);
    float4 w1 = *(const float4*)(wr + c4);
    float4 w2 = *(const float4*)(wr + CC + c4);
    float4 wd = make_float4(w2.x - w1.x, w2.y - w1.y, w2.z - w1.z, w2.w - w1.w);
    *(float4*)(&Wl[o][c4]) = wd;
  }
  __syncthreads();
  for (int oo = 0; oo < 16; ++oo) {
    int o = og * 16 + oo;
    float sq = 0.f;
#pragma unroll
    for (int c = 0; c < CC; c += 4) {
      float4 wv = *(const float4*)(&Wl[o][c]);
      sq = fmaf(wv.x, xcol[c], sq);
      sq = fmaf(wv.y, xcol[c + 1], sq);
      sq = fmaf(wv.z, xcol[c + 2], sq);
      sq = fmaf(wv.w, xcol[c + 3], sq);
    }
    tile[jj][o] = sq;
  }
  __syncthreads();
  for (int it = 0; it < 16; ++it) {
    int r = it * 2 + (t >> 7);
    Q[((size_t)(pt0 + r)) * OO + (t & 127)] = tile[r][t & 127];
  }
}

// ---------------------------------------------------------------------------
// k_prep (Path B fallback): standalone prep pass.
// ---------------------------------------------------------------------------
__global__ __launch_bounds__(256) void k_prep(const float* __restrict__ x,
                                              ushort* __restrict__ xT,
                                              float* __restrict__ xTf,
                                              double* __restrict__ xx,
                                              float* __restrict__ xxf) {
  int i = blockIdx.x * 256 + threadIdx.x;
  int b = i >> 11, n = i & (NN - 1);
  const float* p = x + ((size_t)b * CC) * NN + n;
  ushort* rowp = xT + (size_t)i * CC;
  float* rowf = xTf + (size_t)i * CC;
  double s = 0.0;
#pragma unroll
  for (int c8 = 0; c8 < 8; ++c8) {
    float f[8];
    unsigned tmp[8];
#pragma unroll
    for (int e = 0; e < 8; ++e) {
      float v = p[(size_t)(c8 * 8 + e) * NN];
      f[e] = v;
      double dv = (double)v; s = fma(dv, dv, s);
      __bf16 h = (__bf16)v;
      ushort us; __builtin_memcpy(&us, &h, 2);
      tmp[e] = us;
    }
    uint4 pk;
    pk.x = tmp[0] | (tmp[1] << 16);
    pk.y = tmp[2] | (tmp[3] << 16);
    pk.z = tmp[4] | (tmp[5] << 16);
    pk.w = tmp[6] | (tmp[7] << 16);
    *(uint4*)(rowp + c8 * 8) = pk;
    *(float4*)(rowf + c8 * 8)     = make_float4(f[0], f[1], f[2], f[3]);
    *(float4*)(rowf + c8 * 8 + 4) = make_float4(f[4], f[5], f[6], f[7]);
  }
  xx[i] = s;
  xxf[i] = (float)s;
}

// ---------------------------------------------------------------------------
// k_pq (Path B fallback): P/Q GEMMs only.
// ---------------------------------------------------------------------------
__global__ __launch_bounds__(256) void k_pq(const float* __restrict__ x,
                                            const float* __restrict__ W,
                                            float* __restrict__ P,
                                            float* __restrict__ Q) {
  __shared__ float tile[64][OO + 1];
  const int t = threadIdx.x;
  const int jj = t & 63, og = t >> 6;
  const int pt0 = blockIdx.x * 64;
  const int b = pt0 >> 11;
  const int jn = (pt0 & (NN - 1)) + jj;

  float xcol[CC];
#pragma unroll
  for (int c = 0; c < CC; ++c) xcol[c] = x[((size_t)(b * CC + c) << 11) + jn];

  for (int oo = 0; oo < 32; ++oo) {
    int o = og * 32 + oo;
    const float* wr = W + (size_t)o * (2 * CC);
    float sp = 0.f;
#pragma unroll
    for (int c = 0; c < CC; ++c) sp = fmaf(wr[c], xcol[c], sp);
    tile[jj][o] = sp;
  }
  __syncthreads();
  for (int it = 0; it < 32; ++it) {
    int r = it * 2 + (t >> 7);
    P[((size_t)(pt0 + r)) * OO + (t & 127)] = tile[r][t & 127];
  }
  __syncthreads();
  for (int oo = 0; oo < 32; ++oo) {
    int o = og * 32 + oo;
    const float* wr = W + (size_t)o * (2 * CC);
    float sq = 0.f;
#pragma unroll
    for (int c = 0; c < CC; ++c) sq = fmaf(wr[CC + c] - wr[c], xcol[c], sq);
    tile[jj][o] = sq;
  }
  __syncthreads();
  for (int it = 0; it < 32; ++it) {
    int r = it * 2 + (t >> 7);
    Q[((size_t)(pt0 + r)) * OO + (t & 127)] = tile[r][t & 127];
  }
}

// ---------------------------------------------------------------------------
// k_knn: R16 structure; phase C key scan via ds_read_b128 (4 contiguous 16B
// reads/lane/row vs 16 stride-4 b32) and CANDT 40->28 (shorter rank loop;
// invariant: count(>=tau)>=28 => top-20 all >= tau => candidates superset;
// fp64 rescore+rank identical -> same output).
// ---------------------------------------------------------------------------
__global__ __launch_bounds__(1024, 4) void k_knn(
    const ushort* __restrict__ xT, const float* __restrict__ xxf,
    const float* __restrict__ xTf, const double* __restrict__ xx,
    int* __restrict__ idx, const float* __restrict__ P,
    const float* __restrict__ Q, float* __restrict__ partial,
    float* __restrict__ vmaxA, float* __restrict__ vminA) {
  extern __shared__ char smem[];
  ushort (*Sb)[NN] = (ushort(*)[NN])smem;          // [32][2048] u16 keys 128KB
  int* Cj = (int*)(smem + 32 * NN * 2);            // [16][64] 4KB
  double* Sd = (double*)(smem + 32 * NN * 2 + 4096); // [16][64] 8KB
  float* redF = (float*)Sd;                        // reuse as [2][8][128] in D
  int (*sIdxL)[KK] = (int(*)[KK])(smem + 32 * NN * 2 + 4096 + 8192); // 2.5KB
  const int t = threadIdx.x;
  const int w = t >> 6, lane = t & 63;
  const int bidswz = ((blockIdx.x & 7) << 6) + (blockIdx.x >> 3); // batch/XCD
  const int b = bidswz >> 6;
  const int i0 = (bidswz & 63) << 5;
  const int lr = lane & 31, lh = lane >> 5;
  const ushort* xTb = xT + (((size_t)b) << 11) * CC;

  // ---- Phase A: MFMA 32x32x16 ----
  f32x16 acc[4];
#pragma unroll
  for (int tt = 0; tt < 4; ++tt)
#pragma unroll
    for (int q = 0; q < 16; ++q) acc[tt][q] = 0.f;

  const ushort* Ap = xTb + (size_t)(i0 + lr) * CC + lh * 8;
  bf8v a0 = *(const bf8v*)(Ap);
  bf8v a1 = *(const bf8v*)(Ap + 16);
  bf8v a2 = *(const bf8v*)(Ap + 32);
  bf8v a3 = *(const bf8v*)(Ap + 48);
  const int j0w = w << 7;
#pragma unroll
  for (int tt = 0; tt < 4; ++tt) {
    const ushort* Bp = xTb + (size_t)(j0w + tt * 32 + lr) * CC + lh * 8;
    bf8v b0 = *(const bf8v*)(Bp);
    bf8v b1 = *(const bf8v*)(Bp + 16);
    bf8v b2 = *(const bf8v*)(Bp + 32);
    bf8v b3 = *(const bf8v*)(Bp + 48);
    acc[tt] = __builtin_amdgcn_mfma_f32_32x32x16_bf16(a0, b0, acc[tt], 0, 0, 0);
    acc[tt] = __builtin_amdgcn_mfma_f32_32x32x16_bf16(a1, b1, acc[tt], 0, 0, 0);
    acc[tt] = __builtin_amdgcn_mfma_f32_32x32x16_bf16(a2, b2, acc[tt], 0, 0, 0);
    acc[tt] = __builtin_amdgcn_mfma_f32_32x32x16_bf16(a3, b3, acc[tt], 0, 0, 0);
  }

  // ---- Phase B: f32 score -> monotone u16 key -> LDS ----
  const float* xxfb = xxf + (b << 11);
#pragma unroll
  for (int tt = 0; tt < 4; ++tt) {
    int j = j0w + tt * 32 + lr;
    float xv = xxfb[j];
#pragma unroll
    for (int q = 0; q < 16; ++q) {
      int rr = (q & 3) + 8 * (q >> 2) + 4 * lh;    // 32x32 C/D map (m74/m101)
      float sv = fmaf(2.f, acc[tt][q], -xv);
      unsigned u = __float_as_uint(sv);
      u ^= (0x80000000u | (unsigned)((int)u >> 31)); // monotone u32
      Sb[rr][j] = (ushort)(u >> 16);
    }
  }
  __syncthreads();

  // ---- Phase C: 2 rows per wave (serial, spill-free) ----
  const float* xTfb = xTf + (((size_t)b) << 11) * CC;
  const double* xxb = xx + (b << 11);
#pragma unroll 1
  for (int rw = 0; rw < 2; ++rw) {
    const int rr = w + 16 * rw;
    const int irow = i0 + rr;
    // b128 key scan: lane covers j = lane*8 + g*512 + e (e=0..7), g=0..3
    uint4 kq[4];
    unsigned t0 = 0, t1 = 0, t2 = 0, t3 = 0;
#pragma unroll
    for (int g = 0; g < 4; ++g) {
      uint4 raw = *(const uint4*)(&Sb[rr][lane * 8 + g * 512]);
      kq[g] = raw;
      const unsigned wds[4] = {raw.x, raw.y, raw.z, raw.w};
#pragma unroll
      for (int e = 0; e < 4; ++e) {
        unsigned k0 = wds[e] & 0xffffu, k1 = wds[e] >> 16;
        unsigned mx, mn;
        mx = k0 > t0 ? k0 : t0; mn = k0 > t0 ? t0 : k0; t0 = mx;
        mx = mn > t1 ? mn : t1; mn = mn > t1 ? t1 : mn; t1 = mx;
        mx = mn > t2 ? mn : t2; mn = mn > t2 ? t2 : mn; t2 = mx;
        t3 = mn > t3 ? mn : t3;
        mx = k1 > t0 ? k1 : t0; mn = k1 > t0 ? t0 : k1; t0 = mx;
        mx = mn > t1 ? mn : t1; mn = mn > t1 ? t1 : mn; t1 = mx;
        mx = mn > t2 ? mn : t2; mn = mn > t2 ? t2 : mn; t2 = mx;
        t3 = mn > t3 ? mn : t3;
      }
    }
    unsigned tau = 0;
    for (int bit = 15; bit >= 0; --bit) {
      unsigned cnd = tau | (1u << bit);
      int tot = __popcll(__ballot(t0 >= cnd)) + __popcll(__ballot(t1 >= cnd)) +
                __popcll(__ballot(t2 >= cnd)) + __popcll(__ballot(t3 >= cnd));
      if (tot >= CANDT) tau = cnd;
    }
    // hit mask from regs: bit p = g*8 + e*2 + hi  (j = lane*8 + g*512 + (p&7))
    unsigned mask = 0;
#pragma unroll
    for (int g = 0; g < 4; ++g) {
      const unsigned wds[4] = {kq[g].x, kq[g].y, kq[g].z, kq[g].w};
#pragma unroll
      for (int e = 0; e < 4; ++e) {
        mask |= ((wds[e] & 0xffffu) >= tau ? 1u : 0u) << (g * 8 + e * 2);
        mask |= ((wds[e] >> 16) >= tau ? 1u : 0u) << (g * 8 + e * 2 + 1);
      }
    }
    int myc = __popc(mask);
    int pre = myc;
#pragma unroll
    for (int off = 1; off < 64; off <<= 1) {
      int o = __shfl_up(pre, off, 64);
      pre += (lane >= off) ? o : 0;
    }
    int tot = __shfl(pre, 63, 64);
    if (tot > 64) {                                // cold exact-radix fallback
      tau = 0;
      for (int bit = 15; bit >= 0; --bit) {
        unsigned cnd = tau | (1u << bit);
        int cc = 0;
#pragma unroll
        for (int g = 0; g < 4; ++g) {
          const unsigned wds[4] = {kq[g].x, kq[g].y, kq[g].z, kq[g].w};
#pragma unroll
          for (int e = 0; e < 4; ++e) {
            cc += ((wds[e] & 0xffffu) >= cnd) ? 1 : 0;
            cc += ((wds[e] >> 16) >= cnd) ? 1 : 0;
          }
        }
#pragma unroll
        for (int off = 1; off < 64; off <<= 1) cc += __shfl_xor(cc, off, 64);
        if (cc >= CANDT) tau = cnd;
      }
      mask = 0;
#pragma unroll
      for (int g = 0; g < 4; ++g) {
        const unsigned wds[4] = {kq[g].x, kq[g].y, kq[g].z, kq[g].w};
#pragma unroll
        for (int e = 0; e < 4; ++e) {
          mask |= ((wds[e] & 0xffffu) >= tau ? 1u : 0u) << (g * 8 + e * 2);
          mask |= ((wds[e] >> 16) >= tau ? 1u : 0u) << (g * 8 + e * 2 + 1);
        }
      }
      myc = __popc(mask);
      pre = myc;
#pragma unroll
      for (int off = 1; off < 64; off <<= 1) {
        int o = __shfl_up(pre, off, 64);
        pre += (lane >= off) ? o : 0;
      }
      tot = __shfl(pre, 63, 64);
    }
    {
      int slot = pre - myc;
      unsigned m2 = mask;
      while (m2) {
        int bp = __builtin_ctz(m2); m2 &= m2 - 1;
        if (slot < 64) Cj[w * 64 + slot] = lane * 8 + ((bp >> 3) << 9) + (bp & 7);
        ++slot;
      }
    }
    int cnt = tot > 64 ? 64 : tot;
    int j = Cj[w * 64 + (lane < cnt ? lane : 0)];
    const float* xi = xTfb + (size_t)irow * CC;
    const float* xj = xTfb + (size_t)j * CC;
    double d0 = 0, d1 = 0, d2 = 0, d3 = 0;
#pragma unroll
    for (int c = 0; c < CC; c += 4) {
      float4 fi = *(const float4*)(xi + c);
      float4 fj = *(const float4*)(xj + c);
      d0 = fma((double)fi.x, (double)fj.x, d0);
      d1 = fma((double)fi.y, (double)fj.y, d1);
      d2 = fma((double)fi.z, (double)fj.z, d2);
      d3 = fma((double)fi.w, (double)fj.w, d3);
    }
    double sc = 2.0 * ((d0 + d1) + (d2 + d3)) - xxb[j];
    Sd[w * 64 + lane] = sc;
    int rank = 0;
#pragma unroll 4
    for (int mm = 0; mm < cnt; ++mm) {
      double sm = Sd[w * 64 + mm];
      int jm = Cj[w * 64 + mm];
      rank += (sm > sc || (sm == sc && jm < j)) ? 1 : 0;
    }
    if (lane < cnt && rank < KK) {
      idx[(size_t)((b << 11) + irow) * KK + rank] = j;
      sIdxL[rr][rank] = j;                         // for fused stats
    }
  }

  // ---- Phase D: fused gather-stats (skipped when P==nullptr, Path B) ----
  if (P != nullptr) {
    __syncthreads();                               // sIdxL complete; Sd free
    const int grp = t >> 7;                        // 0..7 (4 points each)
    const int o = t & 127;
    float s = 0.f, s2 = 0.f;
#pragma unroll
    for (int pp = 0; pp < 4; ++pp) {
      const int pl = grp * 4 + pp;                 // local row 0..31
      const int pt = (b << 11) + i0 + pl;          // global point
      float qv = Q[(size_t)pt * OO + o];
      float vmax = -3.0e38f, vmin = 3.0e38f;
#pragma unroll
      for (int k = 0; k < KK; ++k) {
        float v = P[((size_t)((b << 11) + sIdxL[pl][k])) * OO + o] + qv;
        s += v;
        s2 = fmaf(v, v, s2);
        vmax = fmaxf(vmax, v);
        vmin = fminf(vmin, v);
      }
      vmaxA[(size_t)pt * OO + o] = vmax;
      vminA[(size_t)pt * OO + o] = vmin;
    }
    redF[grp * 128 + o] = s;
    redF[1024 + grp * 128 + o] = s2;
    __syncthreads();
    if (t < 128) {
      float as = 0.f, as2 = 0.f;
#pragma unroll
      for (int g = 0; g < 8; ++g) {                // fixed order: deterministic
        as  += redF[g * 128 + t];
        as2 += redF[1024 + g * 128 + t];
      }
      partial[(size_t)bidswz * 128 + t]               = as;
      partial[(size_t)NPART * 128 + (size_t)bidswz * 128 + t] = as2;
    }
  }
}

// ---------------------------------------------------------------------------
// k_stats (Path B fallback): standalone gather-stats.
// ---------------------------------------------------------------------------
__global__ __launch_bounds__(256) void k_stats(const float* __restrict__ P,
                                               const float* __restrict__ Q,
                                               const int* __restrict__ idx,
                                               float* __restrict__ partial) {
  __shared__ int sIdx[16 * KK];
  __shared__ float red[512];
  const int t = threadIdx.x;
  const int o = t & 127, half = t >> 7;
  const int bid = (blockIdx.x & 7) * 128 + (blockIdx.x >> 3);
  const int pt0 = bid * 16;
  const int b = pt0 >> 11;
  if (t < 160)
    *(int2*)(sIdx + t * 2) = *(const int2*)(idx + (size_t)pt0 * KK + t * 2);
  __syncthreads();

  float s = 0.f, s2 = 0.f;
  for (int it = 0; it < 8; ++it) {
    int pl = it * 2 + half;
    int pt = pt0 + pl;
    float qv = Q[(size_t)pt * OO + o];
    const int* ip = sIdx + pl * KK;
#pragma unroll
    for (int k = 0; k < KK; ++k) {
      float v = P[((size_t)((b << 11) + ip[k])) * OO + o] + qv;
      s += v;
      s2 = fmaf(v, v, s2);
    }
  }
  red[t] = s; red[256 + t] = s2;
  __syncthreads();
  if (t < 128) {
    partial[bid * 128 + o]                = red[t] + red[t + 128];
    partial[NPARTB * 128 + bid * 128 + o] = red[256 + t] + red[256 + t + 128];
  }
}

// ---------------------------------------------------------------------------
// k_fin: single-kernel BN finalize. 128 blocks (one per o); npart variable.
// ---------------------------------------------------------------------------
__global__ __launch_bounds__(256) void k_fin(const float* __restrict__ partial,
                                             const float* __restrict__ gamma,
                                             const float* __restrict__ beta,
                                             float* __restrict__ ss, int npart) {
  __shared__ float red[2][256];
  const int o = blockIdx.x;
  const int t = threadIdx.x;
  float s = 0.f, s2 = 0.f;
  for (int blk = t; blk < npart; blk += 256) {
    s  += partial[(size_t)blk * 128 + o];
    s2 += partial[(size_t)npart * 128 + (size_t)blk * 128 + o];
  }
  red[0][t] = s; red[1][t] = s2;
  __syncthreads();
  for (int st = 128; st >= 1; st >>= 1) {
    if (t < st) { red[0][t] += red[0][t + st]; red[1][t] += red[1][t + st]; }
    __syncthreads();
  }
  if (t == 0) {
    float mean = red[0][0] * (1.0f / M_TOT);
    float var  = red[1][0] * (1.0f / M_TOT) - mean * mean;
    float rs = 1.0f / sqrtf(var + 1e-5f);
    float scale = gamma[o] * rs;
    ss[o] = scale;
    ss[128 + o] = beta[o] - mean * scale;
  }
}

// ---------------------------------------------------------------------------
// k_out: BN affine -> exact GELU -> max over k -> out[b][o][n].
// R16 form: 512 blocks x 32-pt tiles, (256,8) occupancy.
// ---------------------------------------------------------------------------
__global__ __launch_bounds__(256, 8) void k_out(const float* __restrict__ P,
                                                const float* __restrict__ Q,
                                                const int* __restrict__ idx,
                                                const float* __restrict__ ss,
                                                const float* __restrict__ vmaxA,
                                                const float* __restrict__ vminA,
                                                int use_minmax,
                                                float* __restrict__ out) {
  __shared__ float tile[32][OO + 1];               // 16.5 KB
  const int t = threadIdx.x;
  const int o = t & 127, half = t >> 7;
  const int bid = (blockIdx.x & 7) * 64 + (blockIdx.x >> 3);   // batch/XCD
  const float scale = ss[o], shift = ss[128 + o];
  const int pt0 = bid * 32;
  const int b = pt0 >> 11;
  const float inv_sqrt2 = 0.70710678118654752f;
  for (int it = 0; it < 16; ++it) {
    int pl = it * 2 + half;
    int pt = pt0 + pl;
    float vmax, vmin;
    if (use_minmax) {
      vmax = vmaxA[(size_t)pt * OO + o];
      vmin = vminA[(size_t)pt * OO + o];
    } else {
      float qv = Q[(size_t)pt * OO + o];
      const int* ip = idx + (size_t)pt * KK;
      vmax = -3.0e38f; vmin = 3.0e38f;
#pragma unroll
      for (int k = 0; k < KK; ++k) {
        float v = P[((size_t)((b << 11) + ip[k])) * OO + o] + qv;
        vmax = fmaxf(vmax, v);
        vmin = fminf(vmin, v);
      }
    }
    float ymax, ymin;
    if (scale >= 0.f) { ymax = fmaf(vmax, scale, shift); ymin = fmaf(vmin, scale, shift); }
    else              { ymax = fmaf(vmin, scale, shift); ymin = fmaf(vmax, scale, shift); }
    float g;
    if (ymax > 0.f) {
      g = 0.5f * ymax * (1.0f + erff(ymax * inv_sqrt2));
    } else {
      float g1 = 0.5f * ymax * (1.0f + erff(ymax * inv_sqrt2));
      float g2 = 0.5f * ymin * (1.0f + erff(ymin * inv_sqrt2));
      g = fmaxf(g1, g2);
    }
    tile[pl][o] = g;
  }
  __syncthreads();
  const int n0 = pt0 & (NN - 1);
  for (int rep = 0; rep < 16; ++rep) {
    int oo = rep * 8 + (t >> 5);
    int nn = t & 31;
    out[((size_t)(b * OO + oo) << 11) + n0 + nn] = tile[nn][oo];
  }
}

// ---------------------------------------------------------------------------
extern "C" void kernel_launch(void* const* d_in, const int* in_sizes, int n_in,
                              void* d_out, int out_size, void* d_ws, size_t ws_size,
                              hipStream_t stream) {
  const float* x     = (const float*)d_in[0];
  const float* W     = (const float*)d_in[1];
  const float* gamma = (const float*)d_in[2];
  const float* beta  = (const float*)d_in[3];
  float* out = (float*)d_out;

  const int knn_lds = 32 * NN * 2 + 4096 + 8192 + 32 * KK * 4;  // 145920 B
  hipFuncSetAttribute((const void*)k_knn,
                      hipFuncAttributeMaxDynamicSharedMemorySize, knn_lds);

  const size_t needA = 131072 + 65536 + 1310720 + (size_t)2 * NPARTB * 128 * 4 +
                       1024 + 4ull * 8388608;

  if (ws_size >= needA) {
    // Path A layout
    double* xx   = (double*)d_ws;                      // 131072 B
    float*  xxf  = (float*)(xx + BB * NN);             // 65536 B
    int*    idxp = (int*)(xxf + BB * NN);              // 1310720 B
    float*  part = (float*)(idxp + (size_t)BB * NN * KK); // 1 MB
    float*  ss   = part + 2 * NPARTB * 128;            // 1024 B
    float*  P    = ss + 256;                           // 8 MB
    float*  Q    = P + (size_t)BB * NN * OO;           // 8 MB
    ushort* xT   = (ushort*)(Q + (size_t)BB * NN * OO);// 2 MB
    float*  xTf  = (float*)(xT + (size_t)BB * NN * CC);// 4 MB
    float*  vmax = xTf + (size_t)BB * NN * CC;         // 8 MB (no alias: knn-D)
    float*  vmin = vmax + (size_t)BB * NN * OO;        // 8 MB
    const size_t needSafe = (size_t)((char*)(vmin + (size_t)BB * NN * OO) - (char*)d_ws);
    if (ws_size >= needSafe) {
      hipLaunchKernelGGL(k_pqprep, dim3(BB * NN / 32), dim3(256), 0, stream,
                         x, W, P, Q, xT, xTf, xx, xxf);
      hipLaunchKernelGGL(k_knn, dim3(BB * NN / 32), dim3(1024), knn_lds, stream,
                         xT, xxf, xTf, xx, idxp, P, Q, part, vmax, vmin);
      hipLaunchKernelGGL(k_fin, dim3(128), dim3(256), 0, stream, part, gamma, beta, ss, NPART);
      hipLaunchKernelGGL(k_out, dim3(BB * NN / 32), dim3(256), 0, stream,
                         P, Q, idxp, ss, vmax, vmin, 1, out);
      return;
    }
    // ws too small for safe vmax/vmin: alias xT/xTf region, no fused stats
    ushort* xTa  = (ushort*)(Q + (size_t)BB * NN * OO);
    float*  xTfa = (float*)(xTa + (size_t)BB * NN * CC);
    hipLaunchKernelGGL(k_pqprep, dim3(BB * NN / 32), dim3(256), 0, stream,
                       x, W, P, Q, xTa, xTfa, xx, xxf);
    hipLaunchKernelGGL(k_knn, dim3(BB * NN / 32), dim3(1024), knn_lds, stream,
                       xTa, xxf, xTfa, xx, idxp,
                       (const float*)nullptr, (const float*)nullptr,
                       (float*)nullptr, (float*)nullptr, (float*)nullptr);
    hipLaunchKernelGGL(k_stats, dim3(NPARTB), dim3(256), 0, stream,
                       P, Q, idxp, part);
    hipLaunchKernelGGL(k_fin, dim3(128), dim3(256), 0, stream, part, gamma, beta, ss, NPARTB);
    hipLaunchKernelGGL(k_out, dim3(BB * NN / 32), dim3(256), 0, stream,
                       P, Q, idxp, ss, (const float*)nullptr, (const float*)nullptr, 0, out);
  } else {
    // Path B layout (minimal ws)
    double* xx   = (double*)d_ws;
    int*    idxp = (int*)(xx + BB * NN);
    float*  P    = (float*)(idxp + (size_t)BB * NN * KK);
    float*  Q    = P + (size_t)BB * NN * OO;
    float*  part = Q + (size_t)BB * NN * OO;
    float*  ss   = part + 2 * NPARTB * 128;
    ushort* xT   = (ushort*)P;
    float*  xTf  = P + (size_t)BB * NN * (CC / 2);
    float*  xxf  = Q;

    hipLaunchKernelGGL(k_prep, dim3(BB * NN / 256), dim3(256), 0, stream,
                       x, xT, xTf, xx, xxf);
    hipLaunchKernelGGL(k_knn, dim3(BB * NN / 32), dim3(1024), knn_lds, stream,
                       xT, xxf, xTf, xx, idxp,
                       (const float*)nullptr, (const float*)nullptr,
                       (float*)nullptr, (float*)nullptr, (float*)nullptr);
    hipLaunchKernelGGL(k_pq, dim3(BB * NN / 64), dim3(256), 0, stream, x, W, P, Q);
    hipLaunchKernelGGL(k_stats, dim3(NPARTB), dim3(256), 0, stream,
                       P, Q, idxp, part);
    hipLaunchKernelGGL(k_fin, dim3(128), dim3(256), 0, stream, part, gamma, beta, ss, NPARTB);
    hipLaunchKernelGGL(k_out, dim3(BB * NN / 32), dim3(256), 0, stream,
                       P, Q, idxp, ss, (const float*)nullptr, (const float*)nullptr, 0, out);
  }
}

// Round 18
// 110.602 us; speedup vs baseline: 3.8477x; 1.0450x over previous
//
#include <hip/hip_runtime.h>
#include <math.h>

#define BB 8
#define CC 64
#define NN 2048
#define KK 20
#define OO 128
#define CANDT 28
#define NPART 512          // = k_knn grid (stats fused there)
#define NPARTB 1024        // Path-B standalone k_stats grid
#define M_TOT 327680.0f    // B*N*K

typedef __attribute__((ext_vector_type(8))) __bf16 bf8v;
typedef __attribute__((ext_vector_type(16))) float f32x16;

// ---------------------------------------------------------------------------
// k_pqprep (Path A): P/Q GEMMs + bf16 xT rows + f32 xTf rows + xx/xxf norms.
// ---------------------------------------------------------------------------
__global__ __launch_bounds__(256, 4) void k_pqprep(const float* __restrict__ x,
                                                   const float* __restrict__ W,
                                                   float* __restrict__ P,
                                                   float* __restrict__ Q,
                                                   ushort* __restrict__ xT,
                                                   float* __restrict__ xTf,
                                                   double* __restrict__ xx,
                                                   float* __restrict__ xxf) {
  __shared__ float xs[32][68];                     // 8.7 KB
  __shared__ float Wl[OO][68];                     // 34 KB
  __shared__ float tile[32][OO + 1];               // 16.5 KB
  const int t = threadIdx.x;
  const int jj = t & 31, og = t >> 5;              // 8 o-groups of 16
  const int pt0 = blockIdx.x * 32;
  const int b = pt0 >> 11;
  const int n0 = pt0 & (NN - 1);

#pragma unroll
  for (int r = 0; r < 2; ++r) {
    int seg = t + r * 256;
    int c = seg >> 3, n4 = (seg & 7) * 4;
    float4 v = *(const float4*)(x + ((size_t)(b * CC + c) << 11) + n0 + n4);
    xs[n4 + 0][c] = v.x; xs[n4 + 1][c] = v.y;
    xs[n4 + 2][c] = v.z; xs[n4 + 3][c] = v.w;
  }
#pragma unroll
  for (int r = 0; r < 8; ++r) {
    int seg = t + r * 256;                         // seg = o*16 + c4
    int o = seg >> 4, c4 = (seg & 15) * 4;
    *(float4*)(&Wl[o][c4]) = *(const float4*)(W + (size_t)o * (2 * CC) + c4);
  }
  __syncthreads();

  float xcol[CC];
#pragma unroll
  for (int c = 0; c < CC; c += 4) {
    float4 v = *(const float4*)(&xs[jj][c]);
    xcol[c] = v.x; xcol[c + 1] = v.y; xcol[c + 2] = v.z; xcol[c + 3] = v.w;
  }

  if (t < 32) {                                    // prep outputs (1 pt/thread)
    int i = pt0 + t;
    ushort* rowp = xT + (size_t)i * CC;
    float* rowf = xTf + (size_t)i * CC;
    double s = 0.0;
#pragma unroll
    for (int c8 = 0; c8 < 8; ++c8) {
      unsigned tmp[8];
      float f[8];
#pragma unroll
      for (int e = 0; e < 8; ++e) {
        float v = xs[t][c8 * 8 + e];
        f[e] = v;
        double dv = (double)v; s = fma(dv, dv, s);
        __bf16 h = (__bf16)v;
        ushort us; __builtin_memcpy(&us, &h, 2);
        tmp[e] = us;
      }
      uint4 pk;
      pk.x = tmp[0] | (tmp[1] << 16);
      pk.y = tmp[2] | (tmp[3] << 16);
      pk.z = tmp[4] | (tmp[5] << 16);
      pk.w = tmp[6] | (tmp[7] << 16);
      *(uint4*)(rowp + c8 * 8) = pk;
      *(float4*)(rowf + c8 * 8)     = make_float4(f[0], f[1], f[2], f[3]);
      *(float4*)(rowf + c8 * 8 + 4) = make_float4(f[4], f[5], f[6], f[7]);
    }
    xx[i] = s;
    xxf[i] = (float)s;
  }

  for (int oo = 0; oo < 16; ++oo) {
    int o = og * 16 + oo;
    float sp = 0.f;
#pragma unroll
    for (int c = 0; c < CC; c += 4) {
      float4 wv = *(const float4*)(&Wl[o][c]);
      sp = fmaf(wv.x, xcol[c], sp);
      sp = fmaf(wv.y, xcol[c + 1], sp);
      sp = fmaf(wv.z, xcol[c + 2], sp);
      sp = fmaf(wv.w, xcol[c + 3], sp);
    }
    tile[jj][o] = sp;
  }
  __syncthreads();
  for (int it = 0; it < 16; ++it) {
    int r = it * 2 + (t >> 7);
    P[((size_t)(pt0 + r)) * OO + (t & 127)] = tile[r][t & 127];
  }
#pragma unroll
  for (int r = 0; r < 8; ++r) {
    int seg = t + r * 256;
    int o = seg >> 4, c4 = (seg & 15) * 4;
    const float* wr = W + (size_t)o * (2 * CC);
    float4 w1 = *(const float4*)(wr + c4);
    float4 w2 = *(const float4*)(wr + CC + c4);
    float4 wd = make_float4(w2.x - w1.x, w2.y - w1.y, w2.z - w1.z, w2.w - w1.w);
    *(float4*)(&Wl[o][c4]) = wd;
  }
  __syncthreads();
  for (int oo = 0; oo < 16; ++oo) {
    int o = og * 16 + oo;
    float sq = 0.f;
#pragma unroll
    for (int c = 0; c < CC; c += 4) {
      float4 wv = *(const float4*)(&Wl[o][c]);
      sq = fmaf(wv.x, xcol[c], sq);
      sq = fmaf(wv.y, xcol[c + 1], sq);
      sq = fmaf(wv.z, xcol[c + 2], sq);
      sq = fmaf(wv.w, xcol[c + 3], sq);
    }
    tile[jj][o] = sq;
  }
  __syncthreads();
  for (int it = 0; it < 16; ++it) {
    int r = it * 2 + (t >> 7);
    Q[((size_t)(pt0 + r)) * OO + (t & 127)] = tile[r][t & 127];
  }
}

// ---------------------------------------------------------------------------
// k_prep (Path B fallback): standalone prep pass.
// ---------------------------------------------------------------------------
__global__ __launch_bounds__(256) void k_prep(const float* __restrict__ x,
                                              ushort* __restrict__ xT,
                                              float* __restrict__ xTf,
                                              double* __restrict__ xx,
                                              float* __restrict__ xxf) {
  int i = blockIdx.x * 256 + threadIdx.x;
  int b = i >> 11, n = i & (NN - 1);
  const float* p = x + ((size_t)b * CC) * NN + n;
  ushort* rowp = xT + (size_t)i * CC;
  float* rowf = xTf + (size_t)i * CC;
  double s = 0.0;
#pragma unroll
  for (int c8 = 0; c8 < 8; ++c8) {
    float f[8];
    unsigned tmp[8];
#pragma unroll
    for (int e = 0; e < 8; ++e) {
      float v = p[(size_t)(c8 * 8 + e) * NN];
      f[e] = v;
      double dv = (double)v; s = fma(dv, dv, s);
      __bf16 h = (__bf16)v;
      ushort us; __builtin_memcpy(&us, &h, 2);
      tmp[e] = us;
    }
    uint4 pk;
    pk.x = tmp[0] | (tmp[1] << 16);
    pk.y = tmp[2] | (tmp[3] << 16);
    pk.z = tmp[4] | (tmp[5] << 16);
    pk.w = tmp[6] | (tmp[7] << 16);
    *(uint4*)(rowp + c8 * 8) = pk;
    *(float4*)(rowf + c8 * 8)     = make_float4(f[0], f[1], f[2], f[3]);
    *(float4*)(rowf + c8 * 8 + 4) = make_float4(f[4], f[5], f[6], f[7]);
  }
  xx[i] = s;
  xxf[i] = (float)s;
}

// ---------------------------------------------------------------------------
// k_pq (Path B fallback): P/Q GEMMs only.
// ---------------------------------------------------------------------------
__global__ __launch_bounds__(256) void k_pq(const float* __restrict__ x,
                                            const float* __restrict__ W,
                                            float* __restrict__ P,
                                            float* __restrict__ Q) {
  __shared__ float tile[64][OO + 1];
  const int t = threadIdx.x;
  const int jj = t & 63, og = t >> 6;
  const int pt0 = blockIdx.x * 64;
  const int b = pt0 >> 11;
  const int jn = (pt0 & (NN - 1)) + jj;

  float xcol[CC];
#pragma unroll
  for (int c = 0; c < CC; ++c) xcol[c] = x[((size_t)(b * CC + c) << 11) + jn];

  for (int oo = 0; oo < 32; ++oo) {
    int o = og * 32 + oo;
    const float* wr = W + (size_t)o * (2 * CC);
    float sp = 0.f;
#pragma unroll
    for (int c = 0; c < CC; ++c) sp = fmaf(wr[c], xcol[c], sp);
    tile[jj][o] = sp;
  }
  __syncthreads();
  for (int it = 0; it < 32; ++it) {
    int r = it * 2 + (t >> 7);
    P[((size_t)(pt0 + r)) * OO + (t & 127)] = tile[r][t & 127];
  }
  __syncthreads();
  for (int oo = 0; oo < 32; ++oo) {
    int o = og * 32 + oo;
    const float* wr = W + (size_t)o * (2 * CC);
    float sq = 0.f;
#pragma unroll
    for (int c = 0; c < CC; ++c) sq = fmaf(wr[CC + c] - wr[c], xcol[c], sq);
    tile[jj][o] = sq;
  }
  __syncthreads();
  for (int it = 0; it < 32; ++it) {
    int r = it * 2 + (t >> 7);
    Q[((size_t)(pt0 + r)) * OO + (t & 127)] = tile[r][t & 127];
  }
}

// ---------------------------------------------------------------------------
// k_knn: R17 + (a) phase A/B split in two halves so only 32 AGPRs are live
// (acc[4]=64 AGPRs was eating half the unified reg file — the root cause of
// R11/R13's phase-C spills); (b) phase C dual-row interleaved (2x ILP on the
// radix ballot chain, scans, fp64 rescore, rank). Selection math identical.
// ---------------------------------------------------------------------------
__device__ __forceinline__ void exact_radix_q(const uint4* kq, int lane,
                                              unsigned& tau, unsigned& mask,
                                              int& myc, int& pre, int& tot) {
  tau = 0;
  for (int bit = 15; bit >= 0; --bit) {
    unsigned cnd = tau | (1u << bit);
    int cc = 0;
#pragma unroll
    for (int g = 0; g < 4; ++g) {
      const unsigned wds[4] = {kq[g].x, kq[g].y, kq[g].z, kq[g].w};
#pragma unroll
      for (int e = 0; e < 4; ++e) {
        cc += ((wds[e] & 0xffffu) >= cnd) ? 1 : 0;
        cc += ((wds[e] >> 16) >= cnd) ? 1 : 0;
      }
    }
#pragma unroll
    for (int off = 1; off < 64; off <<= 1) cc += __shfl_xor(cc, off, 64);
    if (cc >= CANDT) tau = cnd;
  }
  mask = 0;
#pragma unroll
  for (int g = 0; g < 4; ++g) {
    const unsigned wds[4] = {kq[g].x, kq[g].y, kq[g].z, kq[g].w};
#pragma unroll
    for (int e = 0; e < 4; ++e) {
      mask |= ((wds[e] & 0xffffu) >= tau ? 1u : 0u) << (g * 8 + e * 2);
      mask |= ((wds[e] >> 16) >= tau ? 1u : 0u) << (g * 8 + e * 2 + 1);
    }
  }
  myc = __popc(mask); pre = myc;
#pragma unroll
  for (int off = 1; off < 64; off <<= 1) {
    int o = __shfl_up(pre, off, 64);
    pre += (lane >= off) ? o : 0;
  }
  tot = __shfl(pre, 63, 64);
}

__global__ __launch_bounds__(1024, 4) void k_knn(
    const ushort* __restrict__ xT, const float* __restrict__ xxf,
    const float* __restrict__ xTf, const double* __restrict__ xx,
    int* __restrict__ idx, const float* __restrict__ P,
    const float* __restrict__ Q, float* __restrict__ partial,
    float* __restrict__ vmaxA, float* __restrict__ vminA) {
  extern __shared__ char smem[];
  ushort (*Sb)[NN] = (ushort(*)[NN])smem;          // [32][2048] u16 keys 128KB
  int (*CjS)[64] = (int(*)[64])(smem + 32 * NN * 2);           // [32][64] 8KB
  double (*SdS)[64] = (double(*)[64])(smem + 32 * NN * 2 + 8192); // [32][64] 16KB
  float* redF = (float*)SdS;                       // reuse as [2][8][128] in D
  int (*sIdxL)[KK] = (int(*)[KK])(smem + 32 * NN * 2 + 8192 + 16384); // 2.5KB
  const int t = threadIdx.x;
  const int w = t >> 6, lane = t & 63;
  const int bidswz = ((blockIdx.x & 7) << 6) + (blockIdx.x >> 3); // batch/XCD
  const int b = bidswz >> 6;
  const int i0 = (bidswz & 63) << 5;
  const int lr = lane & 31, lh = lane >> 5;
  const ushort* xTb = xT + (((size_t)b) << 11) * CC;
  const float* xxfb = xxf + (b << 11);

  // ---- Phase A+B in 2 halves: only 32 AGPRs (acc2[2]) live at a time ----
  const ushort* Ap = xTb + (size_t)(i0 + lr) * CC + lh * 8;
  bf8v a0 = *(const bf8v*)(Ap);
  bf8v a1 = *(const bf8v*)(Ap + 16);
  bf8v a2 = *(const bf8v*)(Ap + 32);
  bf8v a3 = *(const bf8v*)(Ap + 48);
  const int j0w = w << 7;
#pragma unroll 1
  for (int h = 0; h < 2; ++h) {
    f32x16 acc2[2];
#pragma unroll
    for (int u = 0; u < 2; ++u)
#pragma unroll
      for (int q = 0; q < 16; ++q) acc2[u][q] = 0.f;
#pragma unroll
    for (int u = 0; u < 2; ++u) {
      const int tt = h * 2 + u;
      const ushort* Bp = xTb + (size_t)(j0w + tt * 32 + lr) * CC + lh * 8;
      bf8v b0 = *(const bf8v*)(Bp);
      bf8v b1 = *(const bf8v*)(Bp + 16);
      bf8v b2 = *(const bf8v*)(Bp + 32);
      bf8v b3 = *(const bf8v*)(Bp + 48);
      acc2[u] = __builtin_amdgcn_mfma_f32_32x32x16_bf16(a0, b0, acc2[u], 0, 0, 0);
      acc2[u] = __builtin_amdgcn_mfma_f32_32x32x16_bf16(a1, b1, acc2[u], 0, 0, 0);
      acc2[u] = __builtin_amdgcn_mfma_f32_32x32x16_bf16(a2, b2, acc2[u], 0, 0, 0);
      acc2[u] = __builtin_amdgcn_mfma_f32_32x32x16_bf16(a3, b3, acc2[u], 0, 0, 0);
    }
#pragma unroll
    for (int u = 0; u < 2; ++u) {
      const int tt = h * 2 + u;
      int j = j0w + tt * 32 + lr;
      float xv = xxfb[j];
#pragma unroll
      for (int q = 0; q < 16; ++q) {
        int rr = (q & 3) + 8 * (q >> 2) + 4 * lh;  // 32x32 C/D map (m74/m101)
        float sv = fmaf(2.f, acc2[u][q], -xv);
        unsigned uu = __float_as_uint(sv);
        uu ^= (0x80000000u | (unsigned)((int)uu >> 31)); // monotone u32
        Sb[rr][j] = (ushort)(uu >> 16);
      }
    }
  }
  __syncthreads();

  // ---- Phase C: rows rrA=w, rrB=w+16 fully interleaved (b128 key reads) ----
  const float* xTfb = xTf + (((size_t)b) << 11) * CC;
  const double* xxb = xx + (b << 11);
  const int rrA = w, rrB = w + 16;
  const int irowA = i0 + rrA, irowB = i0 + rrB;

  uint4 kqA[4], kqB[4];
  unsigned tA0 = 0, tA1 = 0, tA2 = 0, tA3 = 0;
  unsigned tB0 = 0, tB1 = 0, tB2 = 0, tB3 = 0;
#pragma unroll
  for (int g = 0; g < 4; ++g) {
    uint4 rawA = *(const uint4*)(&Sb[rrA][lane * 8 + g * 512]);
    uint4 rawB = *(const uint4*)(&Sb[rrB][lane * 8 + g * 512]);
    kqA[g] = rawA; kqB[g] = rawB;
    const unsigned wA[4] = {rawA.x, rawA.y, rawA.z, rawA.w};
    const unsigned wB[4] = {rawB.x, rawB.y, rawB.z, rawB.w};
#pragma unroll
    for (int e = 0; e < 4; ++e) {
      unsigned kA0 = wA[e] & 0xffffu, kA1 = wA[e] >> 16;
      unsigned kB0 = wB[e] & 0xffffu, kB1 = wB[e] >> 16;
      unsigned mx, mn;
      mx = kA0 > tA0 ? kA0 : tA0; mn = kA0 > tA0 ? tA0 : kA0; tA0 = mx;
      mx = mn > tA1 ? mn : tA1; mn = mn > tA1 ? tA1 : mn; tA1 = mx;
      mx = mn > tA2 ? mn : tA2; mn = mn > tA2 ? tA2 : mn; tA2 = mx;
      tA3 = mn > tA3 ? mn : tA3;
      mx = kB0 > tB0 ? kB0 : tB0; mn = kB0 > tB0 ? tB0 : kB0; tB0 = mx;
      mx = mn > tB1 ? mn : tB1; mn = mn > tB1 ? tB1 : mn; tB1 = mx;
      mx = mn > tB2 ? mn : tB2; mn = mn > tB2 ? tB2 : mn; tB2 = mx;
      tB3 = mn > tB3 ? mn : tB3;
      mx = kA1 > tA0 ? kA1 : tA0; mn = kA1 > tA0 ? tA0 : kA1; tA0 = mx;
      mx = mn > tA1 ? mn : tA1; mn = mn > tA1 ? tA1 : mn; tA1 = mx;
      mx = mn > tA2 ? mn : tA2; mn = mn > tA2 ? tA2 : mn; tA2 = mx;
      tA3 = mn > tA3 ? mn : tA3;
      mx = kB1 > tB0 ? kB1 : tB0; mn = kB1 > tB0 ? tB0 : kB1; tB0 = mx;
      mx = mn > tB1 ? mn : tB1; mn = mn > tB1 ? tB1 : mn; tB1 = mx;
      mx = mn > tB2 ? mn : tB2; mn = mn > tB2 ? tB2 : mn; tB2 = mx;
      tB3 = mn > tB3 ? mn : tB3;
    }
  }
  // dual MSB radix with capped (top-4) ballot counts
  unsigned tauA = 0, tauB = 0;
  for (int bit = 15; bit >= 0; --bit) {
    unsigned cA = tauA | (1u << bit), cB = tauB | (1u << bit);
    int totA_ = __popcll(__ballot(tA0 >= cA)) + __popcll(__ballot(tA1 >= cA)) +
                __popcll(__ballot(tA2 >= cA)) + __popcll(__ballot(tA3 >= cA));
    int totB_ = __popcll(__ballot(tB0 >= cB)) + __popcll(__ballot(tB1 >= cB)) +
                __popcll(__ballot(tB2 >= cB)) + __popcll(__ballot(tB3 >= cB));
    if (totA_ >= CANDT) tauA = cA;
    if (totB_ >= CANDT) tauB = cB;
  }
  // dual masks + dual prefix scan
  unsigned maskA = 0, maskB = 0;
#pragma unroll
  for (int g = 0; g < 4; ++g) {
    const unsigned wA[4] = {kqA[g].x, kqA[g].y, kqA[g].z, kqA[g].w};
    const unsigned wB[4] = {kqB[g].x, kqB[g].y, kqB[g].z, kqB[g].w};
#pragma unroll
    for (int e = 0; e < 4; ++e) {
      maskA |= ((wA[e] & 0xffffu) >= tauA ? 1u : 0u) << (g * 8 + e * 2);
      maskA |= ((wA[e] >> 16) >= tauA ? 1u : 0u) << (g * 8 + e * 2 + 1);
      maskB |= ((wB[e] & 0xffffu) >= tauB ? 1u : 0u) << (g * 8 + e * 2);
      maskB |= ((wB[e] >> 16) >= tauB ? 1u : 0u) << (g * 8 + e * 2 + 1);
    }
  }
  int mycA = __popc(maskA), mycB = __popc(maskB);
  int preA = mycA, preB = mycB;
#pragma unroll
  for (int off = 1; off < 64; off <<= 1) {
    int oA = __shfl_up(preA, off, 64);
    int oB = __shfl_up(preB, off, 64);
    preA += (lane >= off) ? oA : 0;
    preB += (lane >= off) ? oB : 0;
  }
  int totA = __shfl(preA, 63, 64);
  int totB = __shfl(preB, 63, 64);
  if (totA > 64) exact_radix_q(kqA, lane, tauA, maskA, mycA, preA, totA); // cold
  if (totB > 64) exact_radix_q(kqB, lane, tauB, maskB, mycB, preB, totB); // cold
  {
    int slot = preA - mycA;
    unsigned m2 = maskA;
    while (m2) {
      int bp = __builtin_ctz(m2); m2 &= m2 - 1;
      if (slot < 64) CjS[rrA][slot] = lane * 8 + ((bp >> 3) << 9) + (bp & 7);
      ++slot;
    }
  }
  {
    int slot = preB - mycB;
    unsigned m2 = maskB;
    while (m2) {
      int bp = __builtin_ctz(m2); m2 &= m2 - 1;
      if (slot < 64) CjS[rrB][slot] = lane * 8 + ((bp >> 3) << 9) + (bp & 7);
      ++slot;
    }
  }
  const int cntA = totA > 64 ? 64 : totA;
  const int cntB = totB > 64 ? 64 : totB;

  // dual fp64 rescore (accumulation order identical to R3..R17)
  int jA = CjS[rrA][lane < cntA ? lane : 0];
  int jB = CjS[rrB][lane < cntB ? lane : 0];
  const float* xiA = xTfb + (size_t)irowA * CC;
  const float* xiB = xTfb + (size_t)irowB * CC;
  const float* xjA = xTfb + (size_t)jA * CC;
  const float* xjB = xTfb + (size_t)jB * CC;
  double dA0 = 0, dA1 = 0, dA2 = 0, dA3 = 0;
  double dB0 = 0, dB1 = 0, dB2 = 0, dB3 = 0;
#pragma unroll
  for (int c = 0; c < CC; c += 4) {
    float4 fiA = *(const float4*)(xiA + c);
    float4 fjA = *(const float4*)(xjA + c);
    float4 fiB = *(const float4*)(xiB + c);
    float4 fjB = *(const float4*)(xjB + c);
    dA0 = fma((double)fiA.x, (double)fjA.x, dA0);
    dB0 = fma((double)fiB.x, (double)fjB.x, dB0);
    dA1 = fma((double)fiA.y, (double)fjA.y, dA1);
    dB1 = fma((double)fiB.y, (double)fjB.y, dB1);
    dA2 = fma((double)fiA.z, (double)fjA.z, dA2);
    dB2 = fma((double)fiB.z, (double)fjB.z, dB2);
    dA3 = fma((double)fiA.w, (double)fjA.w, dA3);
    dB3 = fma((double)fiB.w, (double)fjB.w, dB3);
  }
  double scA = 2.0 * ((dA0 + dA1) + (dA2 + dA3)) - xxb[jA];
  double scB = 2.0 * ((dB0 + dB1) + (dB2 + dB3)) - xxb[jB];

  // dual rank via LDS broadcast reads (same-wave write->read)
  SdS[rrA][lane] = scA;
  SdS[rrB][lane] = scB;
  int rankA = 0, rankB = 0;
  const int cmax = cntA > cntB ? cntA : cntB;
  for (int mm = 0; mm < cmax; ++mm) {
    int mA = mm < cntA ? mm : 0;
    int mB = mm < cntB ? mm : 0;
    double smA = SdS[rrA][mA]; int jmA = CjS[rrA][mA];
    double smB = SdS[rrB][mB]; int jmB = CjS[rrB][mB];
    if (mm < cntA) rankA += (smA > scA || (smA == scA && jmA < jA)) ? 1 : 0;
    if (mm < cntB) rankB += (smB > scB || (smB == scB && jmB < jB)) ? 1 : 0;
  }
  if (lane < cntA && rankA < KK) {
    idx[(size_t)((b << 11) + irowA) * KK + rankA] = jA;
    sIdxL[rrA][rankA] = jA;
  }
  if (lane < cntB && rankB < KK) {
    idx[(size_t)((b << 11) + irowB) * KK + rankB] = jB;
    sIdxL[rrB][rankB] = jB;
  }

  // ---- Phase D: fused gather-stats (skipped when P==nullptr, Path B) ----
  if (P != nullptr) {
    __syncthreads();                               // sIdxL complete; SdS free
    const int grp = t >> 7;                        // 0..7 (4 points each)
    const int o = t & 127;
    float s = 0.f, s2 = 0.f;
#pragma unroll
    for (int pp = 0; pp < 4; ++pp) {
      const int pl = grp * 4 + pp;                 // local row 0..31
      const int pt = (b << 11) + i0 + pl;          // global point
      float qv = Q[(size_t)pt * OO + o];
      float vmax = -3.0e38f, vmin = 3.0e38f;
#pragma unroll
      for (int k = 0; k < KK; ++k) {
        float v = P[((size_t)((b << 11) + sIdxL[pl][k])) * OO + o] + qv;
        s += v;
        s2 = fmaf(v, v, s2);
        vmax = fmaxf(vmax, v);
        vmin = fminf(vmin, v);
      }
      vmaxA[(size_t)pt * OO + o] = vmax;
      vminA[(size_t)pt * OO + o] = vmin;
    }
    redF[grp * 128 + o] = s;
    redF[1024 + grp * 128 + o] = s2;
    __syncthreads();
    if (t < 128) {
      float as = 0.f, as2 = 0.f;
#pragma unroll
      for (int g = 0; g < 8; ++g) {                // fixed order: deterministic
        as  += redF[g * 128 + t];
        as2 += redF[1024 + g * 128 + t];
      }
      partial[(size_t)bidswz * 128 + t]               = as;
      partial[(size_t)NPART * 128 + (size_t)bidswz * 128 + t] = as2;
    }
  }
}

// ---------------------------------------------------------------------------
// k_stats (Path B fallback): standalone gather-stats.
// ---------------------------------------------------------------------------
__global__ __launch_bounds__(256) void k_stats(const float* __restrict__ P,
                                               const float* __restrict__ Q,
                                               const int* __restrict__ idx,
                                               float* __restrict__ partial) {
  __shared__ int sIdx[16 * KK];
  __shared__ float red[512];
  const int t = threadIdx.x;
  const int o = t & 127, half = t >> 7;
  const int bid = (blockIdx.x & 7) * 128 + (blockIdx.x >> 3);
  const int pt0 = bid * 16;
  const int b = pt0 >> 11;
  if (t < 160)
    *(int2*)(sIdx + t * 2) = *(const int2*)(idx + (size_t)pt0 * KK + t * 2);
  __syncthreads();

  float s = 0.f, s2 = 0.f;
  for (int it = 0; it < 8; ++it) {
    int pl = it * 2 + half;
    int pt = pt0 + pl;
    float qv = Q[(size_t)pt * OO + o];
    const int* ip = sIdx + pl * KK;
#pragma unroll
    for (int k = 0; k < KK; ++k) {
      float v = P[((size_t)((b << 11) + ip[k])) * OO + o] + qv;
      s += v;
      s2 = fmaf(v, v, s2);
    }
  }
  red[t] = s; red[256 + t] = s2;
  __syncthreads();
  if (t < 128) {
    partial[bid * 128 + o]                = red[t] + red[t + 128];
    partial[NPARTB * 128 + bid * 128 + o] = red[256 + t] + red[256 + t + 128];
  }
}

// ---------------------------------------------------------------------------
// k_fin: single-kernel BN finalize. 128 blocks (one per o); npart variable.
// ---------------------------------------------------------------------------
__global__ __launch_bounds__(256) void k_fin(const float* __restrict__ partial,
                                             const float* __restrict__ gamma,
                                             const float* __restrict__ beta,
                                             float* __restrict__ ss, int npart) {
  __shared__ float red[2][256];
  const int o = blockIdx.x;
  const int t = threadIdx.x;
  float s = 0.f, s2 = 0.f;
  for (int blk = t; blk < npart; blk += 256) {
    s  += partial[(size_t)blk * 128 + o];
    s2 += partial[(size_t)npart * 128 + (size_t)blk * 128 + o];
  }
  red[0][t] = s; red[1][t] = s2;
  __syncthreads();
  for (int st = 128; st >= 1; st >>= 1) {
    if (t < st) { red[0][t] += red[0][t + st]; red[1][t] += red[1][t + st]; }
    __syncthreads();
  }
  if (t == 0) {
    float mean = red[0][0] * (1.0f / M_TOT);
    float var  = red[1][0] * (1.0f / M_TOT) - mean * mean;
    float rs = 1.0f / sqrtf(var + 1e-5f);
    float scale = gamma[o] * rs;
    ss[o] = scale;
    ss[128 + o] = beta[o] - mean * scale;
  }
}

// ---------------------------------------------------------------------------
// k_out: BN affine -> exact GELU -> max over k -> out[b][o][n].
// ---------------------------------------------------------------------------
__global__ __launch_bounds__(256, 8) void k_out(const float* __restrict__ P,
                                                const float* __restrict__ Q,
                                                const int* __restrict__ idx,
                                                const float* __restrict__ ss,
                                                const float* __restrict__ vmaxA,
                                                const float* __restrict__ vminA,
                                                int use_minmax,
                                                float* __restrict__ out) {
  __shared__ float tile[32][OO + 1];               // 16.5 KB
  const int t = threadIdx.x;
  const int o = t & 127, half = t >> 7;
  const int bid = (blockIdx.x & 7) * 64 + (blockIdx.x >> 3);   // batch/XCD
  const float scale = ss[o], shift = ss[128 + o];
  const int pt0 = bid * 32;
  const int b = pt0 >> 11;
  const float inv_sqrt2 = 0.70710678118654752f;
  for (int it = 0; it < 16; ++it) {
    int pl = it * 2 + half;
    int pt = pt0 + pl;
    float vmax, vmin;
    if (use_minmax) {
      vmax = vmaxA[(size_t)pt * OO + o];
      vmin = vminA[(size_t)pt * OO + o];
    } else {
      float qv = Q[(size_t)pt * OO + o];
      const int* ip = idx + (size_t)pt * KK;
      vmax = -3.0e38f; vmin = 3.0e38f;
#pragma unroll
      for (int k = 0; k < KK; ++k) {
        float v = P[((size_t)((b << 11) + ip[k])) * OO + o] + qv;
        vmax = fmaxf(vmax, v);
        vmin = fminf(vmin, v);
      }
    }
    float ymax, ymin;
    if (scale >= 0.f) { ymax = fmaf(vmax, scale, shift); ymin = fmaf(vmin, scale, shift); }
    else              { ymax = fmaf(vmin, scale, shift); ymin = fmaf(vmax, scale, shift); }
    float g;
    if (ymax > 0.f) {
      g = 0.5f * ymax * (1.0f + erff(ymax * inv_sqrt2));
    } else {
      float g1 = 0.5f * ymax * (1.0f + erff(ymax * inv_sqrt2));
      float g2 = 0.5f * ymin * (1.0f + erff(ymin * inv_sqrt2));
      g = fmaxf(g1, g2);
    }
    tile[pl][o] = g;
  }
  __syncthreads();
  const int n0 = pt0 & (NN - 1);
  for (int rep = 0; rep < 16; ++rep) {
    int oo = rep * 8 + (t >> 5);
    int nn = t & 31;
    out[((size_t)(b * OO + oo) << 11) + n0 + nn] = tile[nn][oo];
  }
}

// ---------------------------------------------------------------------------
extern "C" void kernel_launch(void* const* d_in, const int* in_sizes, int n_in,
                              void* d_out, int out_size, void* d_ws, size_t ws_size,
                              hipStream_t stream) {
  const float* x     = (const float*)d_in[0];
  const float* W     = (const float*)d_in[1];
  const float* gamma = (const float*)d_in[2];
  const float* beta  = (const float*)d_in[3];
  float* out = (float*)d_out;

  const int knn_lds = 32 * NN * 2 + 8192 + 16384 + 32 * KK * 4;  // 158208 B
  hipFuncSetAttribute((const void*)k_knn,
                      hipFuncAttributeMaxDynamicSharedMemorySize, knn_lds);

  const size_t needA = 131072 + 65536 + 1310720 + (size_t)2 * NPARTB * 128 * 4 +
                       1024 + 4ull * 8388608;

  if (ws_size >= needA) {
    // Path A layout
    double* xx   = (double*)d_ws;                      // 131072 B
    float*  xxf  = (float*)(xx + BB * NN);             // 65536 B
    int*    idxp = (int*)(xxf + BB * NN);              // 1310720 B
    float*  part = (float*)(idxp + (size_t)BB * NN * KK); // 1 MB
    float*  ss   = part + 2 * NPARTB * 128;            // 1024 B
    float*  P    = ss + 256;                           // 8 MB
    float*  Q    = P + (size_t)BB * NN * OO;           // 8 MB
    ushort* xT   = (ushort*)(Q + (size_t)BB * NN * OO);// 2 MB
    float*  xTf  = (float*)(xT + (size_t)BB * NN * CC);// 4 MB
    float*  vmax = xTf + (size_t)BB * NN * CC;         // 8 MB (no alias: knn-D)
    float*  vmin = vmax + (size_t)BB * NN * OO;        // 8 MB
    const size_t needSafe = (size_t)((char*)(vmin + (size_t)BB * NN * OO) - (char*)d_ws);
    if (ws_size >= needSafe) {
      hipLaunchKernelGGL(k_pqprep, dim3(BB * NN / 32), dim3(256), 0, stream,
                         x, W, P, Q, xT, xTf, xx, xxf);
      hipLaunchKernelGGL(k_knn, dim3(BB * NN / 32), dim3(1024), knn_lds, stream,
                         xT, xxf, xTf, xx, idxp, P, Q, part, vmax, vmin);
      hipLaunchKernelGGL(k_fin, dim3(128), dim3(256), 0, stream, part, gamma, beta, ss, NPART);
      hipLaunchKernelGGL(k_out, dim3(BB * NN / 32), dim3(256), 0, stream,
                         P, Q, idxp, ss, vmax, vmin, 1, out);
      return;
    }
    // ws too small for safe vmax/vmin: alias xT/xTf region, no fused stats
    ushort* xTa  = (ushort*)(Q + (size_t)BB * NN * OO);
    float*  xTfa = (float*)(xTa + (size_t)BB * NN * CC);
    hipLaunchKernelGGL(k_pqprep, dim3(BB * NN / 32), dim3(256), 0, stream,
                       x, W, P, Q, xTa, xTfa, xx, xxf);
    hipLaunchKernelGGL(k_knn, dim3(BB * NN / 32), dim3(1024), knn_lds, stream,
                       xTa, xxf, xTfa, xx, idxp,
                       (const float*)nullptr, (const float*)nullptr,
                       (float*)nullptr, (float*)nullptr, (float*)nullptr);
    hipLaunchKernelGGL(k_stats, dim3(NPARTB), dim3(256), 0, stream,
                       P, Q, idxp, part);
    hipLaunchKernelGGL(k_fin, dim3(128), dim3(256), 0, stream, part, gamma, beta, ss, NPARTB);
    hipLaunchKernelGGL(k_out, dim3(BB * NN / 32), dim3(256), 0, stream,
                       P, Q, idxp, ss, (const float*)nullptr, (const float*)nullptr, 0, out);
  } else {
    // Path B layout (minimal ws)
    double* xx   = (double*)d_ws;
    int*    idxp = (int*)(xx + BB * NN);
    float*  P    = (float*)(idxp + (size_t)BB * NN * KK);
    float*  Q    = P + (size_t)BB * NN * OO;
    float*  part = Q + (size_t)BB * NN * OO;
    float*  ss   = part + 2 * NPARTB * 128;
    ushort* xT   = (ushort*)P;
    float*  xTf  = P + (size_t)BB * NN * (CC / 2);
    float*  xxf  = Q;

    hipLaunchKernelGGL(k_prep, dim3(BB * NN / 256), dim3(256), 0, stream,
                       x, xT, xTf, xx, xxf);
    hipLaunchKernelGGL(k_knn, dim3(BB * NN / 32), dim3(1024), knn_lds, stream,
                       xT, xxf, xTf, xx, idxp,
                       (const float*)nullptr, (const float*)nullptr,
                       (float*)nullptr, (float*)nullptr, (float*)nullptr);
    hipLaunchKernelGGL(k_pq, dim3(BB * NN / 64), dim3(256), 0, stream, x, W, P, Q);
    hipLaunchKernelGGL(k_stats, dim3(NPARTB), dim3(256), 0, stream,
                       P, Q, idxp, part);
    hipLaunchKernelGGL(k_fin, dim3(128), dim3(256), 0, stream, part, gamma, beta, ss, NPARTB);
    hipLaunchKernelGGL(k_out, dim3(BB * NN / 32), dim3(256), 0, stream,
                       P, Q, idxp, ss, (const float*)nullptr, (const float*)nullptr, 0, out);
  }
}